// Round 1
// baseline (8019.483 us; speedup 1.0000x reference)
//
#include <hip/hip_runtime.h>
#include <cstdint>

#define NTOK 5456
#define BB 2
#define CC 256
#define NHD 8
#define NLAYERS 6

typedef long long i64;

// ---------------- generic tiled f32 GEMM (128x64 tile, 8x4 micro) ----------------
// C(m,n) = sum_k A(m,k)*B(k,n) (+bias[n]) (+relu) (+res)
// A(m,k) at A[batch*bAz + m*sAm + k*sAk]; B(k,n) at B[batch*bBz + k*sBk + n*sBn]
// If KS>1: computes k-chunk ks and writes partial[z*M*N + m*N + n] (z = batch*KS+ks)
__global__ __launch_bounds__(256) void gemm_k(
    const float* __restrict__ A, i64 sAm, i64 sAk, i64 bAz,
    const float* __restrict__ B, i64 sBk, i64 sBn, i64 bBz,
    float* __restrict__ C, i64 sCm, i64 sCn, i64 bCz,
    const float* __restrict__ bias,
    const float* __restrict__ res, i64 bRz,
    int M, int N, int K, int relu, int KS,
    float* __restrict__ part)
{
  __shared__ float As[16][128];
  __shared__ float Bs[16][64];
  int z = blockIdx.z;
  int batch = z / KS;
  int ks = z - batch * KS;
  int Kc = (K + KS - 1) / KS;
  int k0 = ks * Kc;
  int k1 = min(K, k0 + Kc);
  const float* Ab = A + (i64)batch * bAz;
  const float* Bb = B + (i64)batch * bBz;
  int m0 = blockIdx.x * 128, n0 = blockIdx.y * 64;
  int tid = threadIdx.x;
  int tm = tid >> 4, tn = tid & 15;
  float acc[8][4];
#pragma unroll
  for (int i = 0; i < 8; i++)
#pragma unroll
    for (int j = 0; j < 4; j++) acc[i][j] = 0.f;

  for (int kt = k0; kt < k1; kt += 16) {
    if (sAm == 1) {
#pragma unroll
      for (int i = 0; i < 8; i++) {
        int e = tid + i * 256;
        int m = e & 127, k = e >> 7;
        int gm = m0 + m, gk = kt + k;
        As[k][m] = (gm < M && gk < k1) ? Ab[(i64)gm + (i64)gk * sAk] : 0.f;
      }
    } else {
#pragma unroll
      for (int i = 0; i < 8; i++) {
        int e = tid + i * 256;
        int k = e & 15, m = e >> 4;
        int gm = m0 + m, gk = kt + k;
        As[k][m] = (gm < M && gk < k1) ? Ab[(i64)gm * sAm + (i64)gk * sAk] : 0.f;
      }
    }
    if (sBn == 1) {
#pragma unroll
      for (int i = 0; i < 4; i++) {
        int e = tid + i * 256;
        int n = e & 63, k = e >> 6;
        int gk = kt + k, gn = n0 + n;
        Bs[k][n] = (gk < k1 && gn < N) ? Bb[(i64)gk * sBk + (i64)gn] : 0.f;
      }
    } else {
#pragma unroll
      for (int i = 0; i < 4; i++) {
        int e = tid + i * 256;
        int k = e & 15, n = e >> 4;
        int gk = kt + k, gn = n0 + n;
        Bs[k][n] = (gk < k1 && gn < N) ? Bb[(i64)gk * sBk + (i64)gn * sBn] : 0.f;
      }
    }
    __syncthreads();
#pragma unroll
    for (int kk = 0; kk < 16; kk++) {
      float4 a0 = *(const float4*)&As[kk][tm * 8];
      float4 a1 = *(const float4*)&As[kk][tm * 8 + 4];
      float4 b0 = *(const float4*)&Bs[kk][tn * 4];
      float a[8] = {a0.x, a0.y, a0.z, a0.w, a1.x, a1.y, a1.z, a1.w};
      float b[4] = {b0.x, b0.y, b0.z, b0.w};
#pragma unroll
      for (int i = 0; i < 8; i++)
#pragma unroll
        for (int j = 0; j < 4; j++) acc[i][j] = fmaf(a[i], b[j], acc[i][j]);
    }
    __syncthreads();
  }

  if (KS == 1) {
    float* Cb = C + (i64)batch * bCz;
#pragma unroll
    for (int i = 0; i < 8; i++) {
      int gm = m0 + tm * 8 + i;
      if (gm >= M) continue;
#pragma unroll
      for (int j = 0; j < 4; j++) {
        int gn = n0 + tn * 4 + j;
        if (gn >= N) continue;
        float v = acc[i][j];
        if (bias) v += bias[gn];
        if (relu) v = fmaxf(v, 0.f);
        i64 ci = (i64)gm * sCm + (i64)gn * sCn;
        if (res) v += res[(i64)batch * bRz + ci];
        Cb[ci] = v;
      }
    }
  } else {
    float* Pb = part + (i64)z * M * N;
#pragma unroll
    for (int i = 0; i < 8; i++) {
      int gm = m0 + tm * 8 + i;
      if (gm >= M) continue;
#pragma unroll
      for (int j = 0; j < 4; j++) {
        int gn = n0 + tn * 4 + j;
        if (gn >= N) continue;
        Pb[(i64)gm * N + gn] = acc[i][j];
      }
    }
  }
}

// reduce split-K partials: C = bias + sum_ks partial (+relu)(+res)
__global__ void reduce_k(const float* __restrict__ part, float* __restrict__ C,
    const float* __restrict__ bias, const float* __restrict__ res, i64 bRz,
    i64 sCm, i64 sCn, i64 bCz, int M, int N, int KS, int relu)
{
  int b = blockIdx.y;
  int idx = blockIdx.x * 256 + threadIdx.x;
  if (idx >= M * N) return;
  int m = idx / N, n = idx - m * N;
  const float* p = part + ((i64)b * KS) * M * N + idx;
  float v = bias ? bias[n] : 0.f;
  for (int ks = 0; ks < KS; ks++) v += p[(i64)ks * M * N];
  if (relu) v = fmaxf(v, 0.f);
  i64 ci = (i64)m * sCm + (i64)n * sCn;
  if (res) v += res[(i64)b * bRz + ci];
  C[(i64)b * bCz + ci] = v;
}

// im2col for 3x3 stride-2 pad-1 convs: out[b][ci*9+ky*3+kx][oy*Wout+ox]
__global__ void im2col_k(const float* __restrict__ in, float* __restrict__ out,
    int Cin, int Hin, int Win, int Hout, int Wout)
{
  int b = blockIdx.y;
  i64 K = (i64)Cin * 9, Mo = (i64)Hout * Wout;
  i64 total = K * Mo;
  for (i64 idx = (i64)blockIdx.x * 256 + threadIdx.x; idx < total;
       idx += (i64)gridDim.x * 256) {
    int m = (int)(idx % Mo);
    i64 k = idx / Mo;
    int kx = (int)(k % 3);
    int t9 = (int)(k / 3);
    int ky = t9 % 3, ci = t9 / 3;
    int oy = m / Wout, ox = m - oy * Wout;
    int iy = oy * 2 - 1 + ky, ix = ox * 2 - 1 + kx;
    float v = 0.f;
    if (iy >= 0 && iy < Hin && ix >= 0 && ix < Win)
      v = in[((i64)b * Cin + ci) * (i64)(Hin * Win) + iy * Win + ix];
    out[((i64)b * K + k) * Mo + m] = v;
  }
}

// GroupNorm(8)+ReLU over feats tokens [5376..5440) -> y as [b][256][64]
__global__ void gn_relu_k(const float* __restrict__ feats, float* __restrict__ y,
    const float* __restrict__ g, const float* __restrict__ bt)
{
  int grp = blockIdx.x, b = blockIdx.y;
  int tid = threadIdx.x;
  const float* fb = feats + ((i64)b * NTOK + 5376) * CC + grp * 32;
  float s = 0.f, ss = 0.f;
  for (int i = tid; i < 2048; i += 256) {
    int cl = i >> 6, p = i & 63;
    float v = fb[(i64)p * CC + cl];
    s += v;
    ss += v * v;
  }
  __shared__ float sb[4], ssb[4];
#pragma unroll
  for (int o = 32; o > 0; o >>= 1) { s += __shfl_down(s, o); ss += __shfl_down(ss, o); }
  int w = tid >> 6;
  if ((tid & 63) == 0) { sb[w] = s; ssb[w] = ss; }
  __syncthreads();
  float ts = sb[0] + sb[1] + sb[2] + sb[3];
  float tss = ssb[0] + ssb[1] + ssb[2] + ssb[3];
  float mean = ts * (1.f / 2048.f);
  float rs = rsqrtf(tss * (1.f / 2048.f) - mean * mean + 1e-5f);
  for (int i = tid; i < 2048; i += 256) {
    int cl = i >> 6, p = i & 63;
    int c = grp * 32 + cl;
    float v = (fb[(i64)p * CC + cl] - mean) * rs * g[c] + bt[c];
    y[((i64)b * CC + c) * 64 + p] = fmaxf(v, 0.f);
  }
}

// LayerNorm over rows of 256, one wave per row (4 rows per block)
__global__ __launch_bounds__(256) void ln_k(const float* __restrict__ x,
    float* __restrict__ y, const float* __restrict__ g, const float* __restrict__ bt,
    int rows)
{
  int row = blockIdx.x * 4 + (threadIdx.x >> 6);
  if (row >= rows) return;
  int lane = threadIdx.x & 63;
  const float4* xr = (const float4*)(x + (i64)row * CC);
  float4 v = xr[lane];
  float s = v.x + v.y + v.z + v.w;
  float ss = v.x * v.x + v.y * v.y + v.z * v.z + v.w * v.w;
#pragma unroll
  for (int o = 32; o > 0; o >>= 1) { s += __shfl_down(s, o); ss += __shfl_down(ss, o); }
  s = __shfl(s, 0);
  ss = __shfl(ss, 0);
  float mean = s * (1.f / 256.f);
  float rs = rsqrtf(ss * (1.f / 256.f) - mean * mean + 1e-5f);
  float4 gg = ((const float4*)g)[lane];
  float4 bb = ((const float4*)bt)[lane];
  float4 o4;
  o4.x = (v.x - mean) * rs * gg.x + bb.x;
  o4.y = (v.y - mean) * rs * gg.y + bb.y;
  o4.z = (v.z - mean) * rs * gg.z + bb.z;
  o4.w = (v.w - mean) * rs * gg.w + bb.w;
  ((float4*)(y + (i64)row * CC))[lane] = o4;
}

// in-place softmax over groups of 20
__global__ void softmax20_k(float* __restrict__ att, int total)
{
  int idx = blockIdx.x * 256 + threadIdx.x;
  if (idx >= total) return;
  float* p = att + (i64)idx * 20;
  float mx = p[0];
#pragma unroll
  for (int i = 1; i < 20; i++) mx = fmaxf(mx, p[i]);
  float e[20];
  float sum = 0.f;
#pragma unroll
  for (int i = 0; i < 20; i++) { e[i] = __expf(p[i] - mx); sum += e[i]; }
  float r = 1.f / sum;
#pragma unroll
  for (int i = 0; i < 20; i++) p[i] = e[i] * r;
}

// deformable sampling: block = one (b,t); 256 thr = 8 heads x 32 dh
__global__ __launch_bounds__(256) void dsample_k(
    const float* __restrict__ val, const float* __restrict__ off,
    const float* __restrict__ att, float* __restrict__ out)
{
  const int FH[5] = {64, 32, 16, 8, 4};
  const int ST[5] = {0, 4096, 5120, 5376, 5440};
  int t = blockIdx.x, b = blockIdx.y;
  int h = threadIdx.x >> 5, dh = threadIdx.x & 31;
  int lv, loc;
  if (t < 4096)      { lv = 0; loc = t; }
  else if (t < 5120) { lv = 1; loc = t - 4096; }
  else if (t < 5376) { lv = 2; loc = t - 5120; }
  else if (t < 5440) { lv = 3; loc = t - 5376; }
  else               { lv = 4; loc = t - 5440; }
  int fw0 = FH[lv];
  int py = loc / fw0, px = loc - py * fw0;
  float prx = (px + 0.5f) / fw0, pry = (py + 0.5f) / fw0;
  i64 bt = (i64)b * NTOK + t;
  const float* offp = off + (bt * 8 + h) * 40;
  const float* attp = att + (bt * 8 + h) * 20;
  const float* vb = val + (i64)b * NTOK * CC + h * 32 + dh;
  float acc = 0.f;
#pragma unroll
  for (int l = 0; l < 5; l++) {
    const int sf = FH[l], st = ST[l];
    const float sff = (float)sf;
#pragma unroll
    for (int p = 0; p < 4; p++) {
      float ox = offp[(l * 4 + p) * 2];
      float oy = offp[(l * 4 + p) * 2 + 1];
      float a = attp[l * 4 + p];
      float lx = prx + ox / sff;
      float ly = pry + oy / sff;
      float xx = lx * sff - 0.5f;
      float yy = ly * sff - 0.5f;
      float xf = floorf(xx), yf = floorf(yy);
      float fx = xx - xf, fy = yy - yf;
      int x0 = (int)xf, y0 = (int)yf;
      float w00 = (1.f - fx) * (1.f - fy);
      float w10 = fx * (1.f - fy);
      float w01 = (1.f - fx) * fy;
      float w11 = fx * fy;
      float sv = 0.f;
      bool xin0 = (x0 >= 0) & (x0 < sf), xin1 = (x0 + 1 >= 0) & (x0 + 1 < sf);
      bool yin0 = (y0 >= 0) & (y0 < sf), yin1 = (y0 + 1 >= 0) & (y0 + 1 < sf);
      if (xin0 & yin0) sv += w00 * vb[(i64)(st + y0 * sf + x0) * CC];
      if (xin1 & yin0) sv += w10 * vb[(i64)(st + y0 * sf + x0 + 1) * CC];
      if (xin0 & yin1) sv += w01 * vb[(i64)(st + (y0 + 1) * sf + x0) * CC];
      if (xin1 & yin1) sv += w11 * vb[(i64)(st + (y0 + 1) * sf + x0 + 1) * CC];
      acc = fmaf(a, sv, acc);
    }
  }
  out[(bt * 8 + h) * 32 + dh] = acc;
}

// out[b][c][p] = feats[b][start+p][c]   (32x32 LDS tile transpose)
__global__ __launch_bounds__(256) void untranspose_k(const float* __restrict__ feats,
    float* __restrict__ out, int start, int S, i64 ooff)
{
  __shared__ float tile[32][33];
  int pt = blockIdx.x * 32, ct = blockIdx.y * 32, b = blockIdx.z;
  int tx = threadIdx.x & 31, ty = threadIdx.x >> 5;
  for (int i = ty; i < 32; i += 8) {
    int p = pt + i;
    tile[i][tx] = (p < S) ? feats[((i64)b * NTOK + start + p) * CC + ct + tx] : 0.f;
  }
  __syncthreads();
  for (int i = ty; i < 32; i += 8) {
    int c = ct + i, p = pt + tx;
    if (p < S) out[ooff + ((i64)b * CC + c) * S + p] = tile[tx][i];
  }
}

extern "C" void kernel_launch(void* const* d_in, const int* in_sizes, int n_in,
                              void* d_out, int out_size, void* d_ws, size_t ws_size,
                              hipStream_t stream)
{
  const float* in0  = (const float*)d_in[0];
  const float* in1  = (const float*)d_in[1];
  const float* in2  = (const float*)d_in[2];
  const float* pw0  = (const float*)d_in[3];
  const float* pb0  = (const float*)d_in[4];
  const float* pw1  = (const float*)d_in[5];
  const float* pb1  = (const float*)d_in[6];
  const float* pw2  = (const float*)d_in[7];
  const float* pb2  = (const float*)d_in[8];
  const float* buw0 = (const float*)d_in[9];
  const float* bub0 = (const float*)d_in[10];
  const float* gng  = (const float*)d_in[11];
  const float* gnb  = (const float*)d_in[12];
  const float* buw1 = (const float*)d_in[13];
  const float* bub1 = (const float*)d_in[14];
  const float* ln1g = (const float*)d_in[15];
  const float* ln1b = (const float*)d_in[16];
  const float* woff = (const float*)d_in[17];
  const float* boff = (const float*)d_in[18];
  const float* watt = (const float*)d_in[19];
  const float* batt = (const float*)d_in[20];
  const float* wval = (const float*)d_in[21];
  const float* bval = (const float*)d_in[22];
  const float* wout = (const float*)d_in[23];
  const float* bout = (const float*)d_in[24];
  const float* ln2g = (const float*)d_in[25];
  const float* ln2b = (const float*)d_in[26];
  const float* w1   = (const float*)d_in[27];
  const float* b1   = (const float*)d_in[28];
  const float* w2   = (const float*)d_in[29];
  const float* b2   = (const float*)d_in[30];
  float* out = (float*)d_out;

  const i64 TC = (i64)NTOK * CC;          // per-batch feats stride
  const i64 FE = (i64)BB * TC;            // 2,793,472

  float* ws    = (float*)d_ws;
  float* feats = ws;
  float* bufA  = feats + FE;              // q / sampled-out / ln2-out
  float* bufB  = bufA + FE;               // val
  float* bufD  = bufB + FE;               // off (3.49M) U ffn-h (5.587M)
  float* bufE  = bufD + 5586944;          // att logits/weights
  float* m4gn  = bufE + 1745920;          // [2,256,64]
  float* xcol0 = m4gn + 32768;            // [2,18432,64]
  float* xcol1 = xcol0 + 2359296;         // [2,2304,16]
  float* part  = xcol1 + 73728;           // split-K partials (1,048,576)

  auto gemm = [&](const float* A, i64 sAm, i64 sAk, i64 bAz,
                  const float* Bm, i64 sBk, i64 sBn, i64 bBz,
                  float* Cp, i64 sCm, i64 sCn, i64 bCz,
                  const float* bias, const float* res, i64 bRz,
                  int M, int N, int K, int relu, int KS, int zB, float* prt) {
    dim3 g((M + 127) / 128, (N + 63) / 64, zB * KS);
    hipLaunchKernelGGL(gemm_k, g, dim3(256), 0, stream,
                       A, sAm, sAk, bAz, Bm, sBk, sBn, bBz, Cp, sCm, sCn, bCz,
                       bias, res, bRz, M, N, K, relu, KS, prt);
  };
  auto reduce = [&](float* prt, float* Cp, const float* bias, const float* res, i64 bRz,
                    i64 sCm, i64 sCn, i64 bCz, int M, int N, int KS, int zB, int relu) {
    dim3 g((M * N + 255) / 256, zB);
    hipLaunchKernelGGL(reduce_k, g, dim3(256), 0, stream,
                       prt, Cp, bias, res, bRz, sCm, sCn, bCz, M, N, KS, relu);
  };

  // ---- conv1x1 projections directly into feats [b, tok, c] ----
  gemm(in0, 1, 4096, (i64)512 * 4096, pw0, 1, 512, 0,
       feats, CC, 1, TC, pb0, nullptr, 0, 4096, 256, 512, 0, 1, 2, nullptr);
  gemm(in1, 1, 1024, (i64)1024 * 1024, pw1, 1, 1024, 0,
       feats + (i64)4096 * CC, CC, 1, TC, pb1, nullptr, 0, 1024, 256, 1024, 0, 1, 2, nullptr);
  // level2: small M -> split-K
  gemm(in2, 1, 256, (i64)2048 * 256, pw2, 1, 2048, 0,
       feats, CC, 1, TC, nullptr, nullptr, 0, 256, 256, 2048, 0, 8, 2, part);
  reduce(part, feats + (i64)5120 * CC, pb2, nullptr, 0, CC, 1, TC, 256, 256, 8, 2, 0);

  // ---- bottom-up conv 3x3 s2 on raw in_map2 (2048ch, 16x16 -> 8x8) ----
  hipLaunchKernelGGL(im2col_k, dim3(2048, 2), dim3(256), 0, stream,
                     in2, xcol0, 2048, 16, 16, 8, 8);
  gemm(xcol0, 1, 64, (i64)18432 * 64, buw0, 1, 18432, 0,
       feats, CC, 1, TC, nullptr, nullptr, 0, 64, 256, 18432, 0, 32, 2, part);
  reduce(part, feats + (i64)5376 * CC, bub0, nullptr, 0, CC, 1, TC, 64, 256, 32, 2, 0);

  // ---- GN(8)+ReLU then conv 3x3 s2 (256ch, 8x8 -> 4x4) ----
  hipLaunchKernelGGL(gn_relu_k, dim3(8, 2), dim3(256), 0, stream, feats, m4gn, gng, gnb);
  hipLaunchKernelGGL(im2col_k, dim3(144, 2), dim3(256), 0, stream,
                     m4gn, xcol1, 256, 8, 8, 4, 4);
  gemm(xcol1, 1, 16, (i64)2304 * 16, buw1, 1, 2304, 0,
       feats, CC, 1, TC, nullptr, nullptr, 0, 16, 256, 2304, 0, 4, 2, part);
  reduce(part, feats + (i64)5440 * CC, bub1, nullptr, 0, CC, 1, TC, 16, 256, 4, 2, 0);

  // ---- 6 transformer layers ----
  const int BN = BB * NTOK;  // 10912
  for (int i = 0; i < NLAYERS; i++) {
    // LN1 -> q (bufA)
    hipLaunchKernelGGL(ln_k, dim3((BN + 3) / 4), dim3(256), 0, stream,
                       feats, bufA, ln1g + (i64)i * CC, ln1b + (i64)i * CC, BN);
    // offsets: [BN,320]
    gemm(bufA, CC, 1, 0, woff + (i64)i * CC * 320, 320, 1, 0,
         bufD, 320, 1, 0, boff + (i64)i * 320, nullptr, 0, BN, 320, CC, 0, 1, 1, nullptr);
    // attn logits: [BN,160]
    gemm(bufA, CC, 1, 0, watt + (i64)i * CC * 160, 160, 1, 0,
         bufE, 160, 1, 0, batt + (i64)i * 160, nullptr, 0, BN, 160, CC, 0, 1, 1, nullptr);
    // values: [BN,256]
    gemm(bufA, CC, 1, 0, wval + (i64)i * CC * CC, CC, 1, 0,
         bufB, CC, 1, 0, bval + (i64)i * CC, nullptr, 0, BN, CC, CC, 0, 1, 1, nullptr);
    // softmax over 20
    hipLaunchKernelGGL(softmax20_k, dim3((BN * NHD + 255) / 256), dim3(256), 0, stream,
                       bufE, BN * NHD);
    // deformable sampling -> bufA (q dead)
    hipLaunchKernelGGL(dsample_k, dim3(NTOK, BB), dim3(256), 0, stream,
                       bufB, bufD, bufE, bufA);
    // out proj + residual into feats
    gemm(bufA, CC, 1, 0, wout + (i64)i * CC * CC, CC, 1, 0,
         feats, CC, 1, 0, bout + (i64)i * CC, feats, 0, BN, CC, CC, 0, 1, 1, nullptr);
    // LN2 -> bufA
    hipLaunchKernelGGL(ln_k, dim3((BN + 3) / 4), dim3(256), 0, stream,
                       feats, bufA, ln2g + (i64)i * CC, ln2b + (i64)i * CC, BN);
    // FFN per batch (h buffer fits bufD)
    for (int b = 0; b < BB; b++) {
      gemm(bufA + (i64)b * TC, CC, 1, 0, w1 + (i64)i * CC * 1024, 1024, 1, 0,
           bufD, 1024, 1, 0, b1 + (i64)i * 1024, nullptr, 0, NTOK, 1024, CC, 1, 1, 1, nullptr);
      gemm(bufD, 1024, 1, 0, w2 + (i64)i * 1024 * CC, CC, 1, 0,
           feats + (i64)b * TC, CC, 1, 0, b2 + (i64)i * CC, feats + (i64)b * TC, 0,
           NTOK, CC, 1024, 0, 1, 1, nullptr);
    }
  }

  // ---- split back into 5 level maps [B,C,fh,fw], concatenated in d_out ----
  const int starts[5] = {0, 4096, 5120, 5376, 5440};
  const int fhs[5] = {64, 32, 16, 8, 4};
  i64 ooff = 0;
  for (int l = 0; l < 5; l++) {
    int S = fhs[l] * fhs[l];
    dim3 g((S + 31) / 32, CC / 32, BB);
    hipLaunchKernelGGL(untranspose_k, g, dim3(256), 0, stream, feats, out, starts[l], S, ooff);
    ooff += (i64)BB * CC * S;
  }
  (void)in_sizes; (void)n_in; (void)out_size; (void)ws_size;
}

// Round 2
// 2388.867 us; speedup vs baseline: 3.3570x; 3.3570x over previous
//
#include <hip/hip_runtime.h>
#include <cstdint>

typedef long long i64;
typedef unsigned short u16;
typedef __attribute__((ext_vector_type(8))) short short8;
typedef __attribute__((ext_vector_type(4))) float f32x4;

#define NTOK 5456
#define BNROWS 10912
#define NLAYERS 6

__device__ __forceinline__ u16 f2bf(float f) {
  unsigned u = __float_as_uint(f);
  return (u16)((u + 0x7FFFu + ((u >> 16) & 1u)) >> 16);
}
__device__ __forceinline__ float bf2f(u16 h) {
  return __uint_as_float(((unsigned)h) << 16);
}

// ---------------- bf16 MFMA GEMM ----------------
// A: [>=M][K] bf16 row-major. B: [>=Npad][K] bf16 row-major (i.e. B^T, n-major).
// C = A @ B^T : full-K path writes fp32 C (bias/relu/res+=) or bf16 C16.
// KS>1: writes fp32 partials part[ks][M][Npad] for k-chunk ks (grid.z).
// Row->output mapping: out row index = (row/Mb)*bCz + (row%Mb)*sCm.
__global__ __launch_bounds__(256) void mgemm_k(
    const u16* __restrict__ A, const u16* __restrict__ B, int K,
    float* __restrict__ C, u16* __restrict__ C16, i64 sCm,
    const float* __restrict__ bias, int relu, int addres,
    int M, int N, int Mb, i64 bCz,
    int KS, float* __restrict__ part, int Npad)
{
  __shared__ u16 Asm[128 * 64];
  __shared__ u16 Bsm[128 * 64];
  int tid = threadIdx.x;
  int m0 = blockIdx.x * 128, n0 = blockIdx.y * 128;
  int ks = blockIdx.z;
  int Kc = K / KS;
  int k0 = ks * Kc;
  int lane = tid & 63, w = tid >> 6;
  int wr = w >> 1, wc = w & 1;
  int r16 = lane & 15, g = lane >> 4;

  f32x4 acc[4][4];
#pragma unroll
  for (int mi = 0; mi < 4; mi++)
#pragma unroll
    for (int nj = 0; nj < 4; nj++) acc[mi][nj] = (f32x4){0.f, 0.f, 0.f, 0.f};

  const u16* Ag = A + (i64)m0 * K + k0;
  const u16* Bg = B + (i64)n0 * K + k0;

  for (int kt = 0; kt < Kc; kt += 64) {
    // stage A tile [128][64] and B tile [128][64]; LDS linear, source XOR-swizzled
#pragma unroll
    for (int r = 0; r < 4; r++) {
      int s = r * 256 + tid;
      int row = s >> 3, c = s & 7;
      int cs = ((c ^ (row & 7)) << 3);
      __builtin_amdgcn_global_load_lds(
          (const __attribute__((address_space(1))) void*)(Ag + (i64)row * K + kt + cs),
          (__attribute__((address_space(3))) void*)(Asm + ((r * 256 + (w << 6)) << 3)),
          16, 0, 0);
    }
#pragma unroll
    for (int r = 0; r < 4; r++) {
      int s = r * 256 + tid;
      int row = s >> 3, c = s & 7;
      int cs = ((c ^ (row & 7)) << 3);
      __builtin_amdgcn_global_load_lds(
          (const __attribute__((address_space(1))) void*)(Bg + (i64)row * K + kt + cs),
          (__attribute__((address_space(3))) void*)(Bsm + ((r * 256 + (w << 6)) << 3)),
          16, 0, 0);
    }
    __syncthreads();  // drains vmcnt before barrier
#pragma unroll
    for (int h = 0; h < 2; h++) {
      short8 av[4], bv[4];
#pragma unroll
      for (int mi = 0; mi < 4; mi++) {
        int row = wr * 64 + mi * 16 + r16;
        av[mi] = *(const short8*)(Asm + row * 64 + ((((h << 2) + g) ^ (row & 7)) << 3));
      }
#pragma unroll
      for (int nj = 0; nj < 4; nj++) {
        int row = wc * 64 + nj * 16 + r16;
        bv[nj] = *(const short8*)(Bsm + row * 64 + ((((h << 2) + g) ^ (row & 7)) << 3));
      }
#pragma unroll
      for (int mi = 0; mi < 4; mi++)
#pragma unroll
        for (int nj = 0; nj < 4; nj++)
          acc[mi][nj] = __builtin_amdgcn_mfma_f32_16x16x32_bf16(
              av[mi], bv[nj], acc[mi][nj], 0, 0, 0);
    }
    __syncthreads();
  }

  if (KS > 1) {
#pragma unroll
    for (int mi = 0; mi < 4; mi++)
#pragma unroll
      for (int nj = 0; nj < 4; nj++)
#pragma unroll
        for (int r = 0; r < 4; r++) {
          int grow = m0 + wr * 64 + mi * 16 + g * 4 + r;
          if (grow < M) {
            int gcol = n0 + wc * 64 + nj * 16 + r16;
            part[((i64)ks * M + grow) * Npad + gcol] = acc[mi][nj][r];
          }
        }
  } else {
#pragma unroll
    for (int mi = 0; mi < 4; mi++)
#pragma unroll
      for (int nj = 0; nj < 4; nj++)
#pragma unroll
        for (int r = 0; r < 4; r++) {
          int grow = m0 + wr * 64 + mi * 16 + g * 4 + r;
          int gcol = n0 + wc * 64 + nj * 16 + r16;
          if (grow < M && gcol < N) {
            float v = acc[mi][nj][r];
            if (bias) v += bias[gcol];
            if (relu) v = fmaxf(v, 0.f);
            i64 ci = (i64)(grow / Mb) * bCz + (i64)(grow % Mb) * sCm + gcol;
            if (C16) C16[ci] = f2bf(v);
            else {
              if (addres) v += C[ci];
              C[ci] = v;
            }
          }
        }
  }
}

// reduce split-K fp32 partials
__global__ void reduce_k(const float* __restrict__ part, float* __restrict__ C,
    const float* __restrict__ bias, int Mb, i64 bCz, i64 sCm,
    int M, int N, int Npad, int KS)
{
  int idx = blockIdx.x * 256 + threadIdx.x;
  if (idx >= M * N) return;
  int m = idx / N, n = idx - m * N;
  float v = bias ? bias[n] : 0.f;
  for (int ks = 0; ks < KS; ks++) v += part[((i64)ks * M + m) * Npad + n];
  C[(i64)(m / Mb) * bCz + (i64)(m % Mb) * sCm + n] = v;
}

// ---------------- weight conversions ----------------
// prologue weights are already [n][k] row-major -> straight convert
__global__ void cvt_w_pro_k(const float* __restrict__ pw0, const float* __restrict__ pw1,
    const float* __restrict__ pw2, const float* __restrict__ buw0,
    const float* __restrict__ buw1, u16* __restrict__ dst)
{
  int idx = blockIdx.x * 256 + threadIdx.x;
  if (idx >= 6225920) return;
  float v;
  if (idx < 131072) v = pw0[idx];
  else if (idx < 393216) v = pw1[idx - 131072];
  else if (idx < 917504) v = pw2[idx - 393216];
  else if (idx < 5636096) v = buw0[idx - 917504];
  else v = buw1[idx - 5636096];
  dst[idx] = f2bf(v);
}

// layer weights [k][n] -> [n][k] bf16, padded segments:
// off 384x256 | att 256x256 | val 256x256 | out 256x256 | w1 1024x256 | w2 256x1024
__global__ void cvt_w_layer_k(const float* __restrict__ woff, const float* __restrict__ watt,
    const float* __restrict__ wval, const float* __restrict__ wout,
    const float* __restrict__ w1, const float* __restrict__ w2, u16* __restrict__ dst)
{
  int L = blockIdx.y;
  int o = blockIdx.x * 256 + threadIdx.x;
  if (o >= 819200) return;
  u16* d = dst + (i64)L * 819200;
  float v;
  if (o < 98304) {
    int n = o >> 8, k = o & 255;
    if (n >= 320) return;
    v = woff[(i64)L * 81920 + k * 320 + n];
  } else if (o < 163840) {
    int o2 = o - 98304; int n = o2 >> 8, k = o2 & 255;
    if (n >= 160) return;
    v = watt[(i64)L * 40960 + k * 160 + n];
  } else if (o < 229376) {
    int o2 = o - 163840; int n = o2 >> 8, k = o2 & 255;
    v = wval[(i64)L * 65536 + k * 256 + n];
  } else if (o < 294912) {
    int o2 = o - 229376; int n = o2 >> 8, k = o2 & 255;
    v = wout[(i64)L * 65536 + k * 256 + n];
  } else if (o < 557056) {
    int o2 = o - 294912; int n = o2 >> 8, k = o2 & 255;
    v = w1[(i64)L * 262144 + (i64)k * 1024 + n];
  } else {
    int o2 = o - 557056; int n = o2 >> 10, k = o2 & 1023;
    v = w2[(i64)L * 262144 + (i64)k * 256 + n];
  }
  d[o] = f2bf(v);
}

// in_map [2][K][P] fp32 -> A [2*P][K] bf16 (transpose-convert)
__global__ void cvt_a_proj_k(const float* __restrict__ in, u16* __restrict__ out,
                             int P, int K)
{
  i64 o = (i64)blockIdx.x * 256 + threadIdx.x;
  if (o >= (i64)2 * P * K) return;
  int m = (int)(o / K), k = (int)(o % K);
  int b = m / P, p = m - b * P;
  out[o] = f2bf(in[((i64)b * K + k) * P + p]);
}

// im2col 3x3 s2 p1 -> bf16 [2*Ho*Wo][Cin*9] row-major
__global__ void im2col_bf16_k(const float* __restrict__ in, u16* __restrict__ out,
    int Cin, int Hin, int Win, int Ho, int Wo)
{
  int Kk = Cin * 9;
  i64 total = (i64)2 * Ho * Wo * Kk;
  i64 o = (i64)blockIdx.x * 256 + threadIdx.x;
  if (o >= total) return;
  int k = (int)(o % Kk);
  int m = (int)(o / Kk);
  int hw = Ho * Wo;
  int b = m / hw, pix = m - b * hw;
  int oy = pix / Wo, ox = pix - oy * Wo;
  int ci = k / 9, r = k - ci * 9;
  int ky = r / 3, kx = r - ky * 3;
  int iy = oy * 2 - 1 + ky, ix = ox * 2 - 1 + kx;
  float v = 0.f;
  if (iy >= 0 && iy < Hin && ix >= 0 && ix < Win)
    v = in[(((i64)b * Cin + ci) * Hin + iy) * Win + ix];
  out[o] = f2bf(v);
}

// GroupNorm(8)+ReLU over feats tokens [5376..5440) -> y [b][256][64] fp32
__global__ void gn_relu_k(const float* __restrict__ feats, float* __restrict__ y,
    const float* __restrict__ g, const float* __restrict__ bt)
{
  int grp = blockIdx.x, b = blockIdx.y;
  int tid = threadIdx.x;
  const float* fb = feats + ((i64)b * NTOK + 5376) * 256 + grp * 32;
  float s = 0.f, ss = 0.f;
  for (int i = tid; i < 2048; i += 256) {
    int cl = i >> 6, p = i & 63;
    float v = fb[(i64)p * 256 + cl];
    s += v; ss += v * v;
  }
  __shared__ float sb[4], ssb[4];
#pragma unroll
  for (int o = 32; o > 0; o >>= 1) { s += __shfl_down(s, o); ss += __shfl_down(ss, o); }
  int wv = tid >> 6;
  if ((tid & 63) == 0) { sb[wv] = s; ssb[wv] = ss; }
  __syncthreads();
  float ts = sb[0] + sb[1] + sb[2] + sb[3];
  float tss = ssb[0] + ssb[1] + ssb[2] + ssb[3];
  float mean = ts * (1.f / 2048.f);
  float rs = rsqrtf(tss * (1.f / 2048.f) - mean * mean + 1e-5f);
  for (int i = tid; i < 2048; i += 256) {
    int cl = i >> 6, p = i & 63;
    int c = grp * 32 + cl;
    float v = (fb[(i64)p * 256 + cl] - mean) * rs * g[c] + bt[c];
    y[((i64)b * 256 + c) * 64 + p] = fmaxf(v, 0.f);
  }
}

// LayerNorm rows of 256, fp32 in -> bf16 out
__global__ __launch_bounds__(256) void ln_k(const float* __restrict__ x,
    u16* __restrict__ y, const float* __restrict__ g, const float* __restrict__ bt,
    int rows)
{
  int row = blockIdx.x * 4 + (threadIdx.x >> 6);
  if (row >= rows) return;
  int lane = threadIdx.x & 63;
  float4 v = ((const float4*)(x + (i64)row * 256))[lane];
  float s = v.x + v.y + v.z + v.w;
  float ss = v.x * v.x + v.y * v.y + v.z * v.z + v.w * v.w;
#pragma unroll
  for (int o = 32; o > 0; o >>= 1) { s += __shfl_down(s, o); ss += __shfl_down(ss, o); }
  s = __shfl(s, 0);
  ss = __shfl(ss, 0);
  float mean = s * (1.f / 256.f);
  float rs = rsqrtf(ss * (1.f / 256.f) - mean * mean + 1e-5f);
  float4 gg = ((const float4*)g)[lane];
  float4 bb = ((const float4*)bt)[lane];
  ushort4 o4;
  o4.x = f2bf((v.x - mean) * rs * gg.x + bb.x);
  o4.y = f2bf((v.y - mean) * rs * gg.y + bb.y);
  o4.z = f2bf((v.z - mean) * rs * gg.z + bb.z);
  o4.w = f2bf((v.w - mean) * rs * gg.w + bb.w);
  ((ushort4*)(y + (i64)row * 256))[lane] = o4;
}

__global__ void softmax20_k(float* __restrict__ att, int total)
{
  int idx = blockIdx.x * 256 + threadIdx.x;
  if (idx >= total) return;
  float* p = att + (i64)idx * 20;
  float mx = p[0];
#pragma unroll
  for (int i = 1; i < 20; i++) mx = fmaxf(mx, p[i]);
  float e[20]; float sum = 0.f;
#pragma unroll
  for (int i = 0; i < 20; i++) { e[i] = __expf(p[i] - mx); sum += e[i]; }
  float r = 1.f / sum;
#pragma unroll
  for (int i = 0; i < 20; i++) p[i] = e[i] * r;
}

// deformable sampling: block = one (b,t); 256 thr = 8 heads x 32 dh; bf16 val/out
__global__ __launch_bounds__(256) void dsample_k(
    const u16* __restrict__ val, const float* __restrict__ off,
    const float* __restrict__ att, u16* __restrict__ out)
{
  const int FH[5] = {64, 32, 16, 8, 4};
  const int ST[5] = {0, 4096, 5120, 5376, 5440};
  int t = blockIdx.x, b = blockIdx.y;
  int h = threadIdx.x >> 5, dh = threadIdx.x & 31;
  int lv, loc;
  if (t < 4096)      { lv = 0; loc = t; }
  else if (t < 5120) { lv = 1; loc = t - 4096; }
  else if (t < 5376) { lv = 2; loc = t - 5120; }
  else if (t < 5440) { lv = 3; loc = t - 5376; }
  else               { lv = 4; loc = t - 5440; }
  int fw0 = FH[lv];
  int py = loc / fw0, px = loc - py * fw0;
  float prx = (px + 0.5f) / fw0, pry = (py + 0.5f) / fw0;
  i64 bt = (i64)b * NTOK + t;
  const float* offp = off + bt * 320 + h * 40;
  const float* attp = att + bt * 160 + h * 20;
  const u16* vb = val + (i64)b * NTOK * 256 + h * 32 + dh;
  float acc = 0.f;
#pragma unroll
  for (int l = 0; l < 5; l++) {
    const int sf = FH[l], st = ST[l];
    const float sff = (float)sf;
#pragma unroll
    for (int p = 0; p < 4; p++) {
      float ox = offp[(l * 4 + p) * 2];
      float oy = offp[(l * 4 + p) * 2 + 1];
      float a = attp[l * 4 + p];
      float xx = (prx + ox / sff) * sff - 0.5f;
      float yy = (pry + oy / sff) * sff - 0.5f;
      float xf = floorf(xx), yf = floorf(yy);
      float fx = xx - xf, fy = yy - yf;
      int x0 = (int)xf, y0 = (int)yf;
      float w00 = (1.f - fx) * (1.f - fy);
      float w10 = fx * (1.f - fy);
      float w01 = (1.f - fx) * fy;
      float w11 = fx * fy;
      float sv = 0.f;
      bool xin0 = (x0 >= 0) & (x0 < sf), xin1 = (x0 + 1 >= 0) & (x0 + 1 < sf);
      bool yin0 = (y0 >= 0) & (y0 < sf), yin1 = (y0 + 1 >= 0) & (y0 + 1 < sf);
      if (xin0 & yin0) sv += w00 * bf2f(vb[(i64)(st + y0 * sf + x0) * 256]);
      if (xin1 & yin0) sv += w10 * bf2f(vb[(i64)(st + y0 * sf + x0 + 1) * 256]);
      if (xin0 & yin1) sv += w01 * bf2f(vb[(i64)(st + (y0 + 1) * sf + x0) * 256]);
      if (xin1 & yin1) sv += w11 * bf2f(vb[(i64)(st + (y0 + 1) * sf + x0 + 1) * 256]);
      acc = fmaf(a, sv, acc);
    }
  }
  out[(bt * 8 + h) * 32 + dh] = f2bf(acc);
}

// out[b][c][p] = feats[b][start+p][c]
__global__ __launch_bounds__(256) void untranspose_k(const float* __restrict__ feats,
    float* __restrict__ out, int start, int S, i64 ooff)
{
  __shared__ float tile[32][33];
  int pt = blockIdx.x * 32, ct = blockIdx.y * 32, b = blockIdx.z;
  int tx = threadIdx.x & 31, ty = threadIdx.x >> 5;
  for (int i = ty; i < 32; i += 8) {
    int p = pt + i;
    tile[i][tx] = (p < S) ? feats[((i64)b * NTOK + start + p) * 256 + ct + tx] : 0.f;
  }
  __syncthreads();
  for (int i = ty; i < 32; i += 8) {
    int c = ct + i, p = pt + tx;
    if (p < S) out[ooff + ((i64)b * 256 + c) * S + p] = tile[tx][i];
  }
}

extern "C" void kernel_launch(void* const* d_in, const int* in_sizes, int n_in,
                              void* d_out, int out_size, void* d_ws, size_t ws_size,
                              hipStream_t stream)
{
  const float* in0  = (const float*)d_in[0];
  const float* in1  = (const float*)d_in[1];
  const float* in2  = (const float*)d_in[2];
  const float* pw0  = (const float*)d_in[3];
  const float* pb0  = (const float*)d_in[4];
  const float* pw1  = (const float*)d_in[5];
  const float* pb1  = (const float*)d_in[6];
  const float* pw2  = (const float*)d_in[7];
  const float* pb2  = (const float*)d_in[8];
  const float* buw0 = (const float*)d_in[9];
  const float* bub0 = (const float*)d_in[10];
  const float* gng  = (const float*)d_in[11];
  const float* gnb  = (const float*)d_in[12];
  const float* buw1 = (const float*)d_in[13];
  const float* bub1 = (const float*)d_in[14];
  const float* ln1g = (const float*)d_in[15];
  const float* ln1b = (const float*)d_in[16];
  const float* woff = (const float*)d_in[17];
  const float* boff = (const float*)d_in[18];
  const float* watt = (const float*)d_in[19];
  const float* batt = (const float*)d_in[20];
  const float* wval = (const float*)d_in[21];
  const float* bval = (const float*)d_in[22];
  const float* wout = (const float*)d_in[23];
  const float* bout = (const float*)d_in[24];
  const float* ln2g = (const float*)d_in[25];
  const float* ln2b = (const float*)d_in[26];
  const float* w1   = (const float*)d_in[27];
  const float* b1   = (const float*)d_in[28];
  const float* w2   = (const float*)d_in[29];
  const float* b2   = (const float*)d_in[30];
  float* out = (float*)d_out;

  const i64 TC = (i64)NTOK * 256;  // 1,396,736

  // ---- ws layout (f32 units) ----
  float* ws    = (float*)d_ws;
  float* feats = ws;                               // 2,793,472 f32
  u16*   qb    = (u16*)(feats + 2793472);          // 11008x256 bf16
  u16*   valb  = qb + 2818048;
  u16*   sampb = valb + 2818048;
  float* offs  = (float*)(sampb + 2818048);        // U region: 5,636,096 f32
  float* att   = offs + 3491840;
  u16*   hb    = (u16*)offs;                       // overlays offs+att (after dsample)
  u16*   wb    = (u16*)(offs + 5636096);           // 11,141,120 bf16
  u16*   abuf  = wb + 11141120;                    // 4,194,304 bf16
  float* m4gn  = (float*)(abuf + 4194304);         // 32,768 f32
  float* part  = m4gn + 32768;                     // 524,288 f32

  auto mg = [&](dim3 grid, const u16* A, const u16* B, int K,
                float* C, u16* C16, i64 sCm, const float* bias, int relu, int addres,
                int M, int N, int Mb, i64 bCz, int KS, int Npad) {
    mgemm_k<<<grid, dim3(256), 0, stream>>>(A, B, K, C, C16, sCm, bias, relu, addres,
                                            M, N, Mb, bCz, KS, part, Npad);
  };

  // ---- weight conversion ----
  cvt_w_pro_k<<<dim3(24320), dim3(256), 0, stream>>>(pw0, pw1, pw2, buw0, buw1, wb);
  cvt_w_layer_k<<<dim3(3200, NLAYERS), dim3(256), 0, stream>>>(
      woff, watt, wval, wout, w1, w2, wb + 6225920);

  // ---- projections ----
  cvt_a_proj_k<<<dim3(16384), dim3(256), 0, stream>>>(in0, abuf, 4096, 512);
  mg(dim3(64, 2, 1), abuf, wb, 512, feats, nullptr, 256, pb0, 0, 0,
     8192, 256, 4096, TC, 1, 256);
  cvt_a_proj_k<<<dim3(8192), dim3(256), 0, stream>>>(in1, abuf, 1024, 1024);
  mg(dim3(16, 2, 1), abuf, wb + 131072, 1024, feats + (i64)4096 * 256, nullptr, 256,
     pb1, 0, 0, 2048, 256, 1024, TC, 1, 256);
  cvt_a_proj_k<<<dim3(4096), dim3(256), 0, stream>>>(in2, abuf, 256, 2048);
  mg(dim3(4, 2, 4), abuf, wb + 393216, 2048, nullptr, nullptr, 256, nullptr, 0, 0,
     512, 256, 256, 0, 4, 256);
  reduce_k<<<dim3(512), dim3(256), 0, stream>>>(part, feats + (i64)5120 * 256, pb2,
      256, TC, 256, 512, 256, 256, 4);

  // ---- bottom-up conv0: in2 (2048ch,16x16)->8x8 ----
  im2col_bf16_k<<<dim3(9216), dim3(256), 0, stream>>>(in2, abuf, 2048, 16, 16, 8, 8);
  mg(dim3(1, 2, 8), abuf, wb + 917504, 18432, nullptr, nullptr, 256, nullptr, 0, 0,
     128, 256, 64, 0, 8, 256);
  reduce_k<<<dim3(128), dim3(256), 0, stream>>>(part, feats + (i64)5376 * 256, bub0,
      64, TC, 256, 128, 256, 256, 8);

  // ---- GN+ReLU, bottom-up conv1: (256ch,8x8)->4x4 ----
  gn_relu_k<<<dim3(8, 2), dim3(256), 0, stream>>>(feats, m4gn, gng, gnb);
  im2col_bf16_k<<<dim3(288), dim3(256), 0, stream>>>(m4gn, abuf, 256, 8, 8, 4, 4);
  mg(dim3(1, 2, 4), abuf, wb + 5636096, 2304, nullptr, nullptr, 256, nullptr, 0, 0,
     32, 256, 16, 0, 4, 256);
  reduce_k<<<dim3(32), dim3(256), 0, stream>>>(part, feats + (i64)5440 * 256, bub1,
      16, TC, 256, 32, 256, 256, 4);

  // ---- 6 transformer layers ----
  for (int i = 0; i < NLAYERS; i++) {
    const u16* wbL = wb + 6225920 + (i64)i * 819200;
    ln_k<<<dim3(2728), dim3(256), 0, stream>>>(feats, qb,
        ln1g + (i64)i * 256, ln1b + (i64)i * 256, BNROWS);
    mg(dim3(86, 3, 1), qb, wbL, 256, offs, nullptr, 320, boff + (i64)i * 320, 0, 0,
       BNROWS, 320, BNROWS, 0, 1, 384);
    mg(dim3(86, 2, 1), qb, wbL + 98304, 256, att, nullptr, 160, batt + (i64)i * 160,
       0, 0, BNROWS, 160, BNROWS, 0, 1, 256);
    mg(dim3(86, 2, 1), qb, wbL + 163840, 256, nullptr, valb, 256, bval + (i64)i * 256,
       0, 0, BNROWS, 256, BNROWS, 0, 1, 256);
    softmax20_k<<<dim3((BNROWS * 8 + 255) / 256), dim3(256), 0, stream>>>(att, BNROWS * 8);
    dsample_k<<<dim3(NTOK, 2), dim3(256), 0, stream>>>(valb, offs, att, sampb);
    mg(dim3(86, 2, 1), sampb, wbL + 229376, 256, feats, nullptr, 256,
       bout + (i64)i * 256, 0, 1, BNROWS, 256, BNROWS, 0, 1, 256);
    ln_k<<<dim3(2728), dim3(256), 0, stream>>>(feats, qb,
        ln2g + (i64)i * 256, ln2b + (i64)i * 256, BNROWS);
    mg(dim3(86, 8, 1), qb, wbL + 294912, 256, nullptr, hb, 1024, b1 + (i64)i * 1024,
       1, 0, BNROWS, 1024, BNROWS, 0, 1, 1024);
    mg(dim3(86, 2, 1), hb, wbL + 557056, 1024, feats, nullptr, 256, b2 + (i64)i * 256,
       0, 1, BNROWS, 256, BNROWS, 0, 1, 256);
  }

  // ---- split into 5 level maps ----
  const int starts[5] = {0, 4096, 5120, 5376, 5440};
  const int fhs[5] = {64, 32, 16, 8, 4};
  i64 ooff = 0;
  for (int l = 0; l < 5; l++) {
    int S = fhs[l] * fhs[l];
    dim3 g((S + 31) / 32, 8, 2);
    untranspose_k<<<g, dim3(256), 0, stream>>>(feats, out, starts[l], S, ooff);
    ooff += (i64)2 * 256 * S;
  }
  (void)in_sizes; (void)n_in; (void)out_size; (void)ws_size;
}

// Round 4
// 1530.541 us; speedup vs baseline: 5.2396x; 1.5608x over previous
//
#include <hip/hip_runtime.h>
#include <cstdint>

typedef long long i64;
typedef unsigned short u16;
typedef __attribute__((ext_vector_type(8))) short short8;
typedef __attribute__((ext_vector_type(4))) float f32x4;

#define NTOK 5456
#define BNROWS 10912
#define NLAYERS 6

__device__ __forceinline__ u16 f2bf(float f) {
  unsigned u = __float_as_uint(f);
  return (u16)((u + 0x7FFFu + ((u >> 16) & 1u)) >> 16);
}
__device__ __forceinline__ float bf2f(u16 h) {
  return __uint_as_float(((unsigned)h) << 16);
}

// ---------------- bf16 MFMA GEMM, 2-phase double-buffered ----------------
// A: [rows>=ceil(M,128)][K] bf16 row-major. B: [N][K] bf16 (n-major).
// modes: KS>1 -> fp32 partials part[ks][M][N].
//        qkv  -> cols [0,320)->C f32 stride 320; [320,480)->C2 f32 stride 160;
//                [480,736)->C16 bf16 stride 256; bias always.
//        else -> C16 (bf16, bias/relu) or C f32 (bias/relu/addres),
//                row map: (row/Mb)*bCz + (row%Mb)*sCm.
template<int BNT>
__global__ __launch_bounds__(256) void mgemm_k(
    const u16* __restrict__ A, const u16* __restrict__ B, int K,
    float* __restrict__ C, float* __restrict__ C2, u16* __restrict__ C16, i64 sCm,
    const float* __restrict__ bias, int relu, int addres, int qkv,
    int M, int N, int Mb, i64 bCz,
    int KS, float* __restrict__ part)
{
  constexpr int NW = BNT / 32;      // N-frags per wave; also B staging rounds
  __shared__ u16 Asm[2][128 * 64];
  __shared__ u16 Bsm[2][BNT * 64];
  int tid = threadIdx.x;
  int m0 = blockIdx.x * 128, n0 = blockIdx.y * BNT;
  int ks = blockIdx.z;
  int Kc = K / KS;
  int k0 = ks * Kc;
  int lane = tid & 63, w = tid >> 6;
  int wr = w >> 1, wc = w & 1;
  int r16 = lane & 15, g = lane >> 4;

  f32x4 acc[4][NW];
#pragma unroll
  for (int mi = 0; mi < 4; mi++)
#pragma unroll
    for (int nj = 0; nj < NW; nj++) acc[mi][nj] = (f32x4){0.f, 0.f, 0.f, 0.f};

  const u16* Ag = A + (i64)m0 * K + k0;
  const u16* Bg = B + (i64)n0 * K + k0;
  int nt = Kc >> 6;

  auto stage = [&](int buf, int kt) {
    // A tile: 128x64 bf16 = 16 KiB = 4 rounds of (256 thr x 16B)
#pragma unroll
    for (int r = 0; r < 4; r++) {
      int s = r * 256 + tid;
      int row = s >> 3, c = s & 7;
      int cs = ((c ^ (row & 7)) << 3);
      __builtin_amdgcn_global_load_lds(
          (const __attribute__((address_space(1))) void*)(Ag + (i64)row * K + kt + cs),
          (__attribute__((address_space(3))) void*)(&Asm[buf][(r * 256 + (w << 6)) << 3]),
          16, 0, 0);
    }
    // B tile: BNTx64 bf16 = BNT*128 bytes = NW rounds (FIX: was NW/2)
#pragma unroll
    for (int r = 0; r < NW; r++) {
      int s = r * 256 + tid;
      int row = s >> 3, c = s & 7;
      int cs = ((c ^ (row & 7)) << 3);
      __builtin_amdgcn_global_load_lds(
          (const __attribute__((address_space(1))) void*)(Bg + (i64)row * K + kt + cs),
          (__attribute__((address_space(3))) void*)(&Bsm[buf][(r * 256 + (w << 6)) << 3]),
          16, 0, 0);
    }
  };

  stage(0, 0);
  __syncthreads();
  for (int t = 0; t < nt; t++) {
    int cur = t & 1;
    if (t + 1 < nt) stage(cur ^ 1, (t + 1) << 6);
#pragma unroll
    for (int h = 0; h < 2; h++) {
      short8 av[4], bv[NW];
#pragma unroll
      for (int mi = 0; mi < 4; mi++) {
        int row = wr * 64 + mi * 16 + r16;
        av[mi] = *(const short8*)&Asm[cur][row * 64 + ((((h << 2) + g) ^ (row & 7)) << 3)];
      }
#pragma unroll
      for (int nj = 0; nj < NW; nj++) {
        int row = wc * (NW * 16) + nj * 16 + r16;
        bv[nj] = *(const short8*)&Bsm[cur][row * 64 + ((((h << 2) + g) ^ (row & 7)) << 3)];
      }
#pragma unroll
      for (int mi = 0; mi < 4; mi++)
#pragma unroll
        for (int nj = 0; nj < NW; nj++)
          acc[mi][nj] = __builtin_amdgcn_mfma_f32_16x16x32_bf16(
              av[mi], bv[nj], acc[mi][nj], 0, 0, 0);
    }
    __syncthreads();
  }

  if (KS > 1) {
#pragma unroll
    for (int mi = 0; mi < 4; mi++)
#pragma unroll
      for (int nj = 0; nj < NW; nj++)
#pragma unroll
        for (int r = 0; r < 4; r++) {
          int grow = m0 + wr * 64 + mi * 16 + g * 4 + r;
          int gcol = n0 + wc * (NW * 16) + nj * 16 + r16;
          if (grow < M) part[((i64)ks * M + grow) * N + gcol] = acc[mi][nj][r];
        }
  } else if (qkv) {
#pragma unroll
    for (int mi = 0; mi < 4; mi++)
#pragma unroll
      for (int nj = 0; nj < NW; nj++)
#pragma unroll
        for (int r = 0; r < 4; r++) {
          int grow = m0 + wr * 64 + mi * 16 + g * 4 + r;
          int gcol = n0 + wc * (NW * 16) + nj * 16 + r16;
          if (grow < M) {
            float v = acc[mi][nj][r] + bias[gcol];
            if (gcol < 320) C[(i64)grow * 320 + gcol] = v;
            else if (gcol < 480) C2[(i64)grow * 160 + (gcol - 320)] = v;
            else if (gcol < 736) C16[(i64)grow * 256 + (gcol - 480)] = f2bf(v);
          }
        }
  } else {
#pragma unroll
    for (int mi = 0; mi < 4; mi++)
#pragma unroll
      for (int nj = 0; nj < NW; nj++)
#pragma unroll
        for (int r = 0; r < 4; r++) {
          int grow = m0 + wr * 64 + mi * 16 + g * 4 + r;
          int gcol = n0 + wc * (NW * 16) + nj * 16 + r16;
          if (grow < M && gcol < N) {
            float v = acc[mi][nj][r];
            if (bias) v += bias[gcol];
            if (relu) v = fmaxf(v, 0.f);
            i64 ci = (i64)(grow / Mb) * bCz + (i64)(grow % Mb) * sCm + gcol;
            if (C16) C16[ci] = f2bf(v);
            else {
              if (addres) v += C[ci];
              C[ci] = v;
            }
          }
        }
  }
}

// reduce split-K fp32 partials (stride N), row map like mgemm mode0
__global__ void reduce_k(const float* __restrict__ part, float* __restrict__ C,
    const float* __restrict__ bias, int Mb, i64 bCz, i64 sCm, int M, int N, int KS)
{
  int idx = blockIdx.x * 256 + threadIdx.x;
  if (idx >= M * N) return;
  int m = idx / N, n = idx - m * N;
  float v = bias ? bias[n] : 0.f;
  for (int ks = 0; ks < KS; ks++) v += part[((i64)ks * M + m) * N + n];
  C[(i64)(m / Mb) * bCz + (i64)(m % Mb) * sCm + n] = v;
}

// ---------------- weight conversions ----------------
__global__ void cvt_w_pro_k(const float* __restrict__ pw0, const float* __restrict__ pw1,
    const float* __restrict__ pw2, const float* __restrict__ buw0,
    const float* __restrict__ buw1, u16* __restrict__ dst)
{
  int idx = blockIdx.x * 256 + threadIdx.x;
  if (idx >= 6225920) return;
  float v;
  if (idx < 131072) v = pw0[idx];
  else if (idx < 393216) v = pw1[idx - 131072];
  else if (idx < 917504) v = pw2[idx - 393216];
  else if (idx < 5636096) v = buw0[idx - 917504];
  else v = buw1[idx - 5636096];
  dst[idx] = f2bf(v);
}

// per-layer: qkv [768][256] | wout [256][256] | w1 [1024][256] | w2 [256][1024]
__global__ void cvt_w_layer_k(const float* __restrict__ woff, const float* __restrict__ watt,
    const float* __restrict__ wval, const float* __restrict__ wout,
    const float* __restrict__ w1, const float* __restrict__ w2, u16* __restrict__ dst)
{
  int L = blockIdx.y;
  int o = blockIdx.x * 256 + threadIdx.x;
  if (o >= 786432) return;
  u16* d = dst + (i64)L * 786432;
  float v;
  if (o < 196608) {
    int n = o >> 8, k = o & 255;
    if (n < 320) v = woff[(i64)L * 81920 + k * 320 + n];
    else if (n < 480) v = watt[(i64)L * 40960 + k * 160 + (n - 320)];
    else if (n < 736) v = wval[(i64)L * 65536 + k * 256 + (n - 480)];
    else v = 0.f;
  } else if (o < 262144) {
    int o2 = o - 196608; int n = o2 >> 8, k = o2 & 255;
    v = wout[(i64)L * 65536 + k * 256 + n];
  } else if (o < 524288) {
    int o2 = o - 262144; int n = o2 >> 8, k = o2 & 255;
    v = w1[(i64)L * 262144 + (i64)k * 1024 + n];
  } else {
    int o2 = o - 524288; int n = o2 >> 10, k = o2 & 1023;
    v = w2[(i64)L * 262144 + (i64)k * 256 + n];
  }
  d[o] = f2bf(v);
}

// combined qkv bias [L][768] fp32
__global__ void cvt_bias_k(const float* __restrict__ boff, const float* __restrict__ batt,
    const float* __restrict__ bval, float* __restrict__ bq)
{
  int idx = blockIdx.x * 256 + threadIdx.x;
  if (idx >= NLAYERS * 768) return;
  int L = idx / 768, n = idx - L * 768;
  float v;
  if (n < 320) v = boff[(i64)L * 320 + n];
  else if (n < 480) v = batt[(i64)L * 160 + (n - 320)];
  else if (n < 736) v = bval[(i64)L * 256 + (n - 480)];
  else v = 0.f;
  bq[idx] = v;
}

// in_map [2][K][P] fp32 -> A [2*P][K] bf16
__global__ void cvt_a_proj_k(const float* __restrict__ in, u16* __restrict__ out,
                             int P, int K)
{
  i64 o = (i64)blockIdx.x * 256 + threadIdx.x;
  if (o >= (i64)2 * P * K) return;
  int m = (int)(o / K), k = (int)(o % K);
  int b = m / P, p = m - b * P;
  out[o] = f2bf(in[((i64)b * K + k) * P + p]);
}

// im2col 3x3 s2 p1 -> bf16 [2*Ho*Wo][Cin*9]
__global__ void im2col_bf16_k(const float* __restrict__ in, u16* __restrict__ out,
    int Cin, int Hin, int Win, int Ho, int Wo)
{
  int Kk = Cin * 9;
  i64 total = (i64)2 * Ho * Wo * Kk;
  i64 o = (i64)blockIdx.x * 256 + threadIdx.x;
  if (o >= total) return;
  int k = (int)(o % Kk);
  int m = (int)(o / Kk);
  int hw = Ho * Wo;
  int b = m / hw, pix = m - b * hw;
  int oy = pix / Wo, ox = pix - oy * Wo;
  int ci = k / 9, r = k - ci * 9;
  int ky = r / 3, kx = r - ky * 3;
  int iy = oy * 2 - 1 + ky, ix = ox * 2 - 1 + kx;
  float v = 0.f;
  if (iy >= 0 && iy < Hin && ix >= 0 && ix < Win)
    v = in[(((i64)b * Cin + ci) * Hin + iy) * Win + ix];
  out[o] = f2bf(v);
}

// GroupNorm(8)+ReLU over feats tokens [5376..5440) -> y [b][256][64] fp32
__global__ void gn_relu_k(const float* __restrict__ feats, float* __restrict__ y,
    const float* __restrict__ g, const float* __restrict__ bt)
{
  int grp = blockIdx.x, b = blockIdx.y;
  int tid = threadIdx.x;
  const float* fb = feats + ((i64)b * NTOK + 5376) * 256 + grp * 32;
  float s = 0.f, ss = 0.f;
  for (int i = tid; i < 2048; i += 256) {
    int cl = i >> 6, p = i & 63;
    float v = fb[(i64)p * 256 + cl];
    s += v; ss += v * v;
  }
  __shared__ float sb[4], ssb[4];
#pragma unroll
  for (int o = 32; o > 0; o >>= 1) { s += __shfl_down(s, o); ss += __shfl_down(ss, o); }
  int wv = tid >> 6;
  if ((tid & 63) == 0) { sb[wv] = s; ssb[wv] = ss; }
  __syncthreads();
  float ts = sb[0] + sb[1] + sb[2] + sb[3];
  float tss = ssb[0] + ssb[1] + ssb[2] + ssb[3];
  float mean = ts * (1.f / 2048.f);
  float rs = rsqrtf(tss * (1.f / 2048.f) - mean * mean + 1e-5f);
  for (int i = tid; i < 2048; i += 256) {
    int cl = i >> 6, p = i & 63;
    int c = grp * 32 + cl;
    float v = (fb[(i64)p * 256 + cl] - mean) * rs * g[c] + bt[c];
    y[((i64)b * 256 + c) * 64 + p] = fmaxf(v, 0.f);
  }
}

// LayerNorm rows of 256, fp32 in -> bf16 out
__global__ __launch_bounds__(256) void ln_k(const float* __restrict__ x,
    u16* __restrict__ y, const float* __restrict__ g, const float* __restrict__ bt,
    int rows)
{
  int row = blockIdx.x * 4 + (threadIdx.x >> 6);
  if (row >= rows) return;
  int lane = threadIdx.x & 63;
  float4 v = ((const float4*)(x + (i64)row * 256))[lane];
  float s = v.x + v.y + v.z + v.w;
  float ss = v.x * v.x + v.y * v.y + v.z * v.z + v.w * v.w;
#pragma unroll
  for (int o = 32; o > 0; o >>= 1) { s += __shfl_down(s, o); ss += __shfl_down(ss, o); }
  s = __shfl(s, 0);
  ss = __shfl(ss, 0);
  float mean = s * (1.f / 256.f);
  float rs = rsqrtf(ss * (1.f / 256.f) - mean * mean + 1e-5f);
  float4 gg = ((const float4*)g)[lane];
  float4 bb = ((const float4*)bt)[lane];
  ushort4 o4;
  o4.x = f2bf((v.x - mean) * rs * gg.x + bb.x);
  o4.y = f2bf((v.y - mean) * rs * gg.y + bb.y);
  o4.z = f2bf((v.z - mean) * rs * gg.z + bb.z);
  o4.w = f2bf((v.w - mean) * rs * gg.w + bb.w);
  ((ushort4*)(y + (i64)row * 256))[lane] = o4;
}

// deformable sampling + inline softmax(20):
// 1 wave per token; lane = (head h = lane>>3, 4-dh chunk d8 = lane&7)
__global__ __launch_bounds__(256) void dsample_k(
    const u16* __restrict__ val, const float* __restrict__ off,
    const float* __restrict__ att, u16* __restrict__ out)
{
  const int FH[5] = {64, 32, 16, 8, 4};
  const int ST[5] = {0, 4096, 5120, 5376, 5440};
  int t = blockIdx.x * 4 + (threadIdx.x >> 6);
  int b = blockIdx.y;
  int lane = threadIdx.x & 63;
  int h = lane >> 3, d8 = lane & 7;
  int lv, loc;
  if (t < 4096)      { lv = 0; loc = t; }
  else if (t < 5120) { lv = 1; loc = t - 4096; }
  else if (t < 5376) { lv = 2; loc = t - 5120; }
  else if (t < 5440) { lv = 3; loc = t - 5376; }
  else               { lv = 4; loc = t - 5440; }
  int fw0 = FH[lv];
  int py = loc / fw0, px = loc - py * fw0;
  float prx = (px + 0.5f) / fw0, pry = (py + 0.5f) / fw0;
  i64 bt = (i64)b * NTOK + t;
  const float* offp = off + bt * 320 + h * 40;
  const float* attp = att + bt * 160 + h * 20;
  const u16* vbase = val + ((i64)b * NTOK) * 256 + h * 32 + d8 * 4;

  // inline softmax over 20 logits (redundant per 8 lanes of a head; cheap)
  float e[20];
  float mx = attp[0];
#pragma unroll
  for (int i = 1; i < 20; i++) mx = fmaxf(mx, attp[i]);
  float sum = 0.f;
#pragma unroll
  for (int i = 0; i < 20; i++) { e[i] = __expf(attp[i] - mx); sum += e[i]; }
  float rinv = 1.f / sum;

  float a0 = 0.f, a1 = 0.f, a2 = 0.f, a3 = 0.f;
#pragma unroll
  for (int l = 0; l < 5; l++) {
    const int sf = FH[l], st = ST[l];
    const float sff = (float)sf;
#pragma unroll
    for (int p = 0; p < 4; p++) {
      float ox = offp[(l * 4 + p) * 2];
      float oy = offp[(l * 4 + p) * 2 + 1];
      float a = e[l * 4 + p] * rinv;
      float xx = prx * sff + ox - 0.5f;
      float yy = pry * sff + oy - 0.5f;
      float xf = floorf(xx), yf = floorf(yy);
      float fx = xx - xf, fy = yy - yf;
      int x0 = (int)xf, y0 = (int)yf;
      float w00 = (1.f - fx) * (1.f - fy);
      float w10 = fx * (1.f - fy);
      float w01 = (1.f - fx) * fy;
      float w11 = fx * fy;
      bool xin0 = (x0 >= 0) & (x0 < sf), xin1 = (x0 + 1 >= 0) & (x0 + 1 < sf);
      bool yin0 = (y0 >= 0) & (y0 < sf), yin1 = (y0 + 1 >= 0) & (y0 + 1 < sf);
      float s0 = 0.f, s1 = 0.f, s2 = 0.f, s3 = 0.f;
      if (xin0 & yin0) {
        ushort4 v = *(const ushort4*)(vbase + (i64)(st + y0 * sf + x0) * 256);
        s0 += w00 * bf2f(v.x); s1 += w00 * bf2f(v.y); s2 += w00 * bf2f(v.z); s3 += w00 * bf2f(v.w);
      }
      if (xin1 & yin0) {
        ushort4 v = *(const ushort4*)(vbase + (i64)(st + y0 * sf + x0 + 1) * 256);
        s0 += w10 * bf2f(v.x); s1 += w10 * bf2f(v.y); s2 += w10 * bf2f(v.z); s3 += w10 * bf2f(v.w);
      }
      if (xin0 & yin1) {
        ushort4 v = *(const ushort4*)(vbase + (i64)(st + (y0 + 1) * sf + x0) * 256);
        s0 += w01 * bf2f(v.x); s1 += w01 * bf2f(v.y); s2 += w01 * bf2f(v.z); s3 += w01 * bf2f(v.w);
      }
      if (xin1 & yin1) {
        ushort4 v = *(const ushort4*)(vbase + (i64)(st + (y0 + 1) * sf + x0 + 1) * 256);
        s0 += w11 * bf2f(v.x); s1 += w11 * bf2f(v.y); s2 += w11 * bf2f(v.z); s3 += w11 * bf2f(v.w);
      }
      a0 = fmaf(a, s0, a0); a1 = fmaf(a, s1, a1);
      a2 = fmaf(a, s2, a2); a3 = fmaf(a, s3, a3);
    }
  }
  ushort4 o;
  o.x = f2bf(a0); o.y = f2bf(a1); o.z = f2bf(a2); o.w = f2bf(a3);
  *(ushort4*)(out + ((bt * 8 + h) * 32 + d8 * 4)) = o;
}

// out[b][c][p] = feats[b][start+p][c]
__global__ __launch_bounds__(256) void untranspose_k(const float* __restrict__ feats,
    float* __restrict__ out, int start, int S, i64 ooff)
{
  __shared__ float tile[32][33];
  int pt = blockIdx.x * 32, ct = blockIdx.y * 32, b = blockIdx.z;
  int tx = threadIdx.x & 31, ty = threadIdx.x >> 5;
  for (int i = ty; i < 32; i += 8) {
    int p = pt + i;
    tile[i][tx] = (p < S) ? feats[((i64)b * NTOK + start + p) * 256 + ct + tx] : 0.f;
  }
  __syncthreads();
  for (int i = ty; i < 32; i += 8) {
    int c = ct + i, p = pt + tx;
    if (p < S) out[ooff + ((i64)b * 256 + c) * S + p] = tile[tx][i];
  }
}

extern "C" void kernel_launch(void* const* d_in, const int* in_sizes, int n_in,
                              void* d_out, int out_size, void* d_ws, size_t ws_size,
                              hipStream_t stream)
{
  const float* in0  = (const float*)d_in[0];
  const float* in1  = (const float*)d_in[1];
  const float* in2  = (const float*)d_in[2];
  const float* pw0  = (const float*)d_in[3];
  const float* pb0  = (const float*)d_in[4];
  const float* pw1  = (const float*)d_in[5];
  const float* pb1  = (const float*)d_in[6];
  const float* pw2  = (const float*)d_in[7];
  const float* pb2  = (const float*)d_in[8];
  const float* buw0 = (const float*)d_in[9];
  const float* bub0 = (const float*)d_in[10];
  const float* gng  = (const float*)d_in[11];
  const float* gnb  = (const float*)d_in[12];
  const float* buw1 = (const float*)d_in[13];
  const float* bub1 = (const float*)d_in[14];
  const float* ln1g = (const float*)d_in[15];
  const float* ln1b = (const float*)d_in[16];
  const float* woff = (const float*)d_in[17];
  const float* boff = (const float*)d_in[18];
  const float* watt = (const float*)d_in[19];
  const float* batt = (const float*)d_in[20];
  const float* wval = (const float*)d_in[21];
  const float* bval = (const float*)d_in[22];
  const float* wout = (const float*)d_in[23];
  const float* bout = (const float*)d_in[24];
  const float* ln2g = (const float*)d_in[25];
  const float* ln2b = (const float*)d_in[26];
  const float* w1   = (const float*)d_in[27];
  const float* b1   = (const float*)d_in[28];
  const float* w2   = (const float*)d_in[29];
  const float* b2   = (const float*)d_in[30];
  float* out = (float*)d_out;

  const i64 TC = (i64)NTOK * 256;

  // ---- ws layout (f32 units) ----
  float* ws    = (float*)d_ws;
  float* feats = ws;                               // 2,793,472
  u16*   qb    = (u16*)(feats + 2793472);          // 11008x256 bf16
  u16*   valb  = qb + 2818048;
  u16*   sampb = valb + 2818048;
  float* U     = (float*)(sampb + 2818048);        // union region: 5,637,120 f32
  float* offs  = U;                                // [10912][320] f32
  float* att   = U + 3491840;                      // [10912][160] f32
  u16*   hb    = (u16*)U;                          // [11008][1024] bf16 (FFN)
  u16*   abuf  = (u16*)U;                          // prologue A (<= 2,097,152 f32)
  float* part  = U + 2097152;                      // split-K partials (<=1,048,576)
  u16*   wb    = (u16*)(U + 5637120);              // 10,944,512 bf16
  float* bqkv  = (float*)(wb + 10944512);          // 4,608 f32
  float* m4gn  = bqkv + 4608;                      // 32,768 f32

  auto mg128 = [&](dim3 grid, const u16* A, const u16* B, int K,
                   float* C, float* C2, u16* C16, i64 sCm, const float* bias,
                   int relu, int addres, int qkv, int M, int N, int Mb, i64 bCz, int KS) {
    mgemm_k<128><<<grid, dim3(256), 0, stream>>>(A, B, K, C, C2, C16, sCm, bias,
        relu, addres, qkv, M, N, Mb, bCz, KS, part);
  };
  auto mg64 = [&](dim3 grid, const u16* A, const u16* B, int K,
                  float* C, u16* C16, i64 sCm, const float* bias,
                  int relu, int addres, int M, int N, int Mb, i64 bCz, int KS) {
    mgemm_k<64><<<grid, dim3(256), 0, stream>>>(A, B, K, C, nullptr, C16, sCm, bias,
        relu, addres, 0, M, N, Mb, bCz, KS, part);
  };

  // ---- weight conversion ----
  cvt_w_pro_k<<<dim3(24320), dim3(256), 0, stream>>>(pw0, pw1, pw2, buw0, buw1, wb);
  cvt_w_layer_k<<<dim3(3072, NLAYERS), dim3(256), 0, stream>>>(
      woff, watt, wval, wout, w1, w2, wb + 6225920);
  cvt_bias_k<<<dim3(18), dim3(256), 0, stream>>>(boff, batt, bval, bqkv);

  // ---- projections ----
  cvt_a_proj_k<<<dim3(16384), dim3(256), 0, stream>>>(in0, abuf, 4096, 512);
  mg64(dim3(64, 4, 1), abuf, wb, 512, feats, nullptr, 256, pb0, 0, 0,
       8192, 256, 4096, TC, 1);
  cvt_a_proj_k<<<dim3(8192), dim3(256), 0, stream>>>(in1, abuf, 1024, 1024);
  mg64(dim3(16, 4, 2), abuf, wb + 131072, 1024, nullptr, nullptr, 256, nullptr, 0, 0,
       2048, 256, 1024, 0, 2);
  reduce_k<<<dim3(2048), dim3(256), 0, stream>>>(part, feats + (i64)4096 * 256, pb1,
      1024, TC, 256, 2048, 256, 2);
  cvt_a_proj_k<<<dim3(4096), dim3(256), 0, stream>>>(in2, abuf, 256, 2048);
  mg64(dim3(4, 4, 4), abuf, wb + 393216, 2048, nullptr, nullptr, 256, nullptr, 0, 0,
       512, 256, 256, 0, 4);
  reduce_k<<<dim3(512), dim3(256), 0, stream>>>(part, feats + (i64)5120 * 256, pb2,
      256, TC, 256, 512, 256, 4);

  // ---- bottom-up conv0: in2 (2048ch,16x16)->8x8 ----
  im2col_bf16_k<<<dim3(9216), dim3(256), 0, stream>>>(in2, abuf, 2048, 16, 16, 8, 8);
  mg64(dim3(1, 4, 16), abuf, wb + 917504, 18432, nullptr, nullptr, 256, nullptr, 0, 0,
       128, 256, 64, 0, 16);
  reduce_k<<<dim3(128), dim3(256), 0, stream>>>(part, feats + (i64)5376 * 256, bub0,
      64, TC, 256, 128, 256, 16);

  // ---- GN+ReLU, bottom-up conv1: (256ch,8x8)->4x4 ----
  gn_relu_k<<<dim3(8, 2), dim3(256), 0, stream>>>(feats, m4gn, gng, gnb);
  im2col_bf16_k<<<dim3(288), dim3(256), 0, stream>>>(m4gn, abuf, 256, 8, 8, 4, 4);
  mg64(dim3(1, 4, 4), abuf, wb + 5636096, 2304, nullptr, nullptr, 256, nullptr, 0, 0,
       32, 256, 16, 0, 4);
  reduce_k<<<dim3(32), dim3(256), 0, stream>>>(part, feats + (i64)5440 * 256, bub1,
      16, TC, 256, 32, 256, 4);

  // ---- 6 transformer layers ----
  for (int i = 0; i < NLAYERS; i++) {
    const u16* wbL = wb + 6225920 + (i64)i * 786432;
    ln_k<<<dim3(2728), dim3(256), 0, stream>>>(feats, qb,
        ln1g + (i64)i * 256, ln1b + (i64)i * 256, BNROWS);
    // fused off|att|val GEMM, N=768
    mg128(dim3(86, 6, 1), qb, wbL, 256, offs, att, valb, 0, bqkv + (i64)i * 768,
          0, 0, 1, BNROWS, 768, BNROWS, 0, 1);
    // sampling (softmax fused)
    dsample_k<<<dim3(1364, 2), dim3(256), 0, stream>>>(valb, offs, att, sampb);
    // out proj + residual
    mg64(dim3(86, 4, 1), sampb, wbL + 196608, 256, feats, nullptr, 256,
         bout + (i64)i * 256, 0, 1, BNROWS, 256, BNROWS, 0, 1);
    ln_k<<<dim3(2728), dim3(256), 0, stream>>>(feats, qb,
        ln2g + (i64)i * 256, ln2b + (i64)i * 256, BNROWS);
    // FFN
    mg128(dim3(86, 8, 1), qb, wbL + 262144, 256, nullptr, nullptr, hb, 1024,
          b1 + (i64)i * 1024, 1, 0, 0, BNROWS, 1024, BNROWS, 0, 1);
    mg64(dim3(86, 4, 1), hb, wbL + 524288, 1024, feats, nullptr, 256,
         b2 + (i64)i * 256, 0, 1, BNROWS, 256, BNROWS, 0, 1);
  }

  // ---- split into 5 level maps ----
  const int starts[5] = {0, 4096, 5120, 5376, 5440};
  const int fhs[5] = {64, 32, 16, 8, 4};
  i64 ooff = 0;
  for (int l = 0; l < 5; l++) {
    int S = fhs[l] * fhs[l];
    dim3 g((S + 31) / 32, 8, 2);
    untranspose_k<<<g, dim3(256), 0, stream>>>(feats, out, starts[l], S, ooff);
    ooff += (i64)2 * 256 * S;
  }
  (void)in_sizes; (void)n_in; (void)out_size; (void)ws_size;
}

// Round 6
// 1347.662 us; speedup vs baseline: 5.9507x; 1.1357x over previous
//
#include <hip/hip_runtime.h>
#include <cstdint>

typedef long long i64;
typedef unsigned short u16;
typedef __attribute__((ext_vector_type(8))) short short8;
typedef __attribute__((ext_vector_type(4))) float f32x4;

#define NTOK 5456
#define BNROWS 10912
#define NLAYERS 6

__device__ __forceinline__ u16 f2bf(float f) {
  unsigned u = __float_as_uint(f);
  return (u16)((u + 0x7FFFu + ((u >> 16) & 1u)) >> 16);
}
__device__ __forceinline__ float bf2f(u16 h) {
  return __uint_as_float(((unsigned)h) << 16);
}

// ---------------- bf16 MFMA GEMM, 2-phase double-buffered ----------------
// A: [rows>=ceil(M,128)][K] bf16 row-major. B: [N][K] bf16 (n-major).
// modes: KS>1 -> fp32 partials part[ks][M][N].
//        qkv  -> cols [0,320)->C f32 stride 320; [320,480)->C2 f32 stride 160;
//                [480,736)->C16 bf16 stride 256; bias always.
//        else -> C16 (bf16, bias/relu) or C f32 (bias/relu/addres),
//                row map: (row/Mb)*bCz + (row%Mb)*sCm.
template<int BNT>
__global__ __launch_bounds__(256) void mgemm_k(
    const u16* __restrict__ A, const u16* __restrict__ B, int K,
    float* __restrict__ C, float* __restrict__ C2, u16* __restrict__ C16, i64 sCm,
    const float* __restrict__ bias, int relu, int addres, int qkv,
    int M, int N, int Mb, i64 bCz,
    int KS, float* __restrict__ part)
{
  constexpr int NW = BNT / 32;      // N-frags per wave; also B staging rounds
  __shared__ u16 Asm[2][128 * 64];
  __shared__ u16 Bsm[2][BNT * 64];
  int tid = threadIdx.x;
  int m0 = blockIdx.x * 128, n0 = blockIdx.y * BNT;
  int ks = blockIdx.z;
  int Kc = K / KS;
  int k0 = ks * Kc;
  int lane = tid & 63, w = tid >> 6;
  int wr = w >> 1, wc = w & 1;
  int r16 = lane & 15, g = lane >> 4;

  f32x4 acc[4][NW];
#pragma unroll
  for (int mi = 0; mi < 4; mi++)
#pragma unroll
    for (int nj = 0; nj < NW; nj++) acc[mi][nj] = (f32x4){0.f, 0.f, 0.f, 0.f};

  const u16* Ag = A + (i64)m0 * K + k0;
  const u16* Bg = B + (i64)n0 * K + k0;
  int nt = Kc >> 6;

  auto stage = [&](int buf, int kt) {
    // A tile: 128x64 bf16 = 16 KiB = 4 rounds of (256 thr x 16B)
#pragma unroll
    for (int r = 0; r < 4; r++) {
      int s = r * 256 + tid;
      int row = s >> 3, c = s & 7;
      int cs = ((c ^ (row & 7)) << 3);
      __builtin_amdgcn_global_load_lds(
          (const __attribute__((address_space(1))) void*)(Ag + (i64)row * K + kt + cs),
          (__attribute__((address_space(3))) void*)(&Asm[buf][(r * 256 + (w << 6)) << 3]),
          16, 0, 0);
    }
    // B tile: BNTx64 bf16 = BNT*128 bytes = NW rounds
#pragma unroll
    for (int r = 0; r < NW; r++) {
      int s = r * 256 + tid;
      int row = s >> 3, c = s & 7;
      int cs = ((c ^ (row & 7)) << 3);
      __builtin_amdgcn_global_load_lds(
          (const __attribute__((address_space(1))) void*)(Bg + (i64)row * K + kt + cs),
          (__attribute__((address_space(3))) void*)(&Bsm[buf][(r * 256 + (w << 6)) << 3]),
          16, 0, 0);
    }
  };

  stage(0, 0);
  __syncthreads();
  for (int t = 0; t < nt; t++) {
    int cur = t & 1;
    if (t + 1 < nt) stage(cur ^ 1, (t + 1) << 6);
#pragma unroll
    for (int h = 0; h < 2; h++) {
      short8 av[4], bv[NW];
#pragma unroll
      for (int mi = 0; mi < 4; mi++) {
        int row = wr * 64 + mi * 16 + r16;
        av[mi] = *(const short8*)&Asm[cur][row * 64 + ((((h << 2) + g) ^ (row & 7)) << 3)];
      }
#pragma unroll
      for (int nj = 0; nj < NW; nj++) {
        int row = wc * (NW * 16) + nj * 16 + r16;
        bv[nj] = *(const short8*)&Bsm[cur][row * 64 + ((((h << 2) + g) ^ (row & 7)) << 3)];
      }
#pragma unroll
      for (int mi = 0; mi < 4; mi++)
#pragma unroll
        for (int nj = 0; nj < NW; nj++)
          acc[mi][nj] = __builtin_amdgcn_mfma_f32_16x16x32_bf16(
              av[mi], bv[nj], acc[mi][nj], 0, 0, 0);
    }
    __syncthreads();
  }

  if (KS > 1) {
#pragma unroll
    for (int mi = 0; mi < 4; mi++)
#pragma unroll
      for (int nj = 0; nj < NW; nj++)
#pragma unroll
        for (int r = 0; r < 4; r++) {
          int grow = m0 + wr * 64 + mi * 16 + g * 4 + r;
          int gcol = n0 + wc * (NW * 16) + nj * 16 + r16;
          if (grow < M) part[((i64)ks * M + grow) * N + gcol] = acc[mi][nj][r];
        }
  } else if (qkv) {
#pragma unroll
    for (int mi = 0; mi < 4; mi++)
#pragma unroll
      for (int nj = 0; nj < NW; nj++)
#pragma unroll
        for (int r = 0; r < 4; r++) {
          int grow = m0 + wr * 64 + mi * 16 + g * 4 + r;
          int gcol = n0 + wc * (NW * 16) + nj * 16 + r16;
          if (grow < M) {
            float v = acc[mi][nj][r] + bias[gcol];
            if (gcol < 320) C[(i64)grow * 320 + gcol] = v;
            else if (gcol < 480) C2[(i64)grow * 160 + (gcol - 320)] = v;
            else if (gcol < 736) C16[(i64)grow * 256 + (gcol - 480)] = f2bf(v);
          }
        }
  } else {
#pragma unroll
    for (int mi = 0; mi < 4; mi++)
#pragma unroll
      for (int nj = 0; nj < NW; nj++)
#pragma unroll
        for (int r = 0; r < 4; r++) {
          int grow = m0 + wr * 64 + mi * 16 + g * 4 + r;
          int gcol = n0 + wc * (NW * 16) + nj * 16 + r16;
          if (grow < M && gcol < N) {
            float v = acc[mi][nj][r];
            if (bias) v += bias[gcol];
            if (relu) v = fmaxf(v, 0.f);
            i64 ci = (i64)(grow / Mb) * bCz + (i64)(grow % Mb) * sCm + gcol;
            if (C16) C16[ci] = f2bf(v);
            else {
              if (addres) v += C[ci];
              C[ci] = v;
            }
          }
        }
  }
}

// reduce split-K fp32 partials (stride N), row map like mgemm mode0
__global__ void reduce_k(const float* __restrict__ part, float* __restrict__ C,
    const float* __restrict__ bias, int Mb, i64 bCz, i64 sCm, int M, int N, int KS)
{
  int idx = blockIdx.x * 256 + threadIdx.x;
  if (idx >= M * N) return;
  int m = idx / N, n = idx - m * N;
  float v = bias ? bias[n] : 0.f;
  for (int ks = 0; ks < KS; ks++) v += part[((i64)ks * M + m) * N + n];
  C[(i64)(m / Mb) * bCz + (i64)(m % Mb) * sCm + n] = v;
}

// ---------------- weight conversions ----------------
__global__ void cvt_w_pro_k(const float* __restrict__ pw0, const float* __restrict__ pw1,
    const float* __restrict__ pw2, const float* __restrict__ buw0,
    const float* __restrict__ buw1, u16* __restrict__ dst)
{
  int idx = blockIdx.x * 256 + threadIdx.x;
  if (idx >= 6225920) return;
  float v;
  if (idx < 131072) v = pw0[idx];
  else if (idx < 393216) v = pw1[idx - 131072];
  else if (idx < 917504) v = pw2[idx - 393216];
  else if (idx < 5636096) v = buw0[idx - 917504];
  else v = buw1[idx - 5636096];
  dst[idx] = f2bf(v);
}

// per-layer: qkv [768][256] | wout [256][256] | w1 [1024][256] | w2 [256][1024]
__global__ void cvt_w_layer_k(const float* __restrict__ woff, const float* __restrict__ watt,
    const float* __restrict__ wval, const float* __restrict__ wout,
    const float* __restrict__ w1, const float* __restrict__ w2, u16* __restrict__ dst)
{
  int L = blockIdx.y;
  int o = blockIdx.x * 256 + threadIdx.x;
  if (o >= 786432) return;
  u16* d = dst + (i64)L * 786432;
  float v;
  if (o < 196608) {
    int n = o >> 8, k = o & 255;
    if (n < 320) v = woff[(i64)L * 81920 + k * 320 + n];
    else if (n < 480) v = watt[(i64)L * 40960 + k * 160 + (n - 320)];
    else if (n < 736) v = wval[(i64)L * 65536 + k * 256 + (n - 480)];
    else v = 0.f;
  } else if (o < 262144) {
    int o2 = o - 196608; int n = o2 >> 8, k = o2 & 255;
    v = wout[(i64)L * 65536 + k * 256 + n];
  } else if (o < 524288) {
    int o2 = o - 262144; int n = o2 >> 8, k = o2 & 255;
    v = w1[(i64)L * 262144 + (i64)k * 1024 + n];
  } else {
    int o2 = o - 524288; int n = o2 >> 10, k = o2 & 1023;
    v = w2[(i64)L * 262144 + (i64)k * 256 + n];
  }
  d[o] = f2bf(v);
}

// combined qkv bias [L][768] fp32
__global__ void cvt_bias_k(const float* __restrict__ boff, const float* __restrict__ batt,
    const float* __restrict__ bval, float* __restrict__ bq)
{
  int idx = blockIdx.x * 256 + threadIdx.x;
  if (idx >= NLAYERS * 768) return;
  int L = idx / 768, n = idx - L * 768;
  float v;
  if (n < 320) v = boff[(i64)L * 320 + n];
  else if (n < 480) v = batt[(i64)L * 160 + (n - 320)];
  else if (n < 736) v = bval[(i64)L * 256 + (n - 480)];
  else v = 0.f;
  bq[idx] = v;
}

// in_map [2][K][P] fp32 -> A [2*P][K] bf16
__global__ void cvt_a_proj_k(const float* __restrict__ in, u16* __restrict__ out,
                             int P, int K)
{
  i64 o = (i64)blockIdx.x * 256 + threadIdx.x;
  if (o >= (i64)2 * P * K) return;
  int m = (int)(o / K), k = (int)(o % K);
  int b = m / P, p = m - b * P;
  out[o] = f2bf(in[((i64)b * K + k) * P + p]);
}

// im2col 3x3 s2 p1 -> bf16 [2*Ho*Wo][Cin*9]
__global__ void im2col_bf16_k(const float* __restrict__ in, u16* __restrict__ out,
    int Cin, int Hin, int Win, int Ho, int Wo)
{
  int Kk = Cin * 9;
  i64 total = (i64)2 * Ho * Wo * Kk;
  i64 o = (i64)blockIdx.x * 256 + threadIdx.x;
  if (o >= total) return;
  int k = (int)(o % Kk);
  int m = (int)(o / Kk);
  int hw = Ho * Wo;
  int b = m / hw, pix = m - b * hw;
  int oy = pix / Wo, ox = pix - oy * Wo;
  int ci = k / 9, r = k - ci * 9;
  int ky = r / 3, kx = r - ky * 3;
  int iy = oy * 2 - 1 + ky, ix = ox * 2 - 1 + kx;
  float v = 0.f;
  if (iy >= 0 && iy < Hin && ix >= 0 && ix < Win)
    v = in[(((i64)b * Cin + ci) * Hin + iy) * Win + ix];
  out[o] = f2bf(v);
}

// GroupNorm(8)+ReLU over feats tokens [5376..5440) -> y [b][256][64] fp32
__global__ void gn_relu_k(const float* __restrict__ feats, float* __restrict__ y,
    const float* __restrict__ g, const float* __restrict__ bt)
{
  int grp = blockIdx.x, b = blockIdx.y;
  int tid = threadIdx.x;
  const float* fb = feats + ((i64)b * NTOK + 5376) * 256 + grp * 32;
  float s = 0.f, ss = 0.f;
  for (int i = tid; i < 2048; i += 256) {
    int cl = i >> 6, p = i & 63;
    float v = fb[(i64)p * 256 + cl];
    s += v; ss += v * v;
  }
  __shared__ float sb[4], ssb[4];
#pragma unroll
  for (int o = 32; o > 0; o >>= 1) { s += __shfl_down(s, o); ss += __shfl_down(ss, o); }
  int wv = tid >> 6;
  if ((tid & 63) == 0) { sb[wv] = s; ssb[wv] = ss; }
  __syncthreads();
  float ts = sb[0] + sb[1] + sb[2] + sb[3];
  float tss = ssb[0] + ssb[1] + ssb[2] + ssb[3];
  float mean = ts * (1.f / 2048.f);
  float rs = rsqrtf(tss * (1.f / 2048.f) - mean * mean + 1e-5f);
  for (int i = tid; i < 2048; i += 256) {
    int cl = i >> 6, p = i & 63;
    int c = grp * 32 + cl;
    float v = (fb[(i64)p * 256 + cl] - mean) * rs * g[c] + bt[c];
    y[((i64)b * 256 + c) * 64 + p] = fmaxf(v, 0.f);
  }
}

// LayerNorm rows of 256, fp32 in -> bf16 out
__global__ __launch_bounds__(256) void ln_k(const float* __restrict__ x,
    u16* __restrict__ y, const float* __restrict__ g, const float* __restrict__ bt,
    int rows)
{
  int row = blockIdx.x * 4 + (threadIdx.x >> 6);
  if (row >= rows) return;
  int lane = threadIdx.x & 63;
  float4 v = ((const float4*)(x + (i64)row * 256))[lane];
  float s = v.x + v.y + v.z + v.w;
  float ss = v.x * v.x + v.y * v.y + v.z * v.z + v.w * v.w;
#pragma unroll
  for (int o = 32; o > 0; o >>= 1) { s += __shfl_down(s, o); ss += __shfl_down(ss, o); }
  s = __shfl(s, 0);
  ss = __shfl(ss, 0);
  float mean = s * (1.f / 256.f);
  float rs = rsqrtf(ss * (1.f / 256.f) - mean * mean + 1e-5f);
  float4 gg = ((const float4*)g)[lane];
  float4 bb = ((const float4*)bt)[lane];
  ushort4 o4;
  o4.x = f2bf((v.x - mean) * rs * gg.x + bb.x);
  o4.y = f2bf((v.y - mean) * rs * gg.y + bb.y);
  o4.z = f2bf((v.z - mean) * rs * gg.z + bb.z);
  o4.w = f2bf((v.w - mean) * rs * gg.w + bb.w);
  ((ushort4*)(y + (i64)row * 256))[lane] = o4;
}

// deformable sampling v3: owner-lane params + shfl broadcast, XCD-local swizzle.
// grid (1368, 2); 1 wave per token; lane = (head h = lane>>3, owner slot d8 = lane&7)
__global__ __launch_bounds__(256) void dsample_k(
    const u16* __restrict__ val, const float* __restrict__ off,
    const float* __restrict__ att, u16* __restrict__ out)
{
  const int FH[5] = {64, 32, 16, 8, 4};
  const int ST[5] = {0, 4096, 5120, 5376, 5440};
  // XCD-locality: xcd = bid%8 (dispatch round-robin); give each XCD a
  // contiguous chunk range so its val working set fits the 4MB XCD L2.
  int bid = blockIdx.x;
  int chunk = (bid & 7) * 171 + (bid >> 3);
  if (chunk >= 1364) return;
  int t = chunk * 4 + (threadIdx.x >> 6);
  int b = blockIdx.y;
  int lane = threadIdx.x & 63;
  int h = lane >> 3, d8 = lane & 7;

  int lv, loc;
  if (t < 4096)      { lv = 0; loc = t; }
  else if (t < 5120) { lv = 1; loc = t - 4096; }
  else if (t < 5376) { lv = 2; loc = t - 5120; }
  else if (t < 5440) { lv = 3; loc = t - 5376; }
  else               { lv = 4; loc = t - 5440; }
  int fw0 = FH[lv];
  int py = loc / fw0, px = loc - py * fw0;
  float prx = (px + 0.5f) / fw0, pry = (py + 0.5f) / fw0;
  i64 bt = (i64)b * NTOK + t;
  const float* offp = off + bt * 320 + h * 40;
  const float* attp = att + bt * 160 + h * 20;
  const u16* vbase = val + ((i64)b * NTOK) * 256 + h * 32 + d8 * 4;

  // ---- owner phase: points p = d8 + 8j ----
  float own_a[3], own_fx[3], own_fy[3];
  int own_pk[3];
  float mx = -1e30f;
#pragma unroll
  for (int j = 0; j < 3; j++) {
    int p = d8 + 8 * j;
    float lg = (p < 20) ? attp[p] : -1e30f;
    own_a[j] = lg;
    mx = fmaxf(mx, lg);
  }
  mx = fmaxf(mx, __shfl_xor(mx, 1));
  mx = fmaxf(mx, __shfl_xor(mx, 2));
  mx = fmaxf(mx, __shfl_xor(mx, 4));
  float sum = 0.f;
#pragma unroll
  for (int j = 0; j < 3; j++) {
    int p = d8 + 8 * j;
    float e = (p < 20) ? __expf(own_a[j] - mx) : 0.f;
    own_a[j] = e;
    sum += e;
  }
  sum += __shfl_xor(sum, 1);
  sum += __shfl_xor(sum, 2);
  sum += __shfl_xor(sum, 4);
  float rinv = 1.f / sum;
#pragma unroll
  for (int j = 0; j < 3; j++) {
    int p = d8 + 8 * j;
    own_a[j] *= rinv;
    float ox = 0.f, oy = 0.f;
    if (p < 20) { ox = offp[2 * p]; oy = offp[2 * p + 1]; }
    float sff = (float)(64 >> (p >> 2));
    float xx = prx * sff + ox - 0.5f;
    float yy = pry * sff + oy - 0.5f;
    float xf = floorf(xx), yf = floorf(yy);
    own_fx[j] = xx - xf;
    own_fy[j] = yy - yf;
    own_pk[j] = (((int)yf) << 16) | (((int)xf) & 0xFFFF);
  }

  // ---- gather phase ----
  float a0 = 0.f, a1 = 0.f, a2 = 0.f, a3 = 0.f;
#pragma unroll
  for (int p = 0; p < 20; p++) {
    const int l = p >> 2;
    const int sf = FH[l], st = ST[l];
    const int j = p >> 3;
    int src = (h << 3) | (p & 7);
    float wa = __shfl(own_a[j], src);
    float fx = __shfl(own_fx[j], src);
    float fy = __shfl(own_fy[j], src);
    int pk = __shfl(own_pk[j], src);
    int x0 = (pk << 16) >> 16;
    int y0 = pk >> 16;
    float gx0 = wa - wa * fx, gx1 = wa * fx;
    float w00 = gx0 - gx0 * fy, w01 = gx0 * fy;
    float w10 = gx1 - gx1 * fy, w11 = gx1 * fy;
    bool xin0 = (x0 >= 0) & (x0 < sf), xin1 = (x0 + 1 >= 0) & (x0 + 1 < sf);
    bool yin0 = (y0 >= 0) & (y0 < sf), yin1 = (y0 + 1 >= 0) & (y0 + 1 < sf);
    int ibase = st + y0 * sf + x0;
    if (xin0 & yin0) {
      ushort4 v = *(const ushort4*)(vbase + (i64)ibase * 256);
      a0 = fmaf(w00, bf2f(v.x), a0); a1 = fmaf(w00, bf2f(v.y), a1);
      a2 = fmaf(w00, bf2f(v.z), a2); a3 = fmaf(w00, bf2f(v.w), a3);
    }
    if (xin1 & yin0) {
      ushort4 v = *(const ushort4*)(vbase + (i64)(ibase + 1) * 256);
      a0 = fmaf(w10, bf2f(v.x), a0); a1 = fmaf(w10, bf2f(v.y), a1);
      a2 = fmaf(w10, bf2f(v.z), a2); a3 = fmaf(w10, bf2f(v.w), a3);
    }
    if (xin0 & yin1) {
      ushort4 v = *(const ushort4*)(vbase + (i64)(ibase + sf) * 256);
      a0 = fmaf(w01, bf2f(v.x), a0); a1 = fmaf(w01, bf2f(v.y), a1);
      a2 = fmaf(w01, bf2f(v.z), a2); a3 = fmaf(w01, bf2f(v.w), a3);
    }
    if (xin1 & yin1) {
      ushort4 v = *(const ushort4*)(vbase + (i64)(ibase + sf + 1) * 256);
      a0 = fmaf(w11, bf2f(v.x), a0); a1 = fmaf(w11, bf2f(v.y), a1);
      a2 = fmaf(w11, bf2f(v.z), a2); a3 = fmaf(w11, bf2f(v.w), a3);
    }
  }
  ushort4 o;
  o.x = f2bf(a0); o.y = f2bf(a1); o.z = f2bf(a2); o.w = f2bf(a3);
  *(ushort4*)(out + ((bt * 8 + h) * 32 + d8 * 4)) = o;
}

// all 5 levels in one dispatch: out[b][c][p] = feats[b][start+p][c]
// grid.x = 171: lvl0 u<128 (128 tiles), lvl1 u<160 (32), lvl2 u<168 (8),
// lvl3 u<170 (2 tiles, S=64), lvl4 u=170 (1 tile, S=16)
__global__ __launch_bounds__(256) void untranspose_all_k(
    const float* __restrict__ feats, float* __restrict__ out)
{
  int u = blockIdx.x;
  int pt0, start, S; i64 ooff;
  if (u < 128)      { pt0 = u;       start = 0;    S = 4096; ooff = 0; }
  else if (u < 160) { pt0 = u - 128; start = 4096; S = 1024; ooff = 2097152; }
  else if (u < 168) { pt0 = u - 160; start = 5120; S = 256;  ooff = 2621440; }
  else if (u < 170) { pt0 = u - 168; start = 5376; S = 64;   ooff = 2752512; }
  else              { pt0 = 0;       start = 5440; S = 16;   ooff = 2785280; }
  __shared__ float tile[32][33];
  int pt = pt0 * 32, ct = blockIdx.y * 32, b = blockIdx.z;
  int tx = threadIdx.x & 31, ty = threadIdx.x >> 5;
  for (int i = ty; i < 32; i += 8) {
    int p = pt + i;
    tile[i][tx] = (p < S) ? feats[((i64)b * NTOK + start + p) * 256 + ct + tx] : 0.f;
  }
  __syncthreads();
  for (int i = ty; i < 32; i += 8) {
    int c = ct + i, p = pt + tx;
    if (p < S) out[ooff + ((i64)b * 256 + c) * S + p] = tile[tx][i];
  }
}

extern "C" void kernel_launch(void* const* d_in, const int* in_sizes, int n_in,
                              void* d_out, int out_size, void* d_ws, size_t ws_size,
                              hipStream_t stream)
{
  const float* in0  = (const float*)d_in[0];
  const float* in1  = (const float*)d_in[1];
  const float* in2  = (const float*)d_in[2];
  const float* pw0  = (const float*)d_in[3];
  const float* pb0  = (const float*)d_in[4];
  const float* pw1  = (const float*)d_in[5];
  const float* pb1  = (const float*)d_in[6];
  const float* pw2  = (const float*)d_in[7];
  const float* pb2  = (const float*)d_in[8];
  const float* buw0 = (const float*)d_in[9];
  const float* bub0 = (const float*)d_in[10];
  const float* gng  = (const float*)d_in[11];
  const float* gnb  = (const float*)d_in[12];
  const float* buw1 = (const float*)d_in[13];
  const float* bub1 = (const float*)d_in[14];
  const float* ln1g = (const float*)d_in[15];
  const float* ln1b = (const float*)d_in[16];
  const float* woff = (const float*)d_in[17];
  const float* boff = (const float*)d_in[18];
  const float* watt = (const float*)d_in[19];
  const float* batt = (const float*)d_in[20];
  const float* wval = (const float*)d_in[21];
  const float* bval = (const float*)d_in[22];
  const float* wout = (const float*)d_in[23];
  const float* bout = (const float*)d_in[24];
  const float* ln2g = (const float*)d_in[25];
  const float* ln2b = (const float*)d_in[26];
  const float* w1   = (const float*)d_in[27];
  const float* b1   = (const float*)d_in[28];
  const float* w2   = (const float*)d_in[29];
  const float* b2   = (const float*)d_in[30];
  float* out = (float*)d_out;

  const i64 TC = (i64)NTOK * 256;

  // ---- ws layout (f32 units) ----
  float* ws    = (float*)d_ws;
  float* feats = ws;                               // 2,793,472
  u16*   qb    = (u16*)(feats + 2793472);          // 11008x256 bf16
  u16*   valb  = qb + 2818048;
  u16*   sampb = valb + 2818048;
  float* U     = (float*)(sampb + 2818048);        // union region: 5,637,120 f32
  float* offs  = U;                                // [10912][320] f32
  float* att   = U + 3491840;                      // [10912][160] f32
  u16*   hb    = (u16*)U;                          // [11008][1024] bf16 (FFN)
  u16*   abuf  = (u16*)U;                          // prologue A (<= 2,097,152 f32)
  float* part  = U + 2097152;                      // split-K partials (<=1,048,576)
  u16*   wb    = (u16*)(U + 5637120);              // 10,944,512 bf16
  float* bqkv  = (float*)(wb + 10944512);          // 4,608 f32
  float* m4gn  = bqkv + 4608;                      // 32,768 f32

  auto mg128 = [&](dim3 grid, const u16* A, const u16* B, int K,
                   float* C, float* C2, u16* C16, i64 sCm, const float* bias,
                   int relu, int addres, int qkv, int M, int N, int Mb, i64 bCz, int KS) {
    mgemm_k<128><<<grid, dim3(256), 0, stream>>>(A, B, K, C, C2, C16, sCm, bias,
        relu, addres, qkv, M, N, Mb, bCz, KS, part);
  };
  auto mg64 = [&](dim3 grid, const u16* A, const u16* B, int K,
                  float* C, u16* C16, i64 sCm, const float* bias,
                  int relu, int addres, int M, int N, int Mb, i64 bCz, int KS) {
    mgemm_k<64><<<grid, dim3(256), 0, stream>>>(A, B, K, C, nullptr, C16, sCm, bias,
        relu, addres, 0, M, N, Mb, bCz, KS, part);
  };

  // ---- weight conversion ----
  cvt_w_pro_k<<<dim3(24320), dim3(256), 0, stream>>>(pw0, pw1, pw2, buw0, buw1, wb);
  cvt_w_layer_k<<<dim3(3072, NLAYERS), dim3(256), 0, stream>>>(
      woff, watt, wval, wout, w1, w2, wb + 6225920);
  cvt_bias_k<<<dim3(18), dim3(256), 0, stream>>>(boff, batt, bval, bqkv);

  // ---- projections ----
  cvt_a_proj_k<<<dim3(16384), dim3(256), 0, stream>>>(in0, abuf, 4096, 512);
  mg64(dim3(64, 4, 1), abuf, wb, 512, feats, nullptr, 256, pb0, 0, 0,
       8192, 256, 4096, TC, 1);
  cvt_a_proj_k<<<dim3(8192), dim3(256), 0, stream>>>(in1, abuf, 1024, 1024);
  mg64(dim3(16, 4, 2), abuf, wb + 131072, 1024, nullptr, nullptr, 256, nullptr, 0, 0,
       2048, 256, 1024, 0, 2);
  reduce_k<<<dim3(2048), dim3(256), 0, stream>>>(part, feats + (i64)4096 * 256, pb1,
      1024, TC, 256, 2048, 256, 2);
  cvt_a_proj_k<<<dim3(4096), dim3(256), 0, stream>>>(in2, abuf, 256, 2048);
  mg64(dim3(4, 4, 4), abuf, wb + 393216, 2048, nullptr, nullptr, 256, nullptr, 0, 0,
       512, 256, 256, 0, 4);
  reduce_k<<<dim3(512), dim3(256), 0, stream>>>(part, feats + (i64)5120 * 256, pb2,
      256, TC, 256, 512, 256, 4);

  // ---- bottom-up conv0: in2 (2048ch,16x16)->8x8 ----
  im2col_bf16_k<<<dim3(9216), dim3(256), 0, stream>>>(in2, abuf, 2048, 16, 16, 8, 8);
  mg64(dim3(1, 4, 16), abuf, wb + 917504, 18432, nullptr, nullptr, 256, nullptr, 0, 0,
       128, 256, 64, 0, 16);
  reduce_k<<<dim3(128), dim3(256), 0, stream>>>(part, feats + (i64)5376 * 256, bub0,
      64, TC, 256, 128, 256, 16);

  // ---- GN+ReLU, bottom-up conv1: (256ch,8x8)->4x4 ----
  gn_relu_k<<<dim3(8, 2), dim3(256), 0, stream>>>(feats, m4gn, gng, gnb);
  im2col_bf16_k<<<dim3(288), dim3(256), 0, stream>>>(m4gn, abuf, 256, 8, 8, 4, 4);
  mg64(dim3(1, 4, 4), abuf, wb + 5636096, 2304, nullptr, nullptr, 256, nullptr, 0, 0,
       32, 256, 16, 0, 4);
  reduce_k<<<dim3(32), dim3(256), 0, stream>>>(part, feats + (i64)5440 * 256, bub1,
      16, TC, 256, 32, 256, 4);

  // ---- 6 transformer layers ----
  for (int i = 0; i < NLAYERS; i++) {
    const u16* wbL = wb + 6225920 + (i64)i * 786432;
    ln_k<<<dim3(2728), dim3(256), 0, stream>>>(feats, qb,
        ln1g + (i64)i * 256, ln1b + (i64)i * 256, BNROWS);
    // fused off|att|val GEMM, N=768
    mg128(dim3(86, 6, 1), qb, wbL, 256, offs, att, valb, 0, bqkv + (i64)i * 768,
          0, 0, 1, BNROWS, 768, BNROWS, 0, 1);
    // sampling (softmax fused), XCD-swizzled
    dsample_k<<<dim3(1368, 2), dim3(256), 0, stream>>>(valb, offs, att, sampb);
    // out proj + residual
    mg64(dim3(86, 4, 1), sampb, wbL + 196608, 256, feats, nullptr, 256,
         bout + (i64)i * 256, 0, 1, BNROWS, 256, BNROWS, 0, 1);
    ln_k<<<dim3(2728), dim3(256), 0, stream>>>(feats, qb,
        ln2g + (i64)i * 256, ln2b + (i64)i * 256, BNROWS);
    // FFN
    mg128(dim3(86, 8, 1), qb, wbL + 262144, 256, nullptr, nullptr, hb, 1024,
          b1 + (i64)i * 1024, 1, 0, 0, BNROWS, 1024, BNROWS, 0, 1);
    mg64(dim3(86, 4, 1), hb, wbL + 524288, 1024, feats, nullptr, 256,
         b2 + (i64)i * 256, 0, 1, BNROWS, 256, BNROWS, 0, 1);
  }

  // ---- split into 5 level maps (one dispatch) ----
  untranspose_all_k<<<dim3(171, 8, 2), dim3(256), 0, stream>>>(feats, out);
  (void)in_sizes; (void)n_in; (void)out_size; (void)ws_size;
}

// Round 7
// 1256.236 us; speedup vs baseline: 6.3837x; 1.0728x over previous
//
#include <hip/hip_runtime.h>
#include <cstdint>

typedef long long i64;
typedef unsigned short u16;
typedef __attribute__((ext_vector_type(8))) short short8;
typedef __attribute__((ext_vector_type(8))) unsigned short us8;
typedef __attribute__((ext_vector_type(4))) float f32x4;

#define NTOK 5456
#define BNROWS 10912
#define NLAYERS 6

__device__ __forceinline__ u16 f2bf(float f) {
  unsigned u = __float_as_uint(f);
  return (u16)((u + 0x7FFFu + ((u >> 16) & 1u)) >> 16);
}
__device__ __forceinline__ float bf2f(u16 h) {
  return __uint_as_float(((unsigned)h) << 16);
}

// ---------------- bf16 MFMA GEMM, 2-phase double-buffered ----------------
// A: [rows>=ceil(M,128)][K] bf16 row-major. B: [N][K] bf16 (n-major).
// modes: KS>1 -> fp32 partials part[ks][M][N].
//        qkv  -> cols [0,320)->(u16*)C bf16 stride 320; [320,480)->(u16*)C2
//                bf16 stride 160; [480,736)->C16 bf16 stride 256; bias always.
//        else -> C16 (bf16, bias/relu) or C f32 (bias/relu/addres),
//                row map: (row/Mb)*bCz + (row%Mb)*sCm.
template<int BNT>
__global__ __launch_bounds__(256) void mgemm_k(
    const u16* __restrict__ A, const u16* __restrict__ B, int K,
    float* __restrict__ C, float* __restrict__ C2, u16* __restrict__ C16, i64 sCm,
    const float* __restrict__ bias, int relu, int addres, int qkv,
    int M, int N, int Mb, i64 bCz,
    int KS, float* __restrict__ part)
{
  constexpr int NW = BNT / 32;      // N-frags per wave; also B staging rounds
  __shared__ u16 Asm[2][128 * 64];
  __shared__ u16 Bsm[2][BNT * 64];
  int tid = threadIdx.x;
  int m0 = blockIdx.x * 128, n0 = blockIdx.y * BNT;
  int ks = blockIdx.z;
  int Kc = K / KS;
  int k0 = ks * Kc;
  int lane = tid & 63, w = tid >> 6;
  int wr = w >> 1, wc = w & 1;
  int r16 = lane & 15, g = lane >> 4;

  f32x4 acc[4][NW];
#pragma unroll
  for (int mi = 0; mi < 4; mi++)
#pragma unroll
    for (int nj = 0; nj < NW; nj++) acc[mi][nj] = (f32x4){0.f, 0.f, 0.f, 0.f};

  const u16* Ag = A + (i64)m0 * K + k0;
  const u16* Bg = B + (i64)n0 * K + k0;
  int nt = Kc >> 6;

  auto stage = [&](int buf, int kt) {
    // A tile: 128x64 bf16 = 16 KiB = 4 rounds of (256 thr x 16B)
#pragma unroll
    for (int r = 0; r < 4; r++) {
      int s = r * 256 + tid;
      int row = s >> 3, c = s & 7;
      int cs = ((c ^ (row & 7)) << 3);
      __builtin_amdgcn_global_load_lds(
          (const __attribute__((address_space(1))) void*)(Ag + (i64)row * K + kt + cs),
          (__attribute__((address_space(3))) void*)(&Asm[buf][(r * 256 + (w << 6)) << 3]),
          16, 0, 0);
    }
    // B tile: BNTx64 bf16 = BNT*128 bytes = NW rounds
#pragma unroll
    for (int r = 0; r < NW; r++) {
      int s = r * 256 + tid;
      int row = s >> 3, c = s & 7;
      int cs = ((c ^ (row & 7)) << 3);
      __builtin_amdgcn_global_load_lds(
          (const __attribute__((address_space(1))) void*)(Bg + (i64)row * K + kt + cs),
          (__attribute__((address_space(3))) void*)(&Bsm[buf][(r * 256 + (w << 6)) << 3]),
          16, 0, 0);
    }
  };

  stage(0, 0);
  __syncthreads();
  for (int t = 0; t < nt; t++) {
    int cur = t & 1;
    if (t + 1 < nt) stage(cur ^ 1, (t + 1) << 6);
#pragma unroll
    for (int h = 0; h < 2; h++) {
      short8 av[4], bv[NW];
#pragma unroll
      for (int mi = 0; mi < 4; mi++) {
        int row = wr * 64 + mi * 16 + r16;
        av[mi] = *(const short8*)&Asm[cur][row * 64 + ((((h << 2) + g) ^ (row & 7)) << 3)];
      }
#pragma unroll
      for (int nj = 0; nj < NW; nj++) {
        int row = wc * (NW * 16) + nj * 16 + r16;
        bv[nj] = *(const short8*)&Bsm[cur][row * 64 + ((((h << 2) + g) ^ (row & 7)) << 3)];
      }
#pragma unroll
      for (int mi = 0; mi < 4; mi++)
#pragma unroll
        for (int nj = 0; nj < NW; nj++)
          acc[mi][nj] = __builtin_amdgcn_mfma_f32_16x16x32_bf16(
              av[mi], bv[nj], acc[mi][nj], 0, 0, 0);
    }
    __syncthreads();
  }

  if (KS > 1) {
#pragma unroll
    for (int mi = 0; mi < 4; mi++)
#pragma unroll
      for (int nj = 0; nj < NW; nj++)
#pragma unroll
        for (int r = 0; r < 4; r++) {
          int grow = m0 + wr * 64 + mi * 16 + g * 4 + r;
          int gcol = n0 + wc * (NW * 16) + nj * 16 + r16;
          if (grow < M) part[((i64)ks * M + grow) * N + gcol] = acc[mi][nj][r];
        }
  } else if (qkv) {
    u16* off16 = (u16*)C;
    u16* att16 = (u16*)C2;
#pragma unroll
    for (int mi = 0; mi < 4; mi++)
#pragma unroll
      for (int nj = 0; nj < NW; nj++)
#pragma unroll
        for (int r = 0; r < 4; r++) {
          int grow = m0 + wr * 64 + mi * 16 + g * 4 + r;
          int gcol = n0 + wc * (NW * 16) + nj * 16 + r16;
          if (grow < M) {
            float v = acc[mi][nj][r] + bias[gcol];
            if (gcol < 320) off16[(i64)grow * 320 + gcol] = f2bf(v);
            else if (gcol < 480) att16[(i64)grow * 160 + (gcol - 320)] = f2bf(v);
            else if (gcol < 736) C16[(i64)grow * 256 + (gcol - 480)] = f2bf(v);
          }
        }
  } else {
#pragma unroll
    for (int mi = 0; mi < 4; mi++)
#pragma unroll
      for (int nj = 0; nj < NW; nj++)
#pragma unroll
        for (int r = 0; r < 4; r++) {
          int grow = m0 + wr * 64 + mi * 16 + g * 4 + r;
          int gcol = n0 + wc * (NW * 16) + nj * 16 + r16;
          if (grow < M && gcol < N) {
            float v = acc[mi][nj][r];
            if (bias) v += bias[gcol];
            if (relu) v = fmaxf(v, 0.f);
            i64 ci = (i64)(grow / Mb) * bCz + (i64)(grow % Mb) * sCm + gcol;
            if (C16) C16[ci] = f2bf(v);
            else {
              if (addres) v += C[ci];
              C[ci] = v;
            }
          }
        }
  }
}

// reduce split-K fp32 partials (stride N), row map like mgemm mode0
__global__ void reduce_k(const float* __restrict__ part, float* __restrict__ C,
    const float* __restrict__ bias, int Mb, i64 bCz, i64 sCm, int M, int N, int KS)
{
  int idx = blockIdx.x * 256 + threadIdx.x;
  if (idx >= M * N) return;
  int m = idx / N, n = idx - m * N;
  float v = bias ? bias[n] : 0.f;
  for (int ks = 0; ks < KS; ks++) v += part[((i64)ks * M + m) * N + n];
  C[(i64)(m / Mb) * bCz + (i64)(m % Mb) * sCm + n] = v;
}

// ---------------- weight conversions ----------------
__global__ void cvt_w_pro_k(const float* __restrict__ pw0, const float* __restrict__ pw1,
    const float* __restrict__ pw2, const float* __restrict__ buw0,
    const float* __restrict__ buw1, u16* __restrict__ dst)
{
  int idx = blockIdx.x * 256 + threadIdx.x;
  if (idx >= 6225920) return;
  float v;
  if (idx < 131072) v = pw0[idx];
  else if (idx < 393216) v = pw1[idx - 131072];
  else if (idx < 917504) v = pw2[idx - 393216];
  else if (idx < 5636096) v = buw0[idx - 917504];
  else v = buw1[idx - 5636096];
  dst[idx] = f2bf(v);
}

// per-layer: qkv [768][256] | wout [256][256] | w1 [1024][256] | w2 [256][1024]
__global__ void cvt_w_layer_k(const float* __restrict__ woff, const float* __restrict__ watt,
    const float* __restrict__ wval, const float* __restrict__ wout,
    const float* __restrict__ w1, const float* __restrict__ w2, u16* __restrict__ dst)
{
  int L = blockIdx.y;
  int o = blockIdx.x * 256 + threadIdx.x;
  if (o >= 786432) return;
  u16* d = dst + (i64)L * 786432;
  float v;
  if (o < 196608) {
    int n = o >> 8, k = o & 255;
    if (n < 320) v = woff[(i64)L * 81920 + k * 320 + n];
    else if (n < 480) v = watt[(i64)L * 40960 + k * 160 + (n - 320)];
    else if (n < 736) v = wval[(i64)L * 65536 + k * 256 + (n - 480)];
    else v = 0.f;
  } else if (o < 262144) {
    int o2 = o - 196608; int n = o2 >> 8, k = o2 & 255;
    v = wout[(i64)L * 65536 + k * 256 + n];
  } else if (o < 524288) {
    int o2 = o - 262144; int n = o2 >> 8, k = o2 & 255;
    v = w1[(i64)L * 262144 + (i64)k * 1024 + n];
  } else {
    int o2 = o - 524288; int n = o2 >> 10, k = o2 & 1023;
    v = w2[(i64)L * 262144 + (i64)k * 256 + n];
  }
  d[o] = f2bf(v);
}

// combined qkv bias [L][768] fp32
__global__ void cvt_bias_k(const float* __restrict__ boff, const float* __restrict__ batt,
    const float* __restrict__ bval, float* __restrict__ bq)
{
  int idx = blockIdx.x * 256 + threadIdx.x;
  if (idx >= NLAYERS * 768) return;
  int L = idx / 768, n = idx - L * 768;
  float v;
  if (n < 320) v = boff[(i64)L * 320 + n];
  else if (n < 480) v = batt[(i64)L * 160 + (n - 320)];
  else if (n < 736) v = bval[(i64)L * 256 + (n - 480)];
  else v = 0.f;
  bq[idx] = v;
}

// in_map [2][K][P] fp32 -> A [2*P][K] bf16
__global__ void cvt_a_proj_k(const float* __restrict__ in, u16* __restrict__ out,
                             int P, int K)
{
  i64 o = (i64)blockIdx.x * 256 + threadIdx.x;
  if (o >= (i64)2 * P * K) return;
  int m = (int)(o / K), k = (int)(o % K);
  int b = m / P, p = m - b * P;
  out[o] = f2bf(in[((i64)b * K + k) * P + p]);
}

// im2col 3x3 s2 p1 -> bf16 [2*Ho*Wo][Cin*9]
__global__ void im2col_bf16_k(const float* __restrict__ in, u16* __restrict__ out,
    int Cin, int Hin, int Win, int Ho, int Wo)
{
  int Kk = Cin * 9;
  i64 total = (i64)2 * Ho * Wo * Kk;
  i64 o = (i64)blockIdx.x * 256 + threadIdx.x;
  if (o >= total) return;
  int k = (int)(o % Kk);
  int m = (int)(o / Kk);
  int hw = Ho * Wo;
  int b = m / hw, pix = m - b * hw;
  int oy = pix / Wo, ox = pix - oy * Wo;
  int ci = k / 9, r = k - ci * 9;
  int ky = r / 3, kx = r - ky * 3;
  int iy = oy * 2 - 1 + ky, ix = ox * 2 - 1 + kx;
  float v = 0.f;
  if (iy >= 0 && iy < Hin && ix >= 0 && ix < Win)
    v = in[(((i64)b * Cin + ci) * Hin + iy) * Win + ix];
  out[o] = f2bf(v);
}

// GroupNorm(8)+ReLU over feats tokens [5376..5440) -> y [b][256][64] fp32
__global__ void gn_relu_k(const float* __restrict__ feats, float* __restrict__ y,
    const float* __restrict__ g, const float* __restrict__ bt)
{
  int grp = blockIdx.x, b = blockIdx.y;
  int tid = threadIdx.x;
  const float* fb = feats + ((i64)b * NTOK + 5376) * 256 + grp * 32;
  float s = 0.f, ss = 0.f;
  for (int i = tid; i < 2048; i += 256) {
    int cl = i >> 6, p = i & 63;
    float v = fb[(i64)p * 256 + cl];
    s += v; ss += v * v;
  }
  __shared__ float sb[4], ssb[4];
#pragma unroll
  for (int o = 32; o > 0; o >>= 1) { s += __shfl_down(s, o); ss += __shfl_down(ss, o); }
  int wv = tid >> 6;
  if ((tid & 63) == 0) { sb[wv] = s; ssb[wv] = ss; }
  __syncthreads();
  float ts = sb[0] + sb[1] + sb[2] + sb[3];
  float tss = ssb[0] + ssb[1] + ssb[2] + ssb[3];
  float mean = ts * (1.f / 2048.f);
  float rs = rsqrtf(tss * (1.f / 2048.f) - mean * mean + 1e-5f);
  for (int i = tid; i < 2048; i += 256) {
    int cl = i >> 6, p = i & 63;
    int c = grp * 32 + cl;
    float v = (fb[(i64)p * 256 + cl] - mean) * rs * g[c] + bt[c];
    y[((i64)b * 256 + c) * 64 + p] = fmaxf(v, 0.f);
  }
}

// LayerNorm rows of 256, fp32 in -> bf16 out
__global__ __launch_bounds__(256) void ln_k(const float* __restrict__ x,
    u16* __restrict__ y, const float* __restrict__ g, const float* __restrict__ bt,
    int rows)
{
  int row = blockIdx.x * 4 + (threadIdx.x >> 6);
  if (row >= rows) return;
  int lane = threadIdx.x & 63;
  float4 v = ((const float4*)(x + (i64)row * 256))[lane];
  float s = v.x + v.y + v.z + v.w;
  float ss = v.x * v.x + v.y * v.y + v.z * v.z + v.w * v.w;
#pragma unroll
  for (int o = 32; o > 0; o >>= 1) { s += __shfl_down(s, o); ss += __shfl_down(ss, o); }
  s = __shfl(s, 0);
  ss = __shfl(ss, 0);
  float mean = s * (1.f / 256.f);
  float rs = rsqrtf(ss * (1.f / 256.f) - mean * mean + 1e-5f);
  float4 gg = ((const float4*)g)[lane];
  float4 bb = ((const float4*)bt)[lane];
  ushort4 o4;
  o4.x = f2bf((v.x - mean) * rs * gg.x + bb.x);
  o4.y = f2bf((v.y - mean) * rs * gg.y + bb.y);
  o4.z = f2bf((v.z - mean) * rs * gg.z + bb.z);
  o4.w = f2bf((v.w - mean) * rs * gg.w + bb.w);
  ((ushort4*)(y + (i64)row * 256))[lane] = o4;
}

// deformable sampling v5: 32 lanes/token (8 heads x 4 dh-chunks of 8),
// owner-lane softmax/params (4 owners x 5 points, level == owner slot j),
// ushort8 16B gathers, bf16 off/att inputs, XCD-contiguous chunk swizzle.
// grid (688, 2): chunk = (bid&7)*86 + bid>>3, 8 tokens per block.
__global__ __launch_bounds__(256) void dsample_k(
    const u16* __restrict__ val, const u16* __restrict__ off,
    const u16* __restrict__ att, u16* __restrict__ out)
{
  const int FH[5] = {64, 32, 16, 8, 4};
  const int ST[5] = {0, 4096, 5120, 5376, 5440};
  int bid = blockIdx.x;
  int chunk = (bid & 7) * 86 + (bid >> 3);
  if (chunk >= 682) return;
  int lane = threadIdx.x & 63;
  int half = lane >> 5;
  int l32 = lane & 31;
  int t = chunk * 8 + ((threadIdx.x >> 6) << 1) + half;
  int b = blockIdx.y;
  int h = l32 >> 2, d4 = l32 & 3;

  int lv;
  if (t < 4096)      lv = 0;
  else if (t < 5120) lv = 1;
  else if (t < 5376) lv = 2;
  else if (t < 5440) lv = 3;
  else               lv = 4;
  int loc = t - ST[lv];
  int sh = 6 - lv;
  int py = loc >> sh, px = loc - (py << sh);
  float inv = 1.f / (float)FH[lv];
  float prx = (px + 0.5f) * inv, pry = (py + 0.5f) * inv;
  i64 bt = (i64)b * NTOK + t;
  const u16* offp = off + bt * 320 + h * 40;
  const u16* attp = att + bt * 160 + h * 20;
  const u16* vbase = val + ((i64)b * NTOK) * 256 + h * 32 + d4 * 8;

  // ---- owner phase: lane d4 owns points p = d4 + 4j (level j), j=0..4 ----
  float own_a[5], own_fx[5], own_fy[5];
  int own_pk[5];
  float mx = -1e30f;
#pragma unroll
  for (int j = 0; j < 5; j++) {
    float lg = bf2f(attp[d4 + 4 * j]);
    own_a[j] = lg;
    mx = fmaxf(mx, lg);
  }
  mx = fmaxf(mx, __shfl_xor(mx, 1));
  mx = fmaxf(mx, __shfl_xor(mx, 2));
  float sum = 0.f;
#pragma unroll
  for (int j = 0; j < 5; j++) {
    float e = __expf(own_a[j] - mx);
    own_a[j] = e;
    sum += e;
  }
  sum += __shfl_xor(sum, 1);
  sum += __shfl_xor(sum, 2);
  float rinv = 1.f / sum;
#pragma unroll
  for (int j = 0; j < 5; j++) {
    int p = d4 + 4 * j;
    own_a[j] *= rinv;
    unsigned opk = *(const unsigned*)(offp + 2 * p);
    float ox = bf2f((u16)(opk & 0xFFFF));
    float oy = bf2f((u16)(opk >> 16));
    float sff = (float)(64 >> j);
    float xx = prx * sff + ox - 0.5f;
    float yy = pry * sff + oy - 0.5f;
    float xf = floorf(xx), yf = floorf(yy);
    own_fx[j] = xx - xf;
    own_fy[j] = yy - yf;
    own_pk[j] = (((int)yf) << 16) | (((int)xf) & 0xFFFF);
  }

  // ---- gather phase: 8 dh per lane, 16B loads ----
  float acc[8] = {0.f, 0.f, 0.f, 0.f, 0.f, 0.f, 0.f, 0.f};
#pragma unroll
  for (int p = 0; p < 20; p++) {
    const int j = p >> 2;               // level == owner slot
    const int sf = FH[j], st = ST[j];
    int src = (half << 5) | (h << 2) | (p & 3);
    float wa = __shfl(own_a[j], src);
    float fx = __shfl(own_fx[j], src);
    float fy = __shfl(own_fy[j], src);
    int pk = __shfl(own_pk[j], src);
    int x0 = (pk << 16) >> 16;
    int y0 = pk >> 16;
    float gx0 = wa - wa * fx, gx1 = wa * fx;
    float w00 = gx0 - gx0 * fy, w01 = gx0 * fy;
    float w10 = gx1 - gx1 * fy, w11 = gx1 * fy;
    bool xin0 = (x0 >= 0) & (x0 < sf), xin1 = (x0 + 1 >= 0) & (x0 + 1 < sf);
    bool yin0 = (y0 >= 0) & (y0 < sf), yin1 = (y0 + 1 >= 0) & (y0 + 1 < sf);
    int ibase = st + y0 * sf + x0;
#define FMA8(W, IDX) { \
      us8 v = *(const us8*)(vbase + (i64)(IDX) * 256); \
      acc[0] = fmaf(W, bf2f(v[0]), acc[0]); acc[1] = fmaf(W, bf2f(v[1]), acc[1]); \
      acc[2] = fmaf(W, bf2f(v[2]), acc[2]); acc[3] = fmaf(W, bf2f(v[3]), acc[3]); \
      acc[4] = fmaf(W, bf2f(v[4]), acc[4]); acc[5] = fmaf(W, bf2f(v[5]), acc[5]); \
      acc[6] = fmaf(W, bf2f(v[6]), acc[6]); acc[7] = fmaf(W, bf2f(v[7]), acc[7]); }
    if (xin0 & yin0) FMA8(w00, ibase);
    if (xin1 & yin0) FMA8(w10, ibase + 1);
    if (xin0 & yin1) FMA8(w01, ibase + sf);
    if (xin1 & yin1) FMA8(w11, ibase + sf + 1);
#undef FMA8
  }
  us8 o;
#pragma unroll
  for (int i = 0; i < 8; i++) o[i] = f2bf(acc[i]);
  *(us8*)(out + ((bt * 8 + h) * 32 + d4 * 8)) = o;
}

// all 5 levels in one dispatch: out[b][c][p] = feats[b][start+p][c]
// grid.x = 171: lvl0 u<128, lvl1 u<160, lvl2 u<168, lvl3 u<170 (S=64), lvl4 u=170
__global__ __launch_bounds__(256) void untranspose_all_k(
    const float* __restrict__ feats, float* __restrict__ out)
{
  int u = blockIdx.x;
  int pt0, start, S; i64 ooff;
  if (u < 128)      { pt0 = u;       start = 0;    S = 4096; ooff = 0; }
  else if (u < 160) { pt0 = u - 128; start = 4096; S = 1024; ooff = 2097152; }
  else if (u < 168) { pt0 = u - 160; start = 5120; S = 256;  ooff = 2621440; }
  else if (u < 170) { pt0 = u - 168; start = 5376; S = 64;   ooff = 2752512; }
  else              { pt0 = 0;       start = 5440; S = 16;   ooff = 2785280; }
  __shared__ float tile[32][33];
  int pt = pt0 * 32, ct = blockIdx.y * 32, b = blockIdx.z;
  int tx = threadIdx.x & 31, ty = threadIdx.x >> 5;
  for (int i = ty; i < 32; i += 8) {
    int p = pt + i;
    tile[i][tx] = (p < S) ? feats[((i64)b * NTOK + start + p) * 256 + ct + tx] : 0.f;
  }
  __syncthreads();
  for (int i = ty; i < 32; i += 8) {
    int c = ct + i, p = pt + tx;
    if (p < S) out[ooff + ((i64)b * 256 + c) * S + p] = tile[tx][i];
  }
}

extern "C" void kernel_launch(void* const* d_in, const int* in_sizes, int n_in,
                              void* d_out, int out_size, void* d_ws, size_t ws_size,
                              hipStream_t stream)
{
  const float* in0  = (const float*)d_in[0];
  const float* in1  = (const float*)d_in[1];
  const float* in2  = (const float*)d_in[2];
  const float* pw0  = (const float*)d_in[3];
  const float* pb0  = (const float*)d_in[4];
  const float* pw1  = (const float*)d_in[5];
  const float* pb1  = (const float*)d_in[6];
  const float* pw2  = (const float*)d_in[7];
  const float* pb2  = (const float*)d_in[8];
  const float* buw0 = (const float*)d_in[9];
  const float* bub0 = (const float*)d_in[10];
  const float* gng  = (const float*)d_in[11];
  const float* gnb  = (const float*)d_in[12];
  const float* buw1 = (const float*)d_in[13];
  const float* bub1 = (const float*)d_in[14];
  const float* ln1g = (const float*)d_in[15];
  const float* ln1b = (const float*)d_in[16];
  const float* woff = (const float*)d_in[17];
  const float* boff = (const float*)d_in[18];
  const float* watt = (const float*)d_in[19];
  const float* batt = (const float*)d_in[20];
  const float* wval = (const float*)d_in[21];
  const float* bval = (const float*)d_in[22];
  const float* wout = (const float*)d_in[23];
  const float* bout = (const float*)d_in[24];
  const float* ln2g = (const float*)d_in[25];
  const float* ln2b = (const float*)d_in[26];
  const float* w1   = (const float*)d_in[27];
  const float* b1   = (const float*)d_in[28];
  const float* w2   = (const float*)d_in[29];
  const float* b2   = (const float*)d_in[30];
  float* out = (float*)d_out;

  const i64 TC = (i64)NTOK * 256;

  // ---- ws layout (f32 units) ----
  float* ws    = (float*)d_ws;
  float* feats = ws;                               // 2,793,472
  u16*   qb    = (u16*)(feats + 2793472);          // 11008x256 bf16
  u16*   valb  = qb + 2818048;
  u16*   sampb = valb + 2818048;
  float* U     = (float*)(sampb + 2818048);        // union region: 5,637,120 f32
  u16*   off16 = (u16*)U;                          // [10912][320] bf16
  u16*   att16 = off16 + 3491840;                  // [10912][160] bf16
  u16*   hb    = (u16*)U;                          // [11008][1024] bf16 (FFN)
  u16*   abuf  = (u16*)U;                          // prologue A
  float* part  = U + 2097152;                      // split-K partials
  u16*   wb    = (u16*)(U + 5637120);              // 10,944,512 bf16
  float* bqkv  = (float*)(wb + 10944512);          // 4,608 f32
  float* m4gn  = bqkv + 4608;                      // 32,768 f32

  auto mg128 = [&](dim3 grid, const u16* A, const u16* B, int K,
                   float* C, float* C2, u16* C16, i64 sCm, const float* bias,
                   int relu, int addres, int qkv, int M, int N, int Mb, i64 bCz, int KS) {
    mgemm_k<128><<<grid, dim3(256), 0, stream>>>(A, B, K, C, C2, C16, sCm, bias,
        relu, addres, qkv, M, N, Mb, bCz, KS, part);
  };
  auto mg64 = [&](dim3 grid, const u16* A, const u16* B, int K,
                  float* C, u16* C16, i64 sCm, const float* bias,
                  int relu, int addres, int M, int N, int Mb, i64 bCz, int KS) {
    mgemm_k<64><<<grid, dim3(256), 0, stream>>>(A, B, K, C, nullptr, C16, sCm, bias,
        relu, addres, 0, M, N, Mb, bCz, KS, part);
  };

  // ---- weight conversion ----
  cvt_w_pro_k<<<dim3(24320), dim3(256), 0, stream>>>(pw0, pw1, pw2, buw0, buw1, wb);
  cvt_w_layer_k<<<dim3(3072, NLAYERS), dim3(256), 0, stream>>>(
      woff, watt, wval, wout, w1, w2, wb + 6225920);
  cvt_bias_k<<<dim3(18), dim3(256), 0, stream>>>(boff, batt, bval, bqkv);

  // ---- projections ----
  cvt_a_proj_k<<<dim3(16384), dim3(256), 0, stream>>>(in0, abuf, 4096, 512);
  mg64(dim3(64, 4, 1), abuf, wb, 512, feats, nullptr, 256, pb0, 0, 0,
       8192, 256, 4096, TC, 1);
  cvt_a_proj_k<<<dim3(8192), dim3(256), 0, stream>>>(in1, abuf, 1024, 1024);
  mg64(dim3(16, 4, 2), abuf, wb + 131072, 1024, nullptr, nullptr, 256, nullptr, 0, 0,
       2048, 256, 1024, 0, 2);
  reduce_k<<<dim3(2048), dim3(256), 0, stream>>>(part, feats + (i64)4096 * 256, pb1,
      1024, TC, 256, 2048, 256, 2);
  cvt_a_proj_k<<<dim3(4096), dim3(256), 0, stream>>>(in2, abuf, 256, 2048);
  mg64(dim3(4, 4, 4), abuf, wb + 393216, 2048, nullptr, nullptr, 256, nullptr, 0, 0,
       512, 256, 256, 0, 4);
  reduce_k<<<dim3(512), dim3(256), 0, stream>>>(part, feats + (i64)5120 * 256, pb2,
      256, TC, 256, 512, 256, 4);

  // ---- bottom-up conv0: in2 (2048ch,16x16)->8x8 ----
  im2col_bf16_k<<<dim3(9216), dim3(256), 0, stream>>>(in2, abuf, 2048, 16, 16, 8, 8);
  mg64(dim3(1, 4, 16), abuf, wb + 917504, 18432, nullptr, nullptr, 256, nullptr, 0, 0,
       128, 256, 64, 0, 16);
  reduce_k<<<dim3(128), dim3(256), 0, stream>>>(part, feats + (i64)5376 * 256, bub0,
      64, TC, 256, 128, 256, 16);

  // ---- GN+ReLU, bottom-up conv1: (256ch,8x8)->4x4 ----
  gn_relu_k<<<dim3(8, 2), dim3(256), 0, stream>>>(feats, m4gn, gng, gnb);
  im2col_bf16_k<<<dim3(288), dim3(256), 0, stream>>>(m4gn, abuf, 256, 8, 8, 4, 4);
  mg64(dim3(1, 4, 4), abuf, wb + 5636096, 2304, nullptr, nullptr, 256, nullptr, 0, 0,
       32, 256, 16, 0, 4);
  reduce_k<<<dim3(32), dim3(256), 0, stream>>>(part, feats + (i64)5440 * 256, bub1,
      16, TC, 256, 32, 256, 4);

  // ---- 6 transformer layers ----
  for (int i = 0; i < NLAYERS; i++) {
    const u16* wbL = wb + 6225920 + (i64)i * 786432;
    ln_k<<<dim3(2728), dim3(256), 0, stream>>>(feats, qb,
        ln1g + (i64)i * 256, ln1b + (i64)i * 256, BNROWS);
    // fused off|att|val GEMM, N=768; off/att written as bf16
    mg128(dim3(86, 6, 1), qb, wbL, 256, (float*)off16, (float*)att16, valb, 0,
          bqkv + (i64)i * 768, 0, 0, 1, BNROWS, 768, BNROWS, 0, 1);
    // sampling (softmax fused), XCD-swizzled, 32 lanes/token
    dsample_k<<<dim3(688, 2), dim3(256), 0, stream>>>(valb, off16, att16, sampb);
    // out proj + residual
    mg64(dim3(86, 4, 1), sampb, wbL + 196608, 256, feats, nullptr, 256,
         bout + (i64)i * 256, 0, 1, BNROWS, 256, BNROWS, 0, 1);
    ln_k<<<dim3(2728), dim3(256), 0, stream>>>(feats, qb,
        ln2g + (i64)i * 256, ln2b + (i64)i * 256, BNROWS);
    // FFN
    mg128(dim3(86, 8, 1), qb, wbL + 262144, 256, nullptr, nullptr, hb, 1024,
          b1 + (i64)i * 1024, 1, 0, 0, BNROWS, 1024, BNROWS, 0, 1);
    mg64(dim3(86, 4, 1), hb, wbL + 524288, 1024, feats, nullptr, 256,
         b2 + (i64)i * 256, 0, 1, BNROWS, 256, BNROWS, 0, 1);
  }

  // ---- split into 5 level maps (one dispatch) ----
  untranspose_all_k<<<dim3(171, 8, 2), dim3(256), 0, stream>>>(feats, out);
  (void)in_sizes; (void)n_in; (void)out_size; (void)ws_size;
}

// Round 8
// 1113.069 us; speedup vs baseline: 7.2048x; 1.1286x over previous
//
#include <hip/hip_runtime.h>
#include <cstdint>

typedef long long i64;
typedef unsigned short u16;
typedef __attribute__((ext_vector_type(8))) short short8;
typedef __attribute__((ext_vector_type(8))) unsigned short us8;
typedef __attribute__((ext_vector_type(4))) float f32x4;

#define NTOK 5456
#define BNROWS 10912
#define NLAYERS 6

__device__ __forceinline__ u16 f2bf(float f) {
  unsigned u = __float_as_uint(f);
  return (u16)((u + 0x7FFFu + ((u >> 16) & 1u)) >> 16);
}
__device__ __forceinline__ float bf2f(u16 h) {
  return __uint_as_float(((unsigned)h) << 16);
}

// ---------------- bf16 MFMA GEMM, 2-phase double-buffered ----------------
// A: [rows>=ceil(M,128)][K] bf16 row-major. B: [N][K] bf16 (n-major).
// Row->output mapping (KS==1, non-qkv): ci = (row>>mbsh)*bCz + (row&mask)*sCm + col
// (layer GEMMs pass mbsh=14 so row>>14==0 and mask is identity).
// T1: bijective XCD swizzle on the flattened (x,y) grid, column-major refold.
template<int BNT>
__global__ __launch_bounds__(256) void mgemm_k(
    const u16* __restrict__ A, const u16* __restrict__ B, int K,
    float* __restrict__ C, float* __restrict__ C2, u16* __restrict__ C16, i64 sCm,
    const float* __restrict__ bias, int relu, int addres, int qkv,
    int M, int N, int mbsh, i64 bCz,
    int KS, float* __restrict__ part)
{
  constexpr int NW = BNT / 32;      // N-frags per wave; also B staging rounds
  __shared__ u16 Asm[2][128 * 64];
  __shared__ u16 Bsm[2][BNT * 64];
  int tid = threadIdx.x;

  // XCD-locality swizzle (bijective, m204 form): contiguous f-range per XCD,
  // column-major refold so one XCD owns ~contiguous m-tiles x all n-tiles.
  int bx = blockIdx.x, by = blockIdx.y;
  int gx = gridDim.x, gy = gridDim.y;
  int nwg = gx * gy;
  if (KS == 1 && nwg >= 16) {
    int lin = bx + gx * by;
    int xcd = lin & 7, k = lin >> 3;
    int q = nwg >> 3, r = nwg & 7;
    int f = (xcd < r) ? (xcd * (q + 1) + k) : (r * (q + 1) + (xcd - r) * q + k);
    bx = f / gy;
    by = f - bx * gy;
  }
  int m0 = bx * 128, n0 = by * BNT;

  int ks = blockIdx.z;
  int Kc = K / KS;
  int k0 = ks * Kc;
  int lane = tid & 63, w = tid >> 6;
  int wr = w >> 1, wc = w & 1;
  int r16 = lane & 15, g = lane >> 4;

  f32x4 acc[4][NW];
#pragma unroll
  for (int mi = 0; mi < 4; mi++)
#pragma unroll
    for (int nj = 0; nj < NW; nj++) acc[mi][nj] = (f32x4){0.f, 0.f, 0.f, 0.f};

  const u16* Ag = A + (i64)m0 * K + k0;
  const u16* Bg = B + (i64)n0 * K + k0;
  int nt = Kc >> 6;

  auto stage = [&](int buf, int kt) {
    // A tile: 128x64 bf16 = 16 KiB = 4 rounds of (256 thr x 16B)
#pragma unroll
    for (int r = 0; r < 4; r++) {
      int s = r * 256 + tid;
      int row = s >> 3, c = s & 7;
      int cs = ((c ^ (row & 7)) << 3);
      __builtin_amdgcn_global_load_lds(
          (const __attribute__((address_space(1))) void*)(Ag + (i64)row * K + kt + cs),
          (__attribute__((address_space(3))) void*)(&Asm[buf][(r * 256 + (w << 6)) << 3]),
          16, 0, 0);
    }
    // B tile: BNTx64 bf16 = BNT*128 bytes = NW rounds
#pragma unroll
    for (int r = 0; r < NW; r++) {
      int s = r * 256 + tid;
      int row = s >> 3, c = s & 7;
      int cs = ((c ^ (row & 7)) << 3);
      __builtin_amdgcn_global_load_lds(
          (const __attribute__((address_space(1))) void*)(Bg + (i64)row * K + kt + cs),
          (__attribute__((address_space(3))) void*)(&Bsm[buf][(r * 256 + (w << 6)) << 3]),
          16, 0, 0);
    }
  };

  stage(0, 0);
  __syncthreads();
  for (int t = 0; t < nt; t++) {
    int cur = t & 1;
    if (t + 1 < nt) stage(cur ^ 1, (t + 1) << 6);
#pragma unroll
    for (int h = 0; h < 2; h++) {
      short8 av[4], bv[NW];
#pragma unroll
      for (int mi = 0; mi < 4; mi++) {
        int row = wr * 64 + mi * 16 + r16;
        av[mi] = *(const short8*)&Asm[cur][row * 64 + ((((h << 2) + g) ^ (row & 7)) << 3)];
      }
#pragma unroll
      for (int nj = 0; nj < NW; nj++) {
        int row = wc * (NW * 16) + nj * 16 + r16;
        bv[nj] = *(const short8*)&Bsm[cur][row * 64 + ((((h << 2) + g) ^ (row & 7)) << 3)];
      }
#pragma unroll
      for (int mi = 0; mi < 4; mi++)
#pragma unroll
        for (int nj = 0; nj < NW; nj++)
          acc[mi][nj] = __builtin_amdgcn_mfma_f32_16x16x32_bf16(
              av[mi], bv[nj], acc[mi][nj], 0, 0, 0);
    }
    __syncthreads();
  }

  if (KS > 1) {
#pragma unroll
    for (int mi = 0; mi < 4; mi++)
#pragma unroll
      for (int nj = 0; nj < NW; nj++)
#pragma unroll
        for (int r = 0; r < 4; r++) {
          int grow = m0 + wr * 64 + mi * 16 + g * 4 + r;
          int gcol = n0 + wc * (NW * 16) + nj * 16 + r16;
          if (grow < M) part[((i64)ks * M + grow) * N + gcol] = acc[mi][nj][r];
        }
  } else if (qkv) {
    u16* off16 = (u16*)C;
    u16* att16 = (u16*)C2;
#pragma unroll
    for (int mi = 0; mi < 4; mi++)
#pragma unroll
      for (int nj = 0; nj < NW; nj++)
#pragma unroll
        for (int r = 0; r < 4; r++) {
          int grow = m0 + wr * 64 + mi * 16 + g * 4 + r;
          int gcol = n0 + wc * (NW * 16) + nj * 16 + r16;
          if (grow < M) {
            float v = acc[mi][nj][r] + bias[gcol];
            if (gcol < 320) off16[(i64)grow * 320 + gcol] = f2bf(v);
            else if (gcol < 480) att16[(i64)grow * 160 + (gcol - 320)] = f2bf(v);
            else if (gcol < 736) C16[(i64)grow * 256 + (gcol - 480)] = f2bf(v);
          }
        }
  } else {
    // preload bias + column bounds once
    float bv[NW];
    int gc0 = n0 + wc * (NW * 16) + r16;
#pragma unroll
    for (int nj = 0; nj < NW; nj++)
      bv[nj] = bias ? bias[gc0 + nj * 16] : 0.f;
    int mask = (1 << mbsh) - 1;
#pragma unroll
    for (int mi = 0; mi < 4; mi++) {
#pragma unroll
      for (int r = 0; r < 4; r++) {
        int grow = m0 + wr * 64 + mi * 16 + g * 4 + r;
        if (grow >= M) continue;
        i64 rowb = (i64)(grow >> mbsh) * bCz + (i64)(grow & mask) * sCm;
#pragma unroll
        for (int nj = 0; nj < NW; nj++) {
          int gcol = gc0 + nj * 16;
          if (gcol >= N) continue;
          float v = acc[mi][nj][r] + bv[nj];
          if (relu) v = fmaxf(v, 0.f);
          i64 ci = rowb + gcol;
          if (C16) C16[ci] = f2bf(v);
          else {
            if (addres) v += C[ci];
            C[ci] = v;
          }
        }
      }
    }
  }
}

// reduce split-K fp32 partials (stride N); row map via shift/mask
__global__ void reduce_k(const float* __restrict__ part, float* __restrict__ C,
    const float* __restrict__ bias, int mbsh, i64 bCz, i64 sCm, int M, int N, int KS)
{
  int idx = blockIdx.x * 256 + threadIdx.x;
  if (idx >= M * N) return;
  int m = idx / N, n = idx - m * N;
  float v = bias ? bias[n] : 0.f;
  for (int ks = 0; ks < KS; ks++) v += part[((i64)ks * M + m) * N + n];
  C[(i64)(m >> mbsh) * bCz + (i64)(m & ((1 << mbsh) - 1)) * sCm + n] = v;
}

// ---------------- weight conversions ----------------
__global__ void cvt_w_pro_k(const float* __restrict__ pw0, const float* __restrict__ pw1,
    const float* __restrict__ pw2, const float* __restrict__ buw0,
    const float* __restrict__ buw1, u16* __restrict__ dst)
{
  int idx = blockIdx.x * 256 + threadIdx.x;
  if (idx >= 6225920) return;
  float v;
  if (idx < 131072) v = pw0[idx];
  else if (idx < 393216) v = pw1[idx - 131072];
  else if (idx < 917504) v = pw2[idx - 393216];
  else if (idx < 5636096) v = buw0[idx - 917504];
  else v = buw1[idx - 5636096];
  dst[idx] = f2bf(v);
}

// per-layer: qkv [768][256] | wout [256][256] | w1 [1024][256] | w2 [256][1024]
__global__ void cvt_w_layer_k(const float* __restrict__ woff, const float* __restrict__ watt,
    const float* __restrict__ wval, const float* __restrict__ wout,
    const float* __restrict__ w1, const float* __restrict__ w2, u16* __restrict__ dst)
{
  int L = blockIdx.y;
  int o = blockIdx.x * 256 + threadIdx.x;
  if (o >= 786432) return;
  u16* d = dst + (i64)L * 786432;
  float v;
  if (o < 196608) {
    int n = o >> 8, k = o & 255;
    if (n < 320) v = woff[(i64)L * 81920 + k * 320 + n];
    else if (n < 480) v = watt[(i64)L * 40960 + k * 160 + (n - 320)];
    else if (n < 736) v = wval[(i64)L * 65536 + k * 256 + (n - 480)];
    else v = 0.f;
  } else if (o < 262144) {
    int o2 = o - 196608; int n = o2 >> 8, k = o2 & 255;
    v = wout[(i64)L * 65536 + k * 256 + n];
  } else if (o < 524288) {
    int o2 = o - 262144; int n = o2 >> 8, k = o2 & 255;
    v = w1[(i64)L * 262144 + (i64)k * 1024 + n];
  } else {
    int o2 = o - 524288; int n = o2 >> 10, k = o2 & 1023;
    v = w2[(i64)L * 262144 + (i64)k * 256 + n];
  }
  d[o] = f2bf(v);
}

// combined qkv bias [L][768] fp32
__global__ void cvt_bias_k(const float* __restrict__ boff, const float* __restrict__ batt,
    const float* __restrict__ bval, float* __restrict__ bq)
{
  int idx = blockIdx.x * 256 + threadIdx.x;
  if (idx >= NLAYERS * 768) return;
  int L = idx / 768, n = idx - L * 768;
  float v;
  if (n < 320) v = boff[(i64)L * 320 + n];
  else if (n < 480) v = batt[(i64)L * 160 + (n - 320)];
  else if (n < 736) v = bval[(i64)L * 256 + (n - 480)];
  else v = 0.f;
  bq[idx] = v;
}

// in_map [2][K][P] fp32 -> A [2*P][K] bf16
__global__ void cvt_a_proj_k(const float* __restrict__ in, u16* __restrict__ out,
                             int P, int K)
{
  i64 o = (i64)blockIdx.x * 256 + threadIdx.x;
  if (o >= (i64)2 * P * K) return;
  int m = (int)(o / K), k = (int)(o % K);
  int b = m / P, p = m - b * P;
  out[o] = f2bf(in[((i64)b * K + k) * P + p]);
}

// im2col 3x3 s2 p1 -> bf16 [2*Ho*Wo][Cin*9]
__global__ void im2col_bf16_k(const float* __restrict__ in, u16* __restrict__ out,
    int Cin, int Hin, int Win, int Ho, int Wo)
{
  int Kk = Cin * 9;
  i64 total = (i64)2 * Ho * Wo * Kk;
  i64 o = (i64)blockIdx.x * 256 + threadIdx.x;
  if (o >= total) return;
  int k = (int)(o % Kk);
  int m = (int)(o / Kk);
  int hw = Ho * Wo;
  int b = m / hw, pix = m - b * hw;
  int oy = pix / Wo, ox = pix - oy * Wo;
  int ci = k / 9, r = k - ci * 9;
  int ky = r / 3, kx = r - ky * 3;
  int iy = oy * 2 - 1 + ky, ix = ox * 2 - 1 + kx;
  float v = 0.f;
  if (iy >= 0 && iy < Hin && ix >= 0 && ix < Win)
    v = in[(((i64)b * Cin + ci) * Hin + iy) * Win + ix];
  out[o] = f2bf(v);
}

// GroupNorm(8)+ReLU over feats tokens [5376..5440) -> y [b][256][64] fp32
__global__ void gn_relu_k(const float* __restrict__ feats, float* __restrict__ y,
    const float* __restrict__ g, const float* __restrict__ bt)
{
  int grp = blockIdx.x, b = blockIdx.y;
  int tid = threadIdx.x;
  const float* fb = feats + ((i64)b * NTOK + 5376) * 256 + grp * 32;
  float s = 0.f, ss = 0.f;
  for (int i = tid; i < 2048; i += 256) {
    int cl = i >> 6, p = i & 63;
    float v = fb[(i64)p * 256 + cl];
    s += v; ss += v * v;
  }
  __shared__ float sb[4], ssb[4];
#pragma unroll
  for (int o = 32; o > 0; o >>= 1) { s += __shfl_down(s, o); ss += __shfl_down(ss, o); }
  int wv = tid >> 6;
  if ((tid & 63) == 0) { sb[wv] = s; ssb[wv] = ss; }
  __syncthreads();
  float ts = sb[0] + sb[1] + sb[2] + sb[3];
  float tss = ssb[0] + ssb[1] + ssb[2] + ssb[3];
  float mean = ts * (1.f / 2048.f);
  float rs = rsqrtf(tss * (1.f / 2048.f) - mean * mean + 1e-5f);
  for (int i = tid; i < 2048; i += 256) {
    int cl = i >> 6, p = i & 63;
    int c = grp * 32 + cl;
    float v = (fb[(i64)p * 256 + cl] - mean) * rs * g[c] + bt[c];
    y[((i64)b * 256 + c) * 64 + p] = fmaxf(v, 0.f);
  }
}

// LayerNorm rows of 256, fp32 in -> bf16 out
__global__ __launch_bounds__(256) void ln_k(const float* __restrict__ x,
    u16* __restrict__ y, const float* __restrict__ g, const float* __restrict__ bt,
    int rows)
{
  int row = blockIdx.x * 4 + (threadIdx.x >> 6);
  if (row >= rows) return;
  int lane = threadIdx.x & 63;
  float4 v = ((const float4*)(x + (i64)row * 256))[lane];
  float s = v.x + v.y + v.z + v.w;
  float ss = v.x * v.x + v.y * v.y + v.z * v.z + v.w * v.w;
#pragma unroll
  for (int o = 32; o > 0; o >>= 1) { s += __shfl_down(s, o); ss += __shfl_down(ss, o); }
  s = __shfl(s, 0);
  ss = __shfl(ss, 0);
  float mean = s * (1.f / 256.f);
  float rs = rsqrtf(ss * (1.f / 256.f) - mean * mean + 1e-5f);
  float4 gg = ((const float4*)g)[lane];
  float4 bb = ((const float4*)bt)[lane];
  ushort4 o4;
  o4.x = f2bf((v.x - mean) * rs * gg.x + bb.x);
  o4.y = f2bf((v.y - mean) * rs * gg.y + bb.y);
  o4.z = f2bf((v.z - mean) * rs * gg.z + bb.z);
  o4.w = f2bf((v.w - mean) * rs * gg.w + bb.w);
  ((ushort4*)(y + (i64)row * 256))[lane] = o4;
}

// deformable sampling v5: 32 lanes/token (8 heads x 4 dh-chunks of 8),
// owner-lane softmax/params (4 owners x 5 points, level == owner slot j),
// ushort8 16B gathers, bf16 off/att inputs, XCD-contiguous chunk swizzle.
// grid (688, 2): chunk = (bid&7)*86 + bid>>3, 8 tokens per block.
__global__ __launch_bounds__(256) void dsample_k(
    const u16* __restrict__ val, const u16* __restrict__ off,
    const u16* __restrict__ att, u16* __restrict__ out)
{
  const int FH[5] = {64, 32, 16, 8, 4};
  const int ST[5] = {0, 4096, 5120, 5376, 5440};
  int bid = blockIdx.x;
  int chunk = (bid & 7) * 86 + (bid >> 3);
  if (chunk >= 682) return;
  int lane = threadIdx.x & 63;
  int half = lane >> 5;
  int l32 = lane & 31;
  int t = chunk * 8 + ((threadIdx.x >> 6) << 1) + half;
  int b = blockIdx.y;
  int h = l32 >> 2, d4 = l32 & 3;

  int lv;
  if (t < 4096)      lv = 0;
  else if (t < 5120) lv = 1;
  else if (t < 5376) lv = 2;
  else if (t < 5440) lv = 3;
  else               lv = 4;
  int loc = t - ST[lv];
  int sh = 6 - lv;
  int py = loc >> sh, px = loc - (py << sh);
  float inv = 1.f / (float)FH[lv];
  float prx = (px + 0.5f) * inv, pry = (py + 0.5f) * inv;
  i64 bt = (i64)b * NTOK + t;
  const u16* offp = off + bt * 320 + h * 40;
  const u16* attp = att + bt * 160 + h * 20;
  const u16* vbase = val + ((i64)b * NTOK) * 256 + h * 32 + d4 * 8;

  // ---- owner phase: lane d4 owns points p = d4 + 4j (level j), j=0..4 ----
  float own_a[5], own_fx[5], own_fy[5];
  int own_pk[5];
  float mx = -1e30f;
#pragma unroll
  for (int j = 0; j < 5; j++) {
    float lg = bf2f(attp[d4 + 4 * j]);
    own_a[j] = lg;
    mx = fmaxf(mx, lg);
  }
  mx = fmaxf(mx, __shfl_xor(mx, 1));
  mx = fmaxf(mx, __shfl_xor(mx, 2));
  float sum = 0.f;
#pragma unroll
  for (int j = 0; j < 5; j++) {
    float e = __expf(own_a[j] - mx);
    own_a[j] = e;
    sum += e;
  }
  sum += __shfl_xor(sum, 1);
  sum += __shfl_xor(sum, 2);
  float rinv = 1.f / sum;
#pragma unroll
  for (int j = 0; j < 5; j++) {
    int p = d4 + 4 * j;
    own_a[j] *= rinv;
    unsigned opk = *(const unsigned*)(offp + 2 * p);
    float ox = bf2f((u16)(opk & 0xFFFF));
    float oy = bf2f((u16)(opk >> 16));
    float sff = (float)(64 >> j);
    float xx = prx * sff + ox - 0.5f;
    float yy = pry * sff + oy - 0.5f;
    float xf = floorf(xx), yf = floorf(yy);
    own_fx[j] = xx - xf;
    own_fy[j] = yy - yf;
    own_pk[j] = (((int)yf) << 16) | (((int)xf) & 0xFFFF);
  }

  // ---- gather phase: 8 dh per lane, 16B loads ----
  float acc[8] = {0.f, 0.f, 0.f, 0.f, 0.f, 0.f, 0.f, 0.f};
#pragma unroll
  for (int p = 0; p < 20; p++) {
    const int j = p >> 2;               // level == owner slot
    const int sf = FH[j], st = ST[j];
    int src = (half << 5) | (h << 2) | (p & 3);
    float wa = __shfl(own_a[j], src);
    float fx = __shfl(own_fx[j], src);
    float fy = __shfl(own_fy[j], src);
    int pk = __shfl(own_pk[j], src);
    int x0 = (pk << 16) >> 16;
    int y0 = pk >> 16;
    float gx0 = wa - wa * fx, gx1 = wa * fx;
    float w00 = gx0 - gx0 * fy, w01 = gx0 * fy;
    float w10 = gx1 - gx1 * fy, w11 = gx1 * fy;
    bool xin0 = (x0 >= 0) & (x0 < sf), xin1 = (x0 + 1 >= 0) & (x0 + 1 < sf);
    bool yin0 = (y0 >= 0) & (y0 < sf), yin1 = (y0 + 1 >= 0) & (y0 + 1 < sf);
    int ibase = st + y0 * sf + x0;
#define FMA8(W, IDX) { \
      us8 v = *(const us8*)(vbase + (i64)(IDX) * 256); \
      acc[0] = fmaf(W, bf2f(v[0]), acc[0]); acc[1] = fmaf(W, bf2f(v[1]), acc[1]); \
      acc[2] = fmaf(W, bf2f(v[2]), acc[2]); acc[3] = fmaf(W, bf2f(v[3]), acc[3]); \
      acc[4] = fmaf(W, bf2f(v[4]), acc[4]); acc[5] = fmaf(W, bf2f(v[5]), acc[5]); \
      acc[6] = fmaf(W, bf2f(v[6]), acc[6]); acc[7] = fmaf(W, bf2f(v[7]), acc[7]); }
    if (xin0 & yin0) FMA8(w00, ibase);
    if (xin1 & yin0) FMA8(w10, ibase + 1);
    if (xin0 & yin1) FMA8(w01, ibase + sf);
    if (xin1 & yin1) FMA8(w11, ibase + sf + 1);
#undef FMA8
  }
  us8 o;
#pragma unroll
  for (int i = 0; i < 8; i++) o[i] = f2bf(acc[i]);
  *(us8*)(out + ((bt * 8 + h) * 32 + d4 * 8)) = o;
}

// all 5 levels in one dispatch: out[b][c][p] = feats[b][start+p][c]
// grid.x = 171: lvl0 u<128, lvl1 u<160, lvl2 u<168, lvl3 u<170 (S=64), lvl4 u=170
__global__ __launch_bounds__(256) void untranspose_all_k(
    const float* __restrict__ feats, float* __restrict__ out)
{
  int u = blockIdx.x;
  int pt0, start, S; i64 ooff;
  if (u < 128)      { pt0 = u;       start = 0;    S = 4096; ooff = 0; }
  else if (u < 160) { pt0 = u - 128; start = 4096; S = 1024; ooff = 2097152; }
  else if (u < 168) { pt0 = u - 160; start = 5120; S = 256;  ooff = 2621440; }
  else if (u < 170) { pt0 = u - 168; start = 5376; S = 64;   ooff = 2752512; }
  else              { pt0 = 0;       start = 5440; S = 16;   ooff = 2785280; }
  __shared__ float tile[32][33];
  int pt = pt0 * 32, ct = blockIdx.y * 32, b = blockIdx.z;
  int tx = threadIdx.x & 31, ty = threadIdx.x >> 5;
  for (int i = ty; i < 32; i += 8) {
    int p = pt + i;
    tile[i][tx] = (p < S) ? feats[((i64)b * NTOK + start + p) * 256 + ct + tx] : 0.f;
  }
  __syncthreads();
  for (int i = ty; i < 32; i += 8) {
    int c = ct + i, p = pt + tx;
    if (p < S) out[ooff + ((i64)b * 256 + c) * S + p] = tile[tx][i];
  }
}

extern "C" void kernel_launch(void* const* d_in, const int* in_sizes, int n_in,
                              void* d_out, int out_size, void* d_ws, size_t ws_size,
                              hipStream_t stream)
{
  const float* in0  = (const float*)d_in[0];
  const float* in1  = (const float*)d_in[1];
  const float* in2  = (const float*)d_in[2];
  const float* pw0  = (const float*)d_in[3];
  const float* pb0  = (const float*)d_in[4];
  const float* pw1  = (const float*)d_in[5];
  const float* pb1  = (const float*)d_in[6];
  const float* pw2  = (const float*)d_in[7];
  const float* pb2  = (const float*)d_in[8];
  const float* buw0 = (const float*)d_in[9];
  const float* bub0 = (const float*)d_in[10];
  const float* gng  = (const float*)d_in[11];
  const float* gnb  = (const float*)d_in[12];
  const float* buw1 = (const float*)d_in[13];
  const float* bub1 = (const float*)d_in[14];
  const float* ln1g = (const float*)d_in[15];
  const float* ln1b = (const float*)d_in[16];
  const float* woff = (const float*)d_in[17];
  const float* boff = (const float*)d_in[18];
  const float* watt = (const float*)d_in[19];
  const float* batt = (const float*)d_in[20];
  const float* wval = (const float*)d_in[21];
  const float* bval = (const float*)d_in[22];
  const float* wout = (const float*)d_in[23];
  const float* bout = (const float*)d_in[24];
  const float* ln2g = (const float*)d_in[25];
  const float* ln2b = (const float*)d_in[26];
  const float* w1   = (const float*)d_in[27];
  const float* b1   = (const float*)d_in[28];
  const float* w2   = (const float*)d_in[29];
  const float* b2   = (const float*)d_in[30];
  float* out = (float*)d_out;

  const i64 TC = (i64)NTOK * 256;

  // ---- ws layout (f32 units) ----
  float* ws    = (float*)d_ws;
  float* feats = ws;                               // 2,793,472
  u16*   qb    = (u16*)(feats + 2793472);          // 11008x256 bf16
  u16*   valb  = qb + 2818048;
  u16*   sampb = valb + 2818048;
  float* U     = (float*)(sampb + 2818048);        // union region: 5,637,120 f32
  u16*   off16 = (u16*)U;                          // [10912][320] bf16
  u16*   att16 = off16 + 3491840;                  // [10912][160] bf16
  u16*   hb    = (u16*)U;                          // [11008][1024] bf16 (FFN)
  u16*   abuf  = (u16*)U;                          // prologue A
  float* part  = U + 2097152;                      // split-K partials
  u16*   wb    = (u16*)(U + 5637120);              // 10,944,512 bf16
  float* bqkv  = (float*)(wb + 10944512);          // 4,608 f32
  float* m4gn  = bqkv + 4608;                      // 32,768 f32

  auto mg128 = [&](dim3 grid, const u16* A, const u16* B, int K,
                   float* C, float* C2, u16* C16, i64 sCm, const float* bias,
                   int relu, int addres, int qkv, int M, int N, int mbsh, i64 bCz, int KS) {
    mgemm_k<128><<<grid, dim3(256), 0, stream>>>(A, B, K, C, C2, C16, sCm, bias,
        relu, addres, qkv, M, N, mbsh, bCz, KS, part);
  };
  auto mg64 = [&](dim3 grid, const u16* A, const u16* B, int K,
                  float* C, u16* C16, i64 sCm, const float* bias,
                  int relu, int addres, int M, int N, int mbsh, i64 bCz, int KS) {
    mgemm_k<64><<<grid, dim3(256), 0, stream>>>(A, B, K, C, nullptr, C16, sCm, bias,
        relu, addres, 0, M, N, mbsh, bCz, KS, part);
  };

  // ---- weight conversion ----
  cvt_w_pro_k<<<dim3(24320), dim3(256), 0, stream>>>(pw0, pw1, pw2, buw0, buw1, wb);
  cvt_w_layer_k<<<dim3(3072, NLAYERS), dim3(256), 0, stream>>>(
      woff, watt, wval, wout, w1, w2, wb + 6225920);
  cvt_bias_k<<<dim3(18), dim3(256), 0, stream>>>(boff, batt, bval, bqkv);

  // ---- projections ----
  cvt_a_proj_k<<<dim3(16384), dim3(256), 0, stream>>>(in0, abuf, 4096, 512);
  mg64(dim3(64, 4, 1), abuf, wb, 512, feats, nullptr, 256, pb0, 0, 0,
       8192, 256, 12, TC, 1);
  cvt_a_proj_k<<<dim3(8192), dim3(256), 0, stream>>>(in1, abuf, 1024, 1024);
  mg64(dim3(16, 4, 2), abuf, wb + 131072, 1024, nullptr, nullptr, 256, nullptr, 0, 0,
       2048, 256, 10, 0, 2);
  reduce_k<<<dim3(2048), dim3(256), 0, stream>>>(part, feats + (i64)4096 * 256, pb1,
      10, TC, 256, 2048, 256, 2);
  cvt_a_proj_k<<<dim3(4096), dim3(256), 0, stream>>>(in2, abuf, 256, 2048);
  mg64(dim3(4, 4, 4), abuf, wb + 393216, 2048, nullptr, nullptr, 256, nullptr, 0, 0,
       512, 256, 8, 0, 4);
  reduce_k<<<dim3(512), dim3(256), 0, stream>>>(part, feats + (i64)5120 * 256, pb2,
      8, TC, 256, 512, 256, 4);

  // ---- bottom-up conv0: in2 (2048ch,16x16)->8x8 ----
  im2col_bf16_k<<<dim3(9216), dim3(256), 0, stream>>>(in2, abuf, 2048, 16, 16, 8, 8);
  mg64(dim3(1, 4, 16), abuf, wb + 917504, 18432, nullptr, nullptr, 256, nullptr, 0, 0,
       128, 256, 6, 0, 16);
  reduce_k<<<dim3(128), dim3(256), 0, stream>>>(part, feats + (i64)5376 * 256, bub0,
      6, TC, 256, 128, 256, 16);

  // ---- GN+ReLU, bottom-up conv1: (256ch,8x8)->4x4 ----
  gn_relu_k<<<dim3(8, 2), dim3(256), 0, stream>>>(feats, m4gn, gng, gnb);
  im2col_bf16_k<<<dim3(288), dim3(256), 0, stream>>>(m4gn, abuf, 256, 8, 8, 4, 4);
  mg64(dim3(1, 4, 4), abuf, wb + 5636096, 2304, nullptr, nullptr, 256, nullptr, 0, 0,
       32, 256, 4, 0, 4);
  reduce_k<<<dim3(32), dim3(256), 0, stream>>>(part, feats + (i64)5440 * 256, bub1,
      4, TC, 256, 32, 256, 4);

  // ---- 6 transformer layers ----
  for (int i = 0; i < NLAYERS; i++) {
    const u16* wbL = wb + 6225920 + (i64)i * 786432;
    ln_k<<<dim3(2728), dim3(256), 0, stream>>>(feats, qb,
        ln1g + (i64)i * 256, ln1b + (i64)i * 256, BNROWS);
    // fused off|att|val GEMM, N=768; off/att written as bf16
    mg128(dim3(86, 6, 1), qb, wbL, 256, (float*)off16, (float*)att16, valb, 0,
          bqkv + (i64)i * 768, 0, 0, 1, BNROWS, 768, 14, 0, 1);
    // sampling (softmax fused), XCD-swizzled, 32 lanes/token
    dsample_k<<<dim3(688, 2), dim3(256), 0, stream>>>(valb, off16, att16, sampb);
    // out proj + residual
    mg64(dim3(86, 4, 1), sampb, wbL + 196608, 256, feats, nullptr, 256,
         bout + (i64)i * 256, 0, 1, BNROWS, 256, 14, 0, 1);
    ln_k<<<dim3(2728), dim3(256), 0, stream>>>(feats, qb,
        ln2g + (i64)i * 256, ln2b + (i64)i * 256, BNROWS);
    // FFN
    mg128(dim3(86, 8, 1), qb, wbL + 262144, 256, nullptr, nullptr, hb, 1024,
          b1 + (i64)i * 1024, 1, 0, 0, BNROWS, 1024, 14, 0, 1);
    mg64(dim3(86, 4, 1), hb, wbL + 524288, 1024, feats, nullptr, 256,
         b2 + (i64)i * 256, 0, 1, BNROWS, 256, 14, 0, 1);
  }

  // ---- split into 5 level maps (one dispatch) ----
  untranspose_all_k<<<dim3(171, 8, 2), dim3(256), 0, stream>>>(feats, out);
  (void)in_sizes; (void)n_in; (void)out_size; (void)ws_size;
}

// Round 9
// 1013.086 us; speedup vs baseline: 7.9159x; 1.0987x over previous
//
#include <hip/hip_runtime.h>
#include <cstdint>

typedef long long i64;
typedef unsigned short u16;
typedef __attribute__((ext_vector_type(8))) short short8;
typedef __attribute__((ext_vector_type(8))) unsigned short us8;
typedef __attribute__((ext_vector_type(4))) float f32x4;

#define NTOK 5456
#define BNROWS 10912
#define NLAYERS 6

__device__ __forceinline__ u16 f2bf(float f) {
  unsigned u = __float_as_uint(f);
  return (u16)((u + 0x7FFFu + ((u >> 16) & 1u)) >> 16);
}
__device__ __forceinline__ float bf2f(u16 h) {
  return __uint_as_float(((unsigned)h) << 16);
}

// ---------------- bf16 MFMA GEMM, 2-phase double-buffered ----------------
template<int BNT>
__global__ __launch_bounds__(256) void mgemm_k(
    const u16* __restrict__ A, const u16* __restrict__ B, int K,
    float* __restrict__ C, float* __restrict__ C2, u16* __restrict__ C16, i64 sCm,
    const float* __restrict__ bias, int relu, int addres, int qkv,
    int M, int N, int mbsh, i64 bCz,
    int KS, float* __restrict__ part)
{
  constexpr int NW = BNT / 32;
  __shared__ u16 Asm[2][128 * 64];
  __shared__ u16 Bsm[2][BNT * 64];
  int tid = threadIdx.x;

  int bx = blockIdx.x, by = blockIdx.y;
  int gx = gridDim.x, gy = gridDim.y;
  int nwg = gx * gy;
  if (KS == 1 && nwg >= 16) {
    int lin = bx + gx * by;
    int xcd = lin & 7, k = lin >> 3;
    int q = nwg >> 3, r = nwg & 7;
    int f = (xcd < r) ? (xcd * (q + 1) + k) : (r * (q + 1) + (xcd - r) * q + k);
    bx = f / gy;
    by = f - bx * gy;
  }
  int m0 = bx * 128, n0 = by * BNT;

  int ks = blockIdx.z;
  int Kc = K / KS;
  int k0 = ks * Kc;
  int lane = tid & 63, w = tid >> 6;
  int wr = w >> 1, wc = w & 1;
  int r16 = lane & 15, g = lane >> 4;

  f32x4 acc[4][NW];
#pragma unroll
  for (int mi = 0; mi < 4; mi++)
#pragma unroll
    for (int nj = 0; nj < NW; nj++) acc[mi][nj] = (f32x4){0.f, 0.f, 0.f, 0.f};

  const u16* Ag = A + (i64)m0 * K + k0;
  const u16* Bg = B + (i64)n0 * K + k0;
  int nt = Kc >> 6;

  auto stage = [&](int buf, int kt) {
#pragma unroll
    for (int r = 0; r < 4; r++) {
      int s = r * 256 + tid;
      int row = s >> 3, c = s & 7;
      int cs = ((c ^ (row & 7)) << 3);
      __builtin_amdgcn_global_load_lds(
          (const __attribute__((address_space(1))) void*)(Ag + (i64)row * K + kt + cs),
          (__attribute__((address_space(3))) void*)(&Asm[buf][(r * 256 + (w << 6)) << 3]),
          16, 0, 0);
    }
#pragma unroll
    for (int r = 0; r < NW; r++) {
      int s = r * 256 + tid;
      int row = s >> 3, c = s & 7;
      int cs = ((c ^ (row & 7)) << 3);
      __builtin_amdgcn_global_load_lds(
          (const __attribute__((address_space(1))) void*)(Bg + (i64)row * K + kt + cs),
          (__attribute__((address_space(3))) void*)(&Bsm[buf][(r * 256 + (w << 6)) << 3]),
          16, 0, 0);
    }
  };

  stage(0, 0);
  __syncthreads();
  for (int t = 0; t < nt; t++) {
    int cur = t & 1;
    if (t + 1 < nt) stage(cur ^ 1, (t + 1) << 6);
#pragma unroll
    for (int h = 0; h < 2; h++) {
      short8 av[4], bv[NW];
#pragma unroll
      for (int mi = 0; mi < 4; mi++) {
        int row = wr * 64 + mi * 16 + r16;
        av[mi] = *(const short8*)&Asm[cur][row * 64 + ((((h << 2) + g) ^ (row & 7)) << 3)];
      }
#pragma unroll
      for (int nj = 0; nj < NW; nj++) {
        int row = wc * (NW * 16) + nj * 16 + r16;
        bv[nj] = *(const short8*)&Bsm[cur][row * 64 + ((((h << 2) + g) ^ (row & 7)) << 3)];
      }
#pragma unroll
      for (int mi = 0; mi < 4; mi++)
#pragma unroll
        for (int nj = 0; nj < NW; nj++)
          acc[mi][nj] = __builtin_amdgcn_mfma_f32_16x16x32_bf16(
              av[mi], bv[nj], acc[mi][nj], 0, 0, 0);
    }
    __syncthreads();
  }

  if (KS > 1) {
#pragma unroll
    for (int mi = 0; mi < 4; mi++)
#pragma unroll
      for (int nj = 0; nj < NW; nj++)
#pragma unroll
        for (int r = 0; r < 4; r++) {
          int grow = m0 + wr * 64 + mi * 16 + g * 4 + r;
          int gcol = n0 + wc * (NW * 16) + nj * 16 + r16;
          if (grow < M) part[((i64)ks * M + grow) * N + gcol] = acc[mi][nj][r];
        }
  } else if (qkv) {
    u16* off16 = (u16*)C;
    u16* att16 = (u16*)C2;
#pragma unroll
    for (int mi = 0; mi < 4; mi++)
#pragma unroll
      for (int nj = 0; nj < NW; nj++)
#pragma unroll
        for (int r = 0; r < 4; r++) {
          int grow = m0 + wr * 64 + mi * 16 + g * 4 + r;
          int gcol = n0 + wc * (NW * 16) + nj * 16 + r16;
          if (grow < M) {
            float v = acc[mi][nj][r] + bias[gcol];
            if (gcol < 320) off16[(i64)grow * 320 + gcol] = f2bf(v);
            else if (gcol < 480) att16[(i64)grow * 160 + (gcol - 320)] = f2bf(v);
            else if (gcol < 736) C16[(i64)grow * 256 + (gcol - 480)] = f2bf(v);
          }
        }
  } else {
    float bv[NW];
    int gc0 = n0 + wc * (NW * 16) + r16;
#pragma unroll
    for (int nj = 0; nj < NW; nj++)
      bv[nj] = bias ? bias[gc0 + nj * 16] : 0.f;
    int mask = (1 << mbsh) - 1;
#pragma unroll
    for (int mi = 0; mi < 4; mi++) {
#pragma unroll
      for (int r = 0; r < 4; r++) {
        int grow = m0 + wr * 64 + mi * 16 + g * 4 + r;
        if (grow >= M) continue;
        i64 rowb = (i64)(grow >> mbsh) * bCz + (i64)(grow & mask) * sCm;
#pragma unroll
        for (int nj = 0; nj < NW; nj++) {
          int gcol = gc0 + nj * 16;
          if (gcol >= N) continue;
          float v = acc[mi][nj][r] + bv[nj];
          if (relu) v = fmaxf(v, 0.f);
          i64 ci = rowb + gcol;
          if (C16) C16[ci] = f2bf(v);
          else {
            if (addres) v += C[ci];
            C[ci] = v;
          }
        }
      }
    }
  }
}

// ---------------- fused FFN: feats += W2^T(relu(W1 q + b1)) + b2 ----------------
// block = 64 token rows; 16 chunks of 64 FFN dims; h stays in LDS (bf16).
// qb [>=M][256] bf16; w1n [1024][256] bf16 (n-major); w2n [256][1024] bf16.
__global__ __launch_bounds__(256) void ffn_fused_k(
    const u16* __restrict__ qb, const u16* __restrict__ w1n,
    const u16* __restrict__ w2n, const float* __restrict__ b1,
    const float* __restrict__ b2, float* __restrict__ feats, int M)
{
  __shared__ u16 As[64 * 256];    // q panel, swizzled
  __shared__ u16 B1s[64 * 256];   // w1 chunk rows, swizzled
  __shared__ u16 B2s[256 * 64];   // w2 chunk cols, swizzled
  __shared__ u16 Hs[64 * 64];     // h chunk bf16, swizzled
  __shared__ float b1s[1024];
  int tid = threadIdx.x;
  int lane = tid & 63, w = tid >> 6;
  int wr = w >> 1, wc = w & 1;
  int r16 = lane & 15, g = lane >> 4;
  int m0 = blockIdx.x * 64;

  for (int i = tid; i < 1024; i += 256) b1s[i] = b1[i];

  // stage A once: 64 rows x 256 cols (8 rounds of 256thr x 16B)
#pragma unroll
  for (int r = 0; r < 8; r++) {
    int s = r * 256 + tid;
    int row = s >> 5, c = s & 31;
    int cs = ((c ^ (row & 7)) << 3);
    __builtin_amdgcn_global_load_lds(
        (const __attribute__((address_space(1))) void*)(qb + (i64)(m0 + row) * 256 + cs),
        (__attribute__((address_space(3))) void*)(&As[(r * 256 + (w << 6)) << 3]),
        16, 0, 0);
  }

  f32x4 acc2[2][8];
#pragma unroll
  for (int mi = 0; mi < 2; mi++)
#pragma unroll
    for (int nj = 0; nj < 8; nj++) acc2[mi][nj] = (f32x4){0.f, 0.f, 0.f, 0.f};

  for (int ch = 0; ch < 16; ch++) {
    // stage B1 chunk: w1n rows [ch*64 .. ch*64+63] x 256 cols
#pragma unroll
    for (int r = 0; r < 8; r++) {
      int s = r * 256 + tid;
      int row = s >> 5, c = s & 31;
      int cs = ((c ^ (row & 7)) << 3);
      __builtin_amdgcn_global_load_lds(
          (const __attribute__((address_space(1))) void*)(w1n + (i64)(ch * 64 + row) * 256 + cs),
          (__attribute__((address_space(3))) void*)(&B1s[(r * 256 + (w << 6)) << 3]),
          16, 0, 0);
    }
    // stage B2 chunk: w2n all 256 rows x cols [ch*64 .. +63]
#pragma unroll
    for (int r = 0; r < 8; r++) {
      int s = r * 256 + tid;
      int row = s >> 3, c = s & 7;
      int cs = ((c ^ (row & 7)) << 3);
      __builtin_amdgcn_global_load_lds(
          (const __attribute__((address_space(1))) void*)(w2n + (i64)row * 1024 + ch * 64 + cs),
          (__attribute__((address_space(3))) void*)(&B2s[(r * 256 + (w << 6)) << 3]),
          16, 0, 0);
    }
    __syncthreads();   // tiles resident (incl. A on ch==0)

    // GEMM1: h[64 rows][64 cols] ; wave = (wr rows32, wc cols32)
    f32x4 acc1[2][2];
#pragma unroll
    for (int mi = 0; mi < 2; mi++)
#pragma unroll
      for (int nj = 0; nj < 2; nj++) acc1[mi][nj] = (f32x4){0.f, 0.f, 0.f, 0.f};
#pragma unroll
    for (int ks = 0; ks < 8; ks++) {
      short8 av[2], bv[2];
#pragma unroll
      for (int mi = 0; mi < 2; mi++) {
        int row = wr * 32 + mi * 16 + r16;
        av[mi] = *(const short8*)&As[row * 256 + ((((ks << 2) + g) ^ (row & 7)) << 3)];
      }
#pragma unroll
      for (int nj = 0; nj < 2; nj++) {
        int row = wc * 32 + nj * 16 + r16;
        bv[nj] = *(const short8*)&B1s[row * 256 + ((((ks << 2) + g) ^ (row & 7)) << 3)];
      }
#pragma unroll
      for (int mi = 0; mi < 2; mi++)
#pragma unroll
        for (int nj = 0; nj < 2; nj++)
          acc1[mi][nj] = __builtin_amdgcn_mfma_f32_16x16x32_bf16(
              av[mi], bv[nj], acc1[mi][nj], 0, 0, 0);
    }
    // h = relu(acc1 + b1) -> Hs (swizzled)
#pragma unroll
    for (int mi = 0; mi < 2; mi++)
#pragma unroll
      for (int nj = 0; nj < 2; nj++)
#pragma unroll
        for (int r = 0; r < 4; r++) {
          int row_h = wr * 32 + mi * 16 + g * 4 + r;
          int col_h = wc * 32 + nj * 16 + r16;
          float v = acc1[mi][nj][r] + b1s[ch * 64 + col_h];
          v = fmaxf(v, 0.f);
          Hs[row_h * 64 + (((col_h >> 3) ^ (row_h & 7)) << 3) + (col_h & 7)] = f2bf(v);
        }
    __syncthreads();   // Hs visible

    // GEMM2: rows wr*32 (2 frags), cols wc*128 (8 frags), K=64 (2 steps)
#pragma unroll
    for (int hh = 0; hh < 2; hh++) {
      short8 av2[2], bv2[8];
#pragma unroll
      for (int mi = 0; mi < 2; mi++) {
        int row = wr * 32 + mi * 16 + r16;
        av2[mi] = *(const short8*)&Hs[row * 64 + ((((hh << 2) + g) ^ (row & 7)) << 3)];
      }
#pragma unroll
      for (int nj = 0; nj < 8; nj++) {
        int n = wc * 128 + nj * 16 + r16;
        bv2[nj] = *(const short8*)&B2s[n * 64 + ((((hh << 2) + g) ^ (n & 7)) << 3)];
      }
#pragma unroll
      for (int mi = 0; mi < 2; mi++)
#pragma unroll
        for (int nj = 0; nj < 8; nj++)
          acc2[mi][nj] = __builtin_amdgcn_mfma_f32_16x16x32_bf16(
              av2[mi], bv2[nj], acc2[mi][nj], 0, 0, 0);
    }
    __syncthreads();   // safe to overwrite B1/B2/Hs
  }

  // epilogue: feats += acc2 + b2
#pragma unroll
  for (int mi = 0; mi < 2; mi++)
#pragma unroll
    for (int r = 0; r < 4; r++) {
      int grow = m0 + wr * 32 + mi * 16 + g * 4 + r;
      if (grow >= M) continue;
#pragma unroll
      for (int nj = 0; nj < 8; nj++) {
        int col = wc * 128 + nj * 16 + r16;
        i64 ci = (i64)grow * 256 + col;
        feats[ci] += acc2[mi][nj][r] + b2[col];
      }
    }
}

// reduce split-K fp32 partials (stride N); row map via shift/mask
__global__ void reduce_k(const float* __restrict__ part, float* __restrict__ C,
    const float* __restrict__ bias, int mbsh, i64 bCz, i64 sCm, int M, int N, int KS)
{
  int idx = blockIdx.x * 256 + threadIdx.x;
  if (idx >= M * N) return;
  int m = idx / N, n = idx - m * N;
  float v = bias ? bias[n] : 0.f;
  for (int ks = 0; ks < KS; ks++) v += part[((i64)ks * M + m) * N + n];
  C[(i64)(m >> mbsh) * bCz + (i64)(m & ((1 << mbsh) - 1)) * sCm + n] = v;
}

// ---------------- weight conversions ----------------
__global__ void cvt_w_pro_k(const float* __restrict__ pw0, const float* __restrict__ pw1,
    const float* __restrict__ pw2, const float* __restrict__ buw0,
    const float* __restrict__ buw1, u16* __restrict__ dst)
{
  int idx = blockIdx.x * 256 + threadIdx.x;
  if (idx >= 6225920) return;
  float v;
  if (idx < 131072) v = pw0[idx];
  else if (idx < 393216) v = pw1[idx - 131072];
  else if (idx < 917504) v = pw2[idx - 393216];
  else if (idx < 5636096) v = buw0[idx - 917504];
  else v = buw1[idx - 5636096];
  dst[idx] = f2bf(v);
}

__global__ void cvt_w_layer_k(const float* __restrict__ woff, const float* __restrict__ watt,
    const float* __restrict__ wval, const float* __restrict__ wout,
    const float* __restrict__ w1, const float* __restrict__ w2, u16* __restrict__ dst)
{
  int L = blockIdx.y;
  int o = blockIdx.x * 256 + threadIdx.x;
  if (o >= 786432) return;
  u16* d = dst + (i64)L * 786432;
  float v;
  if (o < 196608) {
    int n = o >> 8, k = o & 255;
    if (n < 320) v = woff[(i64)L * 81920 + k * 320 + n];
    else if (n < 480) v = watt[(i64)L * 40960 + k * 160 + (n - 320)];
    else if (n < 736) v = wval[(i64)L * 65536 + k * 256 + (n - 480)];
    else v = 0.f;
  } else if (o < 262144) {
    int o2 = o - 196608; int n = o2 >> 8, k = o2 & 255;
    v = wout[(i64)L * 65536 + k * 256 + n];
  } else if (o < 524288) {
    int o2 = o - 262144; int n = o2 >> 8, k = o2 & 255;
    v = w1[(i64)L * 262144 + (i64)k * 1024 + n];
  } else {
    int o2 = o - 524288; int n = o2 >> 10, k = o2 & 1023;
    v = w2[(i64)L * 262144 + (i64)k * 256 + n];
  }
  d[o] = f2bf(v);
}

__global__ void cvt_bias_k(const float* __restrict__ boff, const float* __restrict__ batt,
    const float* __restrict__ bval, float* __restrict__ bq)
{
  int idx = blockIdx.x * 256 + threadIdx.x;
  if (idx >= NLAYERS * 768) return;
  int L = idx / 768, n = idx - L * 768;
  float v;
  if (n < 320) v = boff[(i64)L * 320 + n];
  else if (n < 480) v = batt[(i64)L * 160 + (n - 320)];
  else if (n < 736) v = bval[(i64)L * 256 + (n - 480)];
  else v = 0.f;
  bq[idx] = v;
}

__global__ void cvt_a_proj_k(const float* __restrict__ in, u16* __restrict__ out,
                             int P, int K)
{
  i64 o = (i64)blockIdx.x * 256 + threadIdx.x;
  if (o >= (i64)2 * P * K) return;
  int m = (int)(o / K), k = (int)(o % K);
  int b = m / P, p = m - b * P;
  out[o] = f2bf(in[((i64)b * K + k) * P + p]);
}

__global__ void im2col_bf16_k(const float* __restrict__ in, u16* __restrict__ out,
    int Cin, int Hin, int Win, int Ho, int Wo)
{
  int Kk = Cin * 9;
  i64 total = (i64)2 * Ho * Wo * Kk;
  i64 o = (i64)blockIdx.x * 256 + threadIdx.x;
  if (o >= total) return;
  int k = (int)(o % Kk);
  int m = (int)(o / Kk);
  int hw = Ho * Wo;
  int b = m / hw, pix = m - b * hw;
  int oy = pix / Wo, ox = pix - oy * Wo;
  int ci = k / 9, r = k - ci * 9;
  int ky = r / 3, kx = r - ky * 3;
  int iy = oy * 2 - 1 + ky, ix = ox * 2 - 1 + kx;
  float v = 0.f;
  if (iy >= 0 && iy < Hin && ix >= 0 && ix < Win)
    v = in[(((i64)b * Cin + ci) * Hin + iy) * Win + ix];
  out[o] = f2bf(v);
}

__global__ void gn_relu_k(const float* __restrict__ feats, float* __restrict__ y,
    const float* __restrict__ g, const float* __restrict__ bt)
{
  int grp = blockIdx.x, b = blockIdx.y;
  int tid = threadIdx.x;
  const float* fb = feats + ((i64)b * NTOK + 5376) * 256 + grp * 32;
  float s = 0.f, ss = 0.f;
  for (int i = tid; i < 2048; i += 256) {
    int cl = i >> 6, p = i & 63;
    float v = fb[(i64)p * 256 + cl];
    s += v; ss += v * v;
  }
  __shared__ float sb[4], ssb[4];
#pragma unroll
  for (int o = 32; o > 0; o >>= 1) { s += __shfl_down(s, o); ss += __shfl_down(ss, o); }
  int wv = tid >> 6;
  if ((tid & 63) == 0) { sb[wv] = s; ssb[wv] = ss; }
  __syncthreads();
  float ts = sb[0] + sb[1] + sb[2] + sb[3];
  float tss = ssb[0] + ssb[1] + ssb[2] + ssb[3];
  float mean = ts * (1.f / 2048.f);
  float rs = rsqrtf(tss * (1.f / 2048.f) - mean * mean + 1e-5f);
  for (int i = tid; i < 2048; i += 256) {
    int cl = i >> 6, p = i & 63;
    int c = grp * 32 + cl;
    float v = (fb[(i64)p * 256 + cl] - mean) * rs * g[c] + bt[c];
    y[((i64)b * 256 + c) * 64 + p] = fmaxf(v, 0.f);
  }
}

__global__ __launch_bounds__(256) void ln_k(const float* __restrict__ x,
    u16* __restrict__ y, const float* __restrict__ g, const float* __restrict__ bt,
    int rows)
{
  int row = blockIdx.x * 4 + (threadIdx.x >> 6);
  if (row >= rows) return;
  int lane = threadIdx.x & 63;
  float4 v = ((const float4*)(x + (i64)row * 256))[lane];
  float s = v.x + v.y + v.z + v.w;
  float ss = v.x * v.x + v.y * v.y + v.z * v.z + v.w * v.w;
#pragma unroll
  for (int o = 32; o > 0; o >>= 1) { s += __shfl_down(s, o); ss += __shfl_down(ss, o); }
  s = __shfl(s, 0);
  ss = __shfl(ss, 0);
  float mean = s * (1.f / 256.f);
  float rs = rsqrtf(ss * (1.f / 256.f) - mean * mean + 1e-5f);
  float4 gg = ((const float4*)g)[lane];
  float4 bb = ((const float4*)bt)[lane];
  ushort4 o4;
  o4.x = f2bf((v.x - mean) * rs * gg.x + bb.x);
  o4.y = f2bf((v.y - mean) * rs * gg.y + bb.y);
  o4.z = f2bf((v.z - mean) * rs * gg.z + bb.z);
  o4.w = f2bf((v.w - mean) * rs * gg.w + bb.w);
  ((ushort4*)(y + (i64)row * 256))[lane] = o4;
}

// deformable sampling v5 (unchanged from round 7)
__global__ __launch_bounds__(256) void dsample_k(
    const u16* __restrict__ val, const u16* __restrict__ off,
    const u16* __restrict__ att, u16* __restrict__ out)
{
  const int FH[5] = {64, 32, 16, 8, 4};
  const int ST[5] = {0, 4096, 5120, 5376, 5440};
  int bid = blockIdx.x;
  int chunk = (bid & 7) * 86 + (bid >> 3);
  if (chunk >= 682) return;
  int lane = threadIdx.x & 63;
  int half = lane >> 5;
  int l32 = lane & 31;
  int t = chunk * 8 + ((threadIdx.x >> 6) << 1) + half;
  int b = blockIdx.y;
  int h = l32 >> 2, d4 = l32 & 3;

  int lv;
  if (t < 4096)      lv = 0;
  else if (t < 5120) lv = 1;
  else if (t < 5376) lv = 2;
  else if (t < 5440) lv = 3;
  else               lv = 4;
  int loc = t - ST[lv];
  int sh = 6 - lv;
  int py = loc >> sh, px = loc - (py << sh);
  float inv = 1.f / (float)FH[lv];
  float prx = (px + 0.5f) * inv, pry = (py + 0.5f) * inv;
  i64 bt = (i64)b * NTOK + t;
  const u16* offp = off + bt * 320 + h * 40;
  const u16* attp = att + bt * 160 + h * 20;
  const u16* vbase = val + ((i64)b * NTOK) * 256 + h * 32 + d4 * 8;

  float own_a[5], own_fx[5], own_fy[5];
  int own_pk[5];
  float mx = -1e30f;
#pragma unroll
  for (int j = 0; j < 5; j++) {
    float lg = bf2f(attp[d4 + 4 * j]);
    own_a[j] = lg;
    mx = fmaxf(mx, lg);
  }
  mx = fmaxf(mx, __shfl_xor(mx, 1));
  mx = fmaxf(mx, __shfl_xor(mx, 2));
  float sum = 0.f;
#pragma unroll
  for (int j = 0; j < 5; j++) {
    float e = __expf(own_a[j] - mx);
    own_a[j] = e;
    sum += e;
  }
  sum += __shfl_xor(sum, 1);
  sum += __shfl_xor(sum, 2);
  float rinv = 1.f / sum;
#pragma unroll
  for (int j = 0; j < 5; j++) {
    int p = d4 + 4 * j;
    own_a[j] *= rinv;
    unsigned opk = *(const unsigned*)(offp + 2 * p);
    float ox = bf2f((u16)(opk & 0xFFFF));
    float oy = bf2f((u16)(opk >> 16));
    float sff = (float)(64 >> j);
    float xx = prx * sff + ox - 0.5f;
    float yy = pry * sff + oy - 0.5f;
    float xf = floorf(xx), yf = floorf(yy);
    own_fx[j] = xx - xf;
    own_fy[j] = yy - yf;
    own_pk[j] = (((int)yf) << 16) | (((int)xf) & 0xFFFF);
  }

  float acc[8] = {0.f, 0.f, 0.f, 0.f, 0.f, 0.f, 0.f, 0.f};
#pragma unroll
  for (int p = 0; p < 20; p++) {
    const int j = p >> 2;
    const int sf = FH[j], st = ST[j];
    int src = (half << 5) | (h << 2) | (p & 3);
    float wa = __shfl(own_a[j], src);
    float fx = __shfl(own_fx[j], src);
    float fy = __shfl(own_fy[j], src);
    int pk = __shfl(own_pk[j], src);
    int x0 = (pk << 16) >> 16;
    int y0 = pk >> 16;
    float gx0 = wa - wa * fx, gx1 = wa * fx;
    float w00 = gx0 - gx0 * fy, w01 = gx0 * fy;
    float w10 = gx1 - gx1 * fy, w11 = gx1 * fy;
    bool xin0 = (x0 >= 0) & (x0 < sf), xin1 = (x0 + 1 >= 0) & (x0 + 1 < sf);
    bool yin0 = (y0 >= 0) & (y0 < sf), yin1 = (y0 + 1 >= 0) & (y0 + 1 < sf);
    int ibase = st + y0 * sf + x0;
#define FMA8(W, IDX) { \
      us8 v = *(const us8*)(vbase + (i64)(IDX) * 256); \
      acc[0] = fmaf(W, bf2f(v[0]), acc[0]); acc[1] = fmaf(W, bf2f(v[1]), acc[1]); \
      acc[2] = fmaf(W, bf2f(v[2]), acc[2]); acc[3] = fmaf(W, bf2f(v[3]), acc[3]); \
      acc[4] = fmaf(W, bf2f(v[4]), acc[4]); acc[5] = fmaf(W, bf2f(v[5]), acc[5]); \
      acc[6] = fmaf(W, bf2f(v[6]), acc[6]); acc[7] = fmaf(W, bf2f(v[7]), acc[7]); }
    if (xin0 & yin0) FMA8(w00, ibase);
    if (xin1 & yin0) FMA8(w10, ibase + 1);
    if (xin0 & yin1) FMA8(w01, ibase + sf);
    if (xin1 & yin1) FMA8(w11, ibase + sf + 1);
#undef FMA8
  }
  us8 o;
#pragma unroll
  for (int i = 0; i < 8; i++) o[i] = f2bf(acc[i]);
  *(us8*)(out + ((bt * 8 + h) * 32 + d4 * 8)) = o;
}

// all 5 levels in one dispatch
__global__ __launch_bounds__(256) void untranspose_all_k(
    const float* __restrict__ feats, float* __restrict__ out)
{
  int u = blockIdx.x;
  int pt0, start, S; i64 ooff;
  if (u < 128)      { pt0 = u;       start = 0;    S = 4096; ooff = 0; }
  else if (u < 160) { pt0 = u - 128; start = 4096; S = 1024; ooff = 2097152; }
  else if (u < 168) { pt0 = u - 160; start = 5120; S = 256;  ooff = 2621440; }
  else if (u < 170) { pt0 = u - 168; start = 5376; S = 64;   ooff = 2752512; }
  else              { pt0 = 0;       start = 5440; S = 16;   ooff = 2785280; }
  __shared__ float tile[32][33];
  int pt = pt0 * 32, ct = blockIdx.y * 32, b = blockIdx.z;
  int tx = threadIdx.x & 31, ty = threadIdx.x >> 5;
  for (int i = ty; i < 32; i += 8) {
    int p = pt + i;
    tile[i][tx] = (p < S) ? feats[((i64)b * NTOK + start + p) * 256 + ct + tx] : 0.f;
  }
  __syncthreads();
  for (int i = ty; i < 32; i += 8) {
    int c = ct + i, p = pt + tx;
    if (p < S) out[ooff + ((i64)b * 256 + c) * S + p] = tile[tx][i];
  }
}

extern "C" void kernel_launch(void* const* d_in, const int* in_sizes, int n_in,
                              void* d_out, int out_size, void* d_ws, size_t ws_size,
                              hipStream_t stream)
{
  const float* in0  = (const float*)d_in[0];
  const float* in1  = (const float*)d_in[1];
  const float* in2  = (const float*)d_in[2];
  const float* pw0  = (const float*)d_in[3];
  const float* pb0  = (const float*)d_in[4];
  const float* pw1  = (const float*)d_in[5];
  const float* pb1  = (const float*)d_in[6];
  const float* pw2  = (const float*)d_in[7];
  const float* pb2  = (const float*)d_in[8];
  const float* buw0 = (const float*)d_in[9];
  const float* bub0 = (const float*)d_in[10];
  const float* gng  = (const float*)d_in[11];
  const float* gnb  = (const float*)d_in[12];
  const float* buw1 = (const float*)d_in[13];
  const float* bub1 = (const float*)d_in[14];
  const float* ln1g = (const float*)d_in[15];
  const float* ln1b = (const float*)d_in[16];
  const float* woff = (const float*)d_in[17];
  const float* boff = (const float*)d_in[18];
  const float* watt = (const float*)d_in[19];
  const float* batt = (const float*)d_in[20];
  const float* wval = (const float*)d_in[21];
  const float* bval = (const float*)d_in[22];
  const float* wout = (const float*)d_in[23];
  const float* bout = (const float*)d_in[24];
  const float* ln2g = (const float*)d_in[25];
  const float* ln2b = (const float*)d_in[26];
  const float* w1   = (const float*)d_in[27];
  const float* b1   = (const float*)d_in[28];
  const float* w2   = (const float*)d_in[29];
  const float* b2   = (const float*)d_in[30];
  float* out = (float*)d_out;

  const i64 TC = (i64)NTOK * 256;

  // ---- ws layout (f32 units) ----
  float* ws    = (float*)d_ws;
  float* feats = ws;                               // 2,793,472
  u16*   qb    = (u16*)(feats + 2793472);          // 11008x256 bf16
  u16*   valb  = qb + 2818048;
  u16*   sampb = valb + 2818048;
  float* U     = (float*)(sampb + 2818048);        // union region: 5,637,120 f32
  u16*   off16 = (u16*)U;                          // [10912][320] bf16
  u16*   att16 = off16 + 3491840;                  // [10912][160] bf16
  u16*   abuf  = (u16*)U;                          // prologue A
  float* part  = U + 2097152;                      // split-K partials
  u16*   wb    = (u16*)(U + 5637120);              // 10,944,512 bf16
  float* bqkv  = (float*)(wb + 10944512);          // 4,608 f32
  float* m4gn  = bqkv + 4608;                      // 32,768 f32

  auto mg128 = [&](dim3 grid, const u16* A, const u16* B, int K,
                   float* C, float* C2, u16* C16, i64 sCm, const float* bias,
                   int relu, int addres, int qkv, int M, int N, int mbsh, i64 bCz, int KS) {
    mgemm_k<128><<<grid, dim3(256), 0, stream>>>(A, B, K, C, C2, C16, sCm, bias,
        relu, addres, qkv, M, N, mbsh, bCz, KS, part);
  };
  auto mg64 = [&](dim3 grid, const u16* A, const u16* B, int K,
                  float* C, u16* C16, i64 sCm, const float* bias,
                  int relu, int addres, int M, int N, int mbsh, i64 bCz, int KS) {
    mgemm_k<64><<<grid, dim3(256), 0, stream>>>(A, B, K, C, nullptr, C16, sCm, bias,
        relu, addres, 0, M, N, mbsh, bCz, KS, part);
  };

  // ---- weight conversion ----
  cvt_w_pro_k<<<dim3(24320), dim3(256), 0, stream>>>(pw0, pw1, pw2, buw0, buw1, wb);
  cvt_w_layer_k<<<dim3(3072, NLAYERS), dim3(256), 0, stream>>>(
      woff, watt, wval, wout, w1, w2, wb + 6225920);
  cvt_bias_k<<<dim3(18), dim3(256), 0, stream>>>(boff, batt, bval, bqkv);

  // ---- projections ----
  cvt_a_proj_k<<<dim3(16384), dim3(256), 0, stream>>>(in0, abuf, 4096, 512);
  mg64(dim3(64, 4, 1), abuf, wb, 512, feats, nullptr, 256, pb0, 0, 0,
       8192, 256, 12, TC, 1);
  cvt_a_proj_k<<<dim3(8192), dim3(256), 0, stream>>>(in1, abuf, 1024, 1024);
  mg64(dim3(16, 4, 2), abuf, wb + 131072, 1024, nullptr, nullptr, 256, nullptr, 0, 0,
       2048, 256, 10, 0, 2);
  reduce_k<<<dim3(2048), dim3(256), 0, stream>>>(part, feats + (i64)4096 * 256, pb1,
      10, TC, 256, 2048, 256, 2);
  cvt_a_proj_k<<<dim3(4096), dim3(256), 0, stream>>>(in2, abuf, 256, 2048);
  mg64(dim3(4, 4, 4), abuf, wb + 393216, 2048, nullptr, nullptr, 256, nullptr, 0, 0,
       512, 256, 8, 0, 4);
  reduce_k<<<dim3(512), dim3(256), 0, stream>>>(part, feats + (i64)5120 * 256, pb2,
      8, TC, 256, 512, 256, 4);

  // ---- bottom-up conv0 ----
  im2col_bf16_k<<<dim3(9216), dim3(256), 0, stream>>>(in2, abuf, 2048, 16, 16, 8, 8);
  mg64(dim3(1, 4, 16), abuf, wb + 917504, 18432, nullptr, nullptr, 256, nullptr, 0, 0,
       128, 256, 6, 0, 16);
  reduce_k<<<dim3(128), dim3(256), 0, stream>>>(part, feats + (i64)5376 * 256, bub0,
      6, TC, 256, 128, 256, 16);

  // ---- GN+ReLU, bottom-up conv1 ----
  gn_relu_k<<<dim3(8, 2), dim3(256), 0, stream>>>(feats, m4gn, gng, gnb);
  im2col_bf16_k<<<dim3(288), dim3(256), 0, stream>>>(m4gn, abuf, 256, 8, 8, 4, 4);
  mg64(dim3(1, 4, 4), abuf, wb + 5636096, 2304, nullptr, nullptr, 256, nullptr, 0, 0,
       32, 256, 4, 0, 4);
  reduce_k<<<dim3(32), dim3(256), 0, stream>>>(part, feats + (i64)5440 * 256, bub1,
      4, TC, 256, 32, 256, 4);

  // ---- 6 transformer layers ----
  for (int i = 0; i < NLAYERS; i++) {
    const u16* wbL = wb + 6225920 + (i64)i * 786432;
    ln_k<<<dim3(2728), dim3(256), 0, stream>>>(feats, qb,
        ln1g + (i64)i * 256, ln1b + (i64)i * 256, BNROWS);
    // fused off|att|val GEMM, N=768; off/att written as bf16
    mg128(dim3(86, 6, 1), qb, wbL, 256, (float*)off16, (float*)att16, valb, 0,
          bqkv + (i64)i * 768, 0, 0, 1, BNROWS, 768, 14, 0, 1);
    dsample_k<<<dim3(688, 2), dim3(256), 0, stream>>>(valb, off16, att16, sampb);
    mg64(dim3(86, 4, 1), sampb, wbL + 196608, 256, feats, nullptr, 256,
         bout + (i64)i * 256, 0, 1, BNROWS, 256, 14, 0, 1);
    ln_k<<<dim3(2728), dim3(256), 0, stream>>>(feats, qb,
        ln2g + (i64)i * 256, ln2b + (i64)i * 256, BNROWS);
    // fused FFN (h stays in LDS)
    ffn_fused_k<<<dim3(171), dim3(256), 0, stream>>>(qb, wbL + 262144,
        wbL + 524288, b1 + (i64)i * 1024, b2 + (i64)i * 256, feats, BNROWS);
  }

  // ---- split into 5 level maps (one dispatch) ----
  untranspose_all_k<<<dim3(171, 8, 2), dim3(256), 0, stream>>>(feats, out);
  (void)in_sizes; (void)n_in; (void)out_size; (void)ws_size;
}

// Round 10
// 1008.931 us; speedup vs baseline: 7.9485x; 1.0041x over previous
//
#include <hip/hip_runtime.h>
#include <cstdint>

typedef long long i64;
typedef unsigned short u16;
typedef __attribute__((ext_vector_type(8))) short short8;
typedef __attribute__((ext_vector_type(8))) unsigned short us8;
typedef __attribute__((ext_vector_type(4))) float f32x4;

#define NTOK 5456
#define BNROWS 10912
#define NLAYERS 6

__device__ __forceinline__ u16 f2bf(float f) {
  unsigned u = __float_as_uint(f);
  return (u16)((u + 0x7FFFu + ((u >> 16) & 1u)) >> 16);
}
__device__ __forceinline__ float bf2f(u16 h) {
  return __uint_as_float(((unsigned)h) << 16);
}

// ---------------- bf16 MFMA GEMM, 2-phase double-buffered ----------------
template<int BNT>
__global__ __launch_bounds__(256) void mgemm_k(
    const u16* __restrict__ A, const u16* __restrict__ B, int K,
    float* __restrict__ C, float* __restrict__ C2, u16* __restrict__ C16, i64 sCm,
    const float* __restrict__ bias, int relu, int addres, int qkv,
    int M, int N, int mbsh, i64 bCz,
    int KS, float* __restrict__ part)
{
  constexpr int NW = BNT / 32;
  __shared__ u16 Asm[2][128 * 64];
  __shared__ u16 Bsm[2][BNT * 64];
  int tid = threadIdx.x;

  int bx = blockIdx.x, by = blockIdx.y;
  int gx = gridDim.x, gy = gridDim.y;
  int nwg = gx * gy;
  if (KS == 1 && nwg >= 16) {
    int lin = bx + gx * by;
    int xcd = lin & 7, k = lin >> 3;
    int q = nwg >> 3, r = nwg & 7;
    int f = (xcd < r) ? (xcd * (q + 1) + k) : (r * (q + 1) + (xcd - r) * q + k);
    bx = f / gy;
    by = f - bx * gy;
  }
  int m0 = bx * 128, n0 = by * BNT;

  int ks = blockIdx.z;
  int Kc = K / KS;
  int k0 = ks * Kc;
  int lane = tid & 63, w = tid >> 6;
  int wr = w >> 1, wc = w & 1;
  int r16 = lane & 15, g = lane >> 4;

  f32x4 acc[4][NW];
#pragma unroll
  for (int mi = 0; mi < 4; mi++)
#pragma unroll
    for (int nj = 0; nj < NW; nj++) acc[mi][nj] = (f32x4){0.f, 0.f, 0.f, 0.f};

  const u16* Ag = A + (i64)m0 * K + k0;
  const u16* Bg = B + (i64)n0 * K + k0;
  int nt = Kc >> 6;

  auto stage = [&](int buf, int kt) {
#pragma unroll
    for (int r = 0; r < 4; r++) {
      int s = r * 256 + tid;
      int row = s >> 3, c = s & 7;
      int cs = ((c ^ (row & 7)) << 3);
      __builtin_amdgcn_global_load_lds(
          (const __attribute__((address_space(1))) void*)(Ag + (i64)row * K + kt + cs),
          (__attribute__((address_space(3))) void*)(&Asm[buf][(r * 256 + (w << 6)) << 3]),
          16, 0, 0);
    }
#pragma unroll
    for (int r = 0; r < NW; r++) {
      int s = r * 256 + tid;
      int row = s >> 3, c = s & 7;
      int cs = ((c ^ (row & 7)) << 3);
      __builtin_amdgcn_global_load_lds(
          (const __attribute__((address_space(1))) void*)(Bg + (i64)row * K + kt + cs),
          (__attribute__((address_space(3))) void*)(&Bsm[buf][(r * 256 + (w << 6)) << 3]),
          16, 0, 0);
    }
  };

  stage(0, 0);
  __syncthreads();
  for (int t = 0; t < nt; t++) {
    int cur = t & 1;
    if (t + 1 < nt) stage(cur ^ 1, (t + 1) << 6);
#pragma unroll
    for (int h = 0; h < 2; h++) {
      short8 av[4], bv[NW];
#pragma unroll
      for (int mi = 0; mi < 4; mi++) {
        int row = wr * 64 + mi * 16 + r16;
        av[mi] = *(const short8*)&Asm[cur][row * 64 + ((((h << 2) + g) ^ (row & 7)) << 3)];
      }
#pragma unroll
      for (int nj = 0; nj < NW; nj++) {
        int row = wc * (NW * 16) + nj * 16 + r16;
        bv[nj] = *(const short8*)&Bsm[cur][row * 64 + ((((h << 2) + g) ^ (row & 7)) << 3)];
      }
#pragma unroll
      for (int mi = 0; mi < 4; mi++)
#pragma unroll
        for (int nj = 0; nj < NW; nj++)
          acc[mi][nj] = __builtin_amdgcn_mfma_f32_16x16x32_bf16(
              av[mi], bv[nj], acc[mi][nj], 0, 0, 0);
    }
    __syncthreads();
  }

  if (KS > 1) {
#pragma unroll
    for (int mi = 0; mi < 4; mi++)
#pragma unroll
      for (int nj = 0; nj < NW; nj++)
#pragma unroll
        for (int r = 0; r < 4; r++) {
          int grow = m0 + wr * 64 + mi * 16 + g * 4 + r;
          int gcol = n0 + wc * (NW * 16) + nj * 16 + r16;
          if (grow < M) part[((i64)ks * M + grow) * N + gcol] = acc[mi][nj][r];
        }
  } else if (qkv) {
    u16* off16 = (u16*)C;
    u16* att16 = (u16*)C2;
#pragma unroll
    for (int mi = 0; mi < 4; mi++)
#pragma unroll
      for (int nj = 0; nj < NW; nj++)
#pragma unroll
        for (int r = 0; r < 4; r++) {
          int grow = m0 + wr * 64 + mi * 16 + g * 4 + r;
          int gcol = n0 + wc * (NW * 16) + nj * 16 + r16;
          if (grow < M) {
            float v = acc[mi][nj][r] + bias[gcol];
            if (gcol < 320) off16[(i64)grow * 320 + gcol] = f2bf(v);
            else if (gcol < 480) att16[(i64)grow * 160 + (gcol - 320)] = f2bf(v);
            else if (gcol < 736) C16[(i64)grow * 256 + (gcol - 480)] = f2bf(v);
          }
        }
  } else {
    float bv[NW];
    int gc0 = n0 + wc * (NW * 16) + r16;
#pragma unroll
    for (int nj = 0; nj < NW; nj++)
      bv[nj] = bias ? bias[gc0 + nj * 16] : 0.f;
    int mask = (1 << mbsh) - 1;
#pragma unroll
    for (int mi = 0; mi < 4; mi++) {
#pragma unroll
      for (int r = 0; r < 4; r++) {
        int grow = m0 + wr * 64 + mi * 16 + g * 4 + r;
        if (grow >= M) continue;
        i64 rowb = (i64)(grow >> mbsh) * bCz + (i64)(grow & mask) * sCm;
#pragma unroll
        for (int nj = 0; nj < NW; nj++) {
          int gcol = gc0 + nj * 16;
          if (gcol >= N) continue;
          float v = acc[mi][nj][r] + bv[nj];
          if (relu) v = fmaxf(v, 0.f);
          i64 ci = rowb + gcol;
          if (C16) C16[ci] = f2bf(v);
          else {
            if (addres) v += C[ci];
            C[ci] = v;
          }
        }
      }
    }
  }
}

// ---------------- fused FFN v2: feats += W2^T(relu(W1 q + b1)) + b2 ----------
// block = 64 token rows; 16 chunks of 64 FFN dims.
// A-panel in REGISTERS (16 short8/lane); weight tiles double-buffered in LDS
// with prefetch overlapping GEMM1; h bounces through padded LDS (stride 88).
__global__ __launch_bounds__(256, 1) void ffn_fused_k(
    const u16* __restrict__ qb, const u16* __restrict__ w1n,
    const u16* __restrict__ w2n, const float* __restrict__ b1,
    const float* __restrict__ b2, float* __restrict__ feats, int M)
{
  __shared__ u16 B1s[2][64 * 256];   // w1 chunk rows, swizzled (32KB each)
  __shared__ u16 B2s[2][256 * 64];   // w2 chunk cols, swizzled (32KB each)
  __shared__ u16 Hs[64 * 88];        // h chunk bf16, padded stride 88
  __shared__ float b1s[1024];
  int tid = threadIdx.x;
  int lane = tid & 63, w = tid >> 6;
  int wr = w >> 1, wc = w & 1;
  int r16 = lane & 15, g = lane >> 4;
  int m0 = blockIdx.x * 64;

  for (int i = tid; i < 1024; i += 256) b1s[i] = b1[i];

  // A-panel into registers: av_all[ks][mi] = A[wr*32+mi*16+r16][ks*32+g*8 ..+7]
  short8 av_all[8][2];
#pragma unroll
  for (int ks = 0; ks < 8; ks++)
#pragma unroll
    for (int mi = 0; mi < 2; mi++) {
      int row = m0 + wr * 32 + mi * 16 + r16;
      av_all[ks][mi] = *(const short8*)(qb + (i64)row * 256 + ks * 32 + g * 8);
    }

  auto stageW = [&](int buf, int ch) {
    // B1 chunk: w1n rows [ch*64 .. +63] x 256 k (8 rounds)
#pragma unroll
    for (int r = 0; r < 8; r++) {
      int s = r * 256 + tid;
      int row = s >> 5, c = s & 31;
      int cs = ((c ^ (row & 7)) << 3);
      __builtin_amdgcn_global_load_lds(
          (const __attribute__((address_space(1))) void*)(w1n + (i64)(ch * 64 + row) * 256 + cs),
          (__attribute__((address_space(3))) void*)(&B1s[buf][(r * 256 + (w << 6)) << 3]),
          16, 0, 0);
    }
    // B2 chunk: w2n 256 n-rows x k [ch*64 .. +63] (8 rounds)
#pragma unroll
    for (int r = 0; r < 8; r++) {
      int s = r * 256 + tid;
      int row = s >> 3, c = s & 7;
      int cs = ((c ^ (row & 7)) << 3);
      __builtin_amdgcn_global_load_lds(
          (const __attribute__((address_space(1))) void*)(w2n + (i64)row * 1024 + ch * 64 + cs),
          (__attribute__((address_space(3))) void*)(&B2s[buf][(r * 256 + (w << 6)) << 3]),
          16, 0, 0);
    }
  };

  f32x4 acc2[2][8];
#pragma unroll
  for (int mi = 0; mi < 2; mi++)
#pragma unroll
    for (int nj = 0; nj < 8; nj++) acc2[mi][nj] = (f32x4){0.f, 0.f, 0.f, 0.f};

  stageW(0, 0);
  __syncthreads();   // chunk 0 resident

  int cur = 0;
  for (int ch = 0; ch < 16; ch++) {
    if (ch + 1 < 16) stageW(cur ^ 1, ch + 1);   // prefetch; drains at mid-barrier

    // GEMM1: h[64][64], A from regs, B1 from LDS. acc1[2 m][2 n]
    f32x4 acc1[2][2];
#pragma unroll
    for (int mi = 0; mi < 2; mi++)
#pragma unroll
      for (int nj = 0; nj < 2; nj++) acc1[mi][nj] = (f32x4){0.f, 0.f, 0.f, 0.f};
#pragma unroll
    for (int ks = 0; ks < 8; ks++) {
      short8 bv[2];
#pragma unroll
      for (int nj = 0; nj < 2; nj++) {
        int row = wc * 32 + nj * 16 + r16;
        bv[nj] = *(const short8*)&B1s[cur][row * 256 + ((((ks << 2) + g) ^ (row & 7)) << 3)];
      }
#pragma unroll
      for (int mi = 0; mi < 2; mi++)
#pragma unroll
        for (int nj = 0; nj < 2; nj++)
          acc1[mi][nj] = __builtin_amdgcn_mfma_f32_16x16x32_bf16(
              av_all[ks][mi], bv[nj], acc1[mi][nj], 0, 0, 0);
    }
    // h = relu(acc1 + b1) -> Hs (padded linear, stride 88)
#pragma unroll
    for (int mi = 0; mi < 2; mi++)
#pragma unroll
      for (int nj = 0; nj < 2; nj++)
#pragma unroll
        for (int r = 0; r < 4; r++) {
          int row_h = wr * 32 + mi * 16 + g * 4 + r;
          int col_h = wc * 32 + nj * 16 + r16;
          float v = acc1[mi][nj][r] + b1s[ch * 64 + col_h];
          Hs[row_h * 88 + col_h] = f2bf(fmaxf(v, 0.f));
        }
    __syncthreads();   // Hs visible (also drains prefetch vmcnt — overlapped w/ GEMM1)

    // GEMM2: rows wr*32 (2 frags), cols wc*128 (8 frags), K=64 (2 steps)
#pragma unroll
    for (int hh = 0; hh < 2; hh++) {
      short8 av2[2], bv2[8];
#pragma unroll
      for (int mi = 0; mi < 2; mi++) {
        int row = wr * 32 + mi * 16 + r16;
        av2[mi] = *(const short8*)&Hs[row * 88 + ((hh << 2) + g) * 8];
      }
#pragma unroll
      for (int nj = 0; nj < 8; nj++) {
        int n = wc * 128 + nj * 16 + r16;
        bv2[nj] = *(const short8*)&B2s[cur][n * 64 + ((((hh << 2) + g) ^ (n & 7)) << 3)];
      }
#pragma unroll
      for (int mi = 0; mi < 2; mi++)
#pragma unroll
        for (int nj = 0; nj < 8; nj++)
          acc2[mi][nj] = __builtin_amdgcn_mfma_f32_16x16x32_bf16(
              av2[mi], bv2[nj], acc2[mi][nj], 0, 0, 0);
    }
    __syncthreads();   // all reads of buf[cur]/Hs done before next overwrite
    cur ^= 1;
  }

  // epilogue: feats += acc2 + b2
#pragma unroll
  for (int mi = 0; mi < 2; mi++)
#pragma unroll
    for (int r = 0; r < 4; r++) {
      int grow = m0 + wr * 32 + mi * 16 + g * 4 + r;
      if (grow >= M) continue;
#pragma unroll
      for (int nj = 0; nj < 8; nj++) {
        int col = wc * 128 + nj * 16 + r16;
        i64 ci = (i64)grow * 256 + col;
        feats[ci] += acc2[mi][nj][r] + b2[col];
      }
    }
}

// reduce split-K fp32 partials (stride N); row map via shift/mask
__global__ void reduce_k(const float* __restrict__ part, float* __restrict__ C,
    const float* __restrict__ bias, int mbsh, i64 bCz, i64 sCm, int M, int N, int KS)
{
  int idx = blockIdx.x * 256 + threadIdx.x;
  if (idx >= M * N) return;
  int m = idx / N, n = idx - m * N;
  float v = bias ? bias[n] : 0.f;
  for (int ks = 0; ks < KS; ks++) v += part[((i64)ks * M + m) * N + n];
  C[(i64)(m >> mbsh) * bCz + (i64)(m & ((1 << mbsh) - 1)) * sCm + n] = v;
}

// ---------------- weight conversions ----------------
__global__ void cvt_w_pro_k(const float* __restrict__ pw0, const float* __restrict__ pw1,
    const float* __restrict__ pw2, const float* __restrict__ buw0,
    const float* __restrict__ buw1, u16* __restrict__ dst)
{
  int idx = blockIdx.x * 256 + threadIdx.x;
  if (idx >= 6225920) return;
  float v;
  if (idx < 131072) v = pw0[idx];
  else if (idx < 393216) v = pw1[idx - 131072];
  else if (idx < 917504) v = pw2[idx - 393216];
  else if (idx < 5636096) v = buw0[idx - 917504];
  else v = buw1[idx - 5636096];
  dst[idx] = f2bf(v);
}

__global__ void cvt_w_layer_k(const float* __restrict__ woff, const float* __restrict__ watt,
    const float* __restrict__ wval, const float* __restrict__ wout,
    const float* __restrict__ w1, const float* __restrict__ w2, u16* __restrict__ dst)
{
  int L = blockIdx.y;
  int o = blockIdx.x * 256 + threadIdx.x;
  if (o >= 786432) return;
  u16* d = dst + (i64)L * 786432;
  float v;
  if (o < 196608) {
    int n = o >> 8, k = o & 255;
    if (n < 320) v = woff[(i64)L * 81920 + k * 320 + n];
    else if (n < 480) v = watt[(i64)L * 40960 + k * 160 + (n - 320)];
    else if (n < 736) v = wval[(i64)L * 65536 + k * 256 + (n - 480)];
    else v = 0.f;
  } else if (o < 262144) {
    int o2 = o - 196608; int n = o2 >> 8, k = o2 & 255;
    v = wout[(i64)L * 65536 + k * 256 + n];
  } else if (o < 524288) {
    int o2 = o - 262144; int n = o2 >> 8, k = o2 & 255;
    v = w1[(i64)L * 262144 + (i64)k * 1024 + n];
  } else {
    int o2 = o - 524288; int n = o2 >> 10, k = o2 & 1023;
    v = w2[(i64)L * 262144 + (i64)k * 256 + n];
  }
  d[o] = f2bf(v);
}

__global__ void cvt_bias_k(const float* __restrict__ boff, const float* __restrict__ batt,
    const float* __restrict__ bval, float* __restrict__ bq)
{
  int idx = blockIdx.x * 256 + threadIdx.x;
  if (idx >= NLAYERS * 768) return;
  int L = idx / 768, n = idx - L * 768;
  float v;
  if (n < 320) v = boff[(i64)L * 320 + n];
  else if (n < 480) v = batt[(i64)L * 160 + (n - 320)];
  else if (n < 736) v = bval[(i64)L * 256 + (n - 480)];
  else v = 0.f;
  bq[idx] = v;
}

__global__ void cvt_a_proj_k(const float* __restrict__ in, u16* __restrict__ out,
                             int P, int K)
{
  i64 o = (i64)blockIdx.x * 256 + threadIdx.x;
  if (o >= (i64)2 * P * K) return;
  int m = (int)(o / K), k = (int)(o % K);
  int b = m / P, p = m - b * P;
  out[o] = f2bf(in[((i64)b * K + k) * P + p]);
}

__global__ void im2col_bf16_k(const float* __restrict__ in, u16* __restrict__ out,
    int Cin, int Hin, int Win, int Ho, int Wo)
{
  int Kk = Cin * 9;
  i64 total = (i64)2 * Ho * Wo * Kk;
  i64 o = (i64)blockIdx.x * 256 + threadIdx.x;
  if (o >= total) return;
  int k = (int)(o % Kk);
  int m = (int)(o / Kk);
  int hw = Ho * Wo;
  int b = m / hw, pix = m - b * hw;
  int oy = pix / Wo, ox = pix - oy * Wo;
  int ci = k / 9, r = k - ci * 9;
  int ky = r / 3, kx = r - ky * 3;
  int iy = oy * 2 - 1 + ky, ix = ox * 2 - 1 + kx;
  float v = 0.f;
  if (iy >= 0 && iy < Hin && ix >= 0 && ix < Win)
    v = in[(((i64)b * Cin + ci) * Hin + iy) * Win + ix];
  out[o] = f2bf(v);
}

__global__ void gn_relu_k(const float* __restrict__ feats, float* __restrict__ y,
    const float* __restrict__ g, const float* __restrict__ bt)
{
  int grp = blockIdx.x, b = blockIdx.y;
  int tid = threadIdx.x;
  const float* fb = feats + ((i64)b * NTOK + 5376) * 256 + grp * 32;
  float s = 0.f, ss = 0.f;
  for (int i = tid; i < 2048; i += 256) {
    int cl = i >> 6, p = i & 63;
    float v = fb[(i64)p * 256 + cl];
    s += v; ss += v * v;
  }
  __shared__ float sb[4], ssb[4];
#pragma unroll
  for (int o = 32; o > 0; o >>= 1) { s += __shfl_down(s, o); ss += __shfl_down(ss, o); }
  int wv = tid >> 6;
  if ((tid & 63) == 0) { sb[wv] = s; ssb[wv] = ss; }
  __syncthreads();
  float ts = sb[0] + sb[1] + sb[2] + sb[3];
  float tss = ssb[0] + ssb[1] + ssb[2] + ssb[3];
  float mean = ts * (1.f / 2048.f);
  float rs = rsqrtf(tss * (1.f / 2048.f) - mean * mean + 1e-5f);
  for (int i = tid; i < 2048; i += 256) {
    int cl = i >> 6, p = i & 63;
    int c = grp * 32 + cl;
    float v = (fb[(i64)p * 256 + cl] - mean) * rs * g[c] + bt[c];
    y[((i64)b * 256 + c) * 64 + p] = fmaxf(v, 0.f);
  }
}

__global__ __launch_bounds__(256) void ln_k(const float* __restrict__ x,
    u16* __restrict__ y, const float* __restrict__ g, const float* __restrict__ bt,
    int rows)
{
  int row = blockIdx.x * 4 + (threadIdx.x >> 6);
  if (row >= rows) return;
  int lane = threadIdx.x & 63;
  float4 v = ((const float4*)(x + (i64)row * 256))[lane];
  float s = v.x + v.y + v.z + v.w;
  float ss = v.x * v.x + v.y * v.y + v.z * v.z + v.w * v.w;
#pragma unroll
  for (int o = 32; o > 0; o >>= 1) { s += __shfl_down(s, o); ss += __shfl_down(ss, o); }
  s = __shfl(s, 0);
  ss = __shfl(ss, 0);
  float mean = s * (1.f / 256.f);
  float rs = rsqrtf(ss * (1.f / 256.f) - mean * mean + 1e-5f);
  float4 gg = ((const float4*)g)[lane];
  float4 bb = ((const float4*)bt)[lane];
  ushort4 o4;
  o4.x = f2bf((v.x - mean) * rs * gg.x + bb.x);
  o4.y = f2bf((v.y - mean) * rs * gg.y + bb.y);
  o4.z = f2bf((v.z - mean) * rs * gg.z + bb.z);
  o4.w = f2bf((v.w - mean) * rs * gg.w + bb.w);
  ((ushort4*)(y + (i64)row * 256))[lane] = o4;
}

// deformable sampling v5 (unchanged)
__global__ __launch_bounds__(256) void dsample_k(
    const u16* __restrict__ val, const u16* __restrict__ off,
    const u16* __restrict__ att, u16* __restrict__ out)
{
  const int FH[5] = {64, 32, 16, 8, 4};
  const int ST[5] = {0, 4096, 5120, 5376, 5440};
  int bid = blockIdx.x;
  int chunk = (bid & 7) * 86 + (bid >> 3);
  if (chunk >= 682) return;
  int lane = threadIdx.x & 63;
  int half = lane >> 5;
  int l32 = lane & 31;
  int t = chunk * 8 + ((threadIdx.x >> 6) << 1) + half;
  int b = blockIdx.y;
  int h = l32 >> 2, d4 = l32 & 3;

  int lv;
  if (t < 4096)      lv = 0;
  else if (t < 5120) lv = 1;
  else if (t < 5376) lv = 2;
  else if (t < 5440) lv = 3;
  else               lv = 4;
  int loc = t - ST[lv];
  int sh = 6 - lv;
  int py = loc >> sh, px = loc - (py << sh);
  float inv = 1.f / (float)FH[lv];
  float prx = (px + 0.5f) * inv, pry = (py + 0.5f) * inv;
  i64 bt = (i64)b * NTOK + t;
  const u16* offp = off + bt * 320 + h * 40;
  const u16* attp = att + bt * 160 + h * 20;
  const u16* vbase = val + ((i64)b * NTOK) * 256 + h * 32 + d4 * 8;

  float own_a[5], own_fx[5], own_fy[5];
  int own_pk[5];
  float mx = -1e30f;
#pragma unroll
  for (int j = 0; j < 5; j++) {
    float lg = bf2f(attp[d4 + 4 * j]);
    own_a[j] = lg;
    mx = fmaxf(mx, lg);
  }
  mx = fmaxf(mx, __shfl_xor(mx, 1));
  mx = fmaxf(mx, __shfl_xor(mx, 2));
  float sum = 0.f;
#pragma unroll
  for (int j = 0; j < 5; j++) {
    float e = __expf(own_a[j] - mx);
    own_a[j] = e;
    sum += e;
  }
  sum += __shfl_xor(sum, 1);
  sum += __shfl_xor(sum, 2);
  float rinv = 1.f / sum;
#pragma unroll
  for (int j = 0; j < 5; j++) {
    int p = d4 + 4 * j;
    own_a[j] *= rinv;
    unsigned opk = *(const unsigned*)(offp + 2 * p);
    float ox = bf2f((u16)(opk & 0xFFFF));
    float oy = bf2f((u16)(opk >> 16));
    float sff = (float)(64 >> j);
    float xx = prx * sff + ox - 0.5f;
    float yy = pry * sff + oy - 0.5f;
    float xf = floorf(xx), yf = floorf(yy);
    own_fx[j] = xx - xf;
    own_fy[j] = yy - yf;
    own_pk[j] = (((int)yf) << 16) | (((int)xf) & 0xFFFF);
  }

  float acc[8] = {0.f, 0.f, 0.f, 0.f, 0.f, 0.f, 0.f, 0.f};
#pragma unroll
  for (int p = 0; p < 20; p++) {
    const int j = p >> 2;
    const int sf = FH[j], st = ST[j];
    int src = (half << 5) | (h << 2) | (p & 3);
    float wa = __shfl(own_a[j], src);
    float fx = __shfl(own_fx[j], src);
    float fy = __shfl(own_fy[j], src);
    int pk = __shfl(own_pk[j], src);
    int x0 = (pk << 16) >> 16;
    int y0 = pk >> 16;
    float gx0 = wa - wa * fx, gx1 = wa * fx;
    float w00 = gx0 - gx0 * fy, w01 = gx0 * fy;
    float w10 = gx1 - gx1 * fy, w11 = gx1 * fy;
    bool xin0 = (x0 >= 0) & (x0 < sf), xin1 = (x0 + 1 >= 0) & (x0 + 1 < sf);
    bool yin0 = (y0 >= 0) & (y0 < sf), yin1 = (y0 + 1 >= 0) & (y0 + 1 < sf);
    int ibase = st + y0 * sf + x0;
#define FMA8(W, IDX) { \
      us8 v = *(const us8*)(vbase + (i64)(IDX) * 256); \
      acc[0] = fmaf(W, bf2f(v[0]), acc[0]); acc[1] = fmaf(W, bf2f(v[1]), acc[1]); \
      acc[2] = fmaf(W, bf2f(v[2]), acc[2]); acc[3] = fmaf(W, bf2f(v[3]), acc[3]); \
      acc[4] = fmaf(W, bf2f(v[4]), acc[4]); acc[5] = fmaf(W, bf2f(v[5]), acc[5]); \
      acc[6] = fmaf(W, bf2f(v[6]), acc[6]); acc[7] = fmaf(W, bf2f(v[7]), acc[7]); }
    if (xin0 & yin0) FMA8(w00, ibase);
    if (xin1 & yin0) FMA8(w10, ibase + 1);
    if (xin0 & yin1) FMA8(w01, ibase + sf);
    if (xin1 & yin1) FMA8(w11, ibase + sf + 1);
#undef FMA8
  }
  us8 o;
#pragma unroll
  for (int i = 0; i < 8; i++) o[i] = f2bf(acc[i]);
  *(us8*)(out + ((bt * 8 + h) * 32 + d4 * 8)) = o;
}

// all 5 levels in one dispatch
__global__ __launch_bounds__(256) void untranspose_all_k(
    const float* __restrict__ feats, float* __restrict__ out)
{
  int u = blockIdx.x;
  int pt0, start, S; i64 ooff;
  if (u < 128)      { pt0 = u;       start = 0;    S = 4096; ooff = 0; }
  else if (u < 160) { pt0 = u - 128; start = 4096; S = 1024; ooff = 2097152; }
  else if (u < 168) { pt0 = u - 160; start = 5120; S = 256;  ooff = 2621440; }
  else if (u < 170) { pt0 = u - 168; start = 5376; S = 64;   ooff = 2752512; }
  else              { pt0 = 0;       start = 5440; S = 16;   ooff = 2785280; }
  __shared__ float tile[32][33];
  int pt = pt0 * 32, ct = blockIdx.y * 32, b = blockIdx.z;
  int tx = threadIdx.x & 31, ty = threadIdx.x >> 5;
  for (int i = ty; i < 32; i += 8) {
    int p = pt + i;
    tile[i][tx] = (p < S) ? feats[((i64)b * NTOK + start + p) * 256 + ct + tx] : 0.f;
  }
  __syncthreads();
  for (int i = ty; i < 32; i += 8) {
    int c = ct + i, p = pt + tx;
    if (p < S) out[ooff + ((i64)b * 256 + c) * S + p] = tile[tx][i];
  }
}

extern "C" void kernel_launch(void* const* d_in, const int* in_sizes, int n_in,
                              void* d_out, int out_size, void* d_ws, size_t ws_size,
                              hipStream_t stream)
{
  const float* in0  = (const float*)d_in[0];
  const float* in1  = (const float*)d_in[1];
  const float* in2  = (const float*)d_in[2];
  const float* pw0  = (const float*)d_in[3];
  const float* pb0  = (const float*)d_in[4];
  const float* pw1  = (const float*)d_in[5];
  const float* pb1  = (const float*)d_in[6];
  const float* pw2  = (const float*)d_in[7];
  const float* pb2  = (const float*)d_in[8];
  const float* buw0 = (const float*)d_in[9];
  const float* bub0 = (const float*)d_in[10];
  const float* gng  = (const float*)d_in[11];
  const float* gnb  = (const float*)d_in[12];
  const float* buw1 = (const float*)d_in[13];
  const float* bub1 = (const float*)d_in[14];
  const float* ln1g = (const float*)d_in[15];
  const float* ln1b = (const float*)d_in[16];
  const float* woff = (const float*)d_in[17];
  const float* boff = (const float*)d_in[18];
  const float* watt = (const float*)d_in[19];
  const float* batt = (const float*)d_in[20];
  const float* wval = (const float*)d_in[21];
  const float* bval = (const float*)d_in[22];
  const float* wout = (const float*)d_in[23];
  const float* bout = (const float*)d_in[24];
  const float* ln2g = (const float*)d_in[25];
  const float* ln2b = (const float*)d_in[26];
  const float* w1   = (const float*)d_in[27];
  const float* b1   = (const float*)d_in[28];
  const float* w2   = (const float*)d_in[29];
  const float* b2   = (const float*)d_in[30];
  float* out = (float*)d_out;

  const i64 TC = (i64)NTOK * 256;

  // ---- ws layout (f32 units) ----
  float* ws    = (float*)d_ws;
  float* feats = ws;                               // 2,793,472
  u16*   qb    = (u16*)(feats + 2793472);          // 11008x256 bf16
  u16*   valb  = qb + 2818048;
  u16*   sampb = valb + 2818048;
  float* U     = (float*)(sampb + 2818048);        // union region: 5,637,120 f32
  u16*   off16 = (u16*)U;                          // [10912][320] bf16
  u16*   att16 = off16 + 3491840;                  // [10912][160] bf16
  u16*   abuf  = (u16*)U;                          // prologue A
  float* part  = U + 2097152;                      // split-K partials
  u16*   wb    = (u16*)(U + 5637120);              // 10,944,512 bf16
  float* bqkv  = (float*)(wb + 10944512);          // 4,608 f32
  float* m4gn  = bqkv + 4608;                      // 32,768 f32

  auto mg128 = [&](dim3 grid, const u16* A, const u16* B, int K,
                   float* C, float* C2, u16* C16, i64 sCm, const float* bias,
                   int relu, int addres, int qkv, int M, int N, int mbsh, i64 bCz, int KS) {
    mgemm_k<128><<<grid, dim3(256), 0, stream>>>(A, B, K, C, C2, C16, sCm, bias,
        relu, addres, qkv, M, N, mbsh, bCz, KS, part);
  };
  auto mg64 = [&](dim3 grid, const u16* A, const u16* B, int K,
                  float* C, u16* C16, i64 sCm, const float* bias,
                  int relu, int addres, int M, int N, int mbsh, i64 bCz, int KS) {
    mgemm_k<64><<<grid, dim3(256), 0, stream>>>(A, B, K, C, nullptr, C16, sCm, bias,
        relu, addres, 0, M, N, mbsh, bCz, KS, part);
  };

  // ---- weight conversion ----
  cvt_w_pro_k<<<dim3(24320), dim3(256), 0, stream>>>(pw0, pw1, pw2, buw0, buw1, wb);
  cvt_w_layer_k<<<dim3(3072, NLAYERS), dim3(256), 0, stream>>>(
      woff, watt, wval, wout, w1, w2, wb + 6225920);
  cvt_bias_k<<<dim3(18), dim3(256), 0, stream>>>(boff, batt, bval, bqkv);

  // ---- projections ----
  cvt_a_proj_k<<<dim3(16384), dim3(256), 0, stream>>>(in0, abuf, 4096, 512);
  mg64(dim3(64, 4, 1), abuf, wb, 512, feats, nullptr, 256, pb0, 0, 0,
       8192, 256, 12, TC, 1);
  cvt_a_proj_k<<<dim3(8192), dim3(256), 0, stream>>>(in1, abuf, 1024, 1024);
  mg64(dim3(16, 4, 2), abuf, wb + 131072, 1024, nullptr, nullptr, 256, nullptr, 0, 0,
       2048, 256, 10, 0, 2);
  reduce_k<<<dim3(2048), dim3(256), 0, stream>>>(part, feats + (i64)4096 * 256, pb1,
      10, TC, 256, 2048, 256, 2);
  cvt_a_proj_k<<<dim3(4096), dim3(256), 0, stream>>>(in2, abuf, 256, 2048);
  mg64(dim3(4, 4, 4), abuf, wb + 393216, 2048, nullptr, nullptr, 256, nullptr, 0, 0,
       512, 256, 8, 0, 4);
  reduce_k<<<dim3(512), dim3(256), 0, stream>>>(part, feats + (i64)5120 * 256, pb2,
      8, TC, 256, 512, 256, 4);

  // ---- bottom-up conv0 ----
  im2col_bf16_k<<<dim3(9216), dim3(256), 0, stream>>>(in2, abuf, 2048, 16, 16, 8, 8);
  mg64(dim3(1, 4, 16), abuf, wb + 917504, 18432, nullptr, nullptr, 256, nullptr, 0, 0,
       128, 256, 6, 0, 16);
  reduce_k<<<dim3(128), dim3(256), 0, stream>>>(part, feats + (i64)5376 * 256, bub0,
      6, TC, 256, 128, 256, 16);

  // ---- GN+ReLU, bottom-up conv1 ----
  gn_relu_k<<<dim3(8, 2), dim3(256), 0, stream>>>(feats, m4gn, gng, gnb);
  im2col_bf16_k<<<dim3(288), dim3(256), 0, stream>>>(m4gn, abuf, 256, 8, 8, 4, 4);
  mg64(dim3(1, 4, 4), abuf, wb + 5636096, 2304, nullptr, nullptr, 256, nullptr, 0, 0,
       32, 256, 4, 0, 4);
  reduce_k<<<dim3(32), dim3(256), 0, stream>>>(part, feats + (i64)5440 * 256, bub1,
      4, TC, 256, 32, 256, 4);

  // ---- 6 transformer layers ----
  for (int i = 0; i < NLAYERS; i++) {
    const u16* wbL = wb + 6225920 + (i64)i * 786432;
    ln_k<<<dim3(2728), dim3(256), 0, stream>>>(feats, qb,
        ln1g + (i64)i * 256, ln1b + (i64)i * 256, BNROWS);
    mg128(dim3(86, 6, 1), qb, wbL, 256, (float*)off16, (float*)att16, valb, 0,
          bqkv + (i64)i * 768, 0, 0, 1, BNROWS, 768, 14, 0, 1);
    dsample_k<<<dim3(688, 2), dim3(256), 0, stream>>>(valb, off16, att16, sampb);
    mg64(dim3(86, 4, 1), sampb, wbL + 196608, 256, feats, nullptr, 256,
         bout + (i64)i * 256, 0, 1, BNROWS, 256, 14, 0, 1);
    ln_k<<<dim3(2728), dim3(256), 0, stream>>>(feats, qb,
        ln2g + (i64)i * 256, ln2b + (i64)i * 256, BNROWS);
    ffn_fused_k<<<dim3(171), dim3(256), 0, stream>>>(qb, wbL + 262144,
        wbL + 524288, b1 + (i64)i * 1024, b2 + (i64)i * 256, feats, BNROWS);
  }

  // ---- split into 5 level maps (one dispatch) ----
  untranspose_all_k<<<dim3(171, 8, 2), dim3(256), 0, stream>>>(feats, out);
  (void)in_sizes; (void)n_in; (void)out_size; (void)ws_size;
}

// Round 11
// 957.345 us; speedup vs baseline: 8.3768x; 1.0539x over previous
//
#include <hip/hip_runtime.h>
#include <cstdint>

typedef long long i64;
typedef unsigned short u16;
typedef __attribute__((ext_vector_type(8))) short short8;
typedef __attribute__((ext_vector_type(8))) unsigned short us8;
typedef __attribute__((ext_vector_type(4))) float f32x4;

#define NTOK 5456
#define BNROWS 10912
#define NLAYERS 6

__device__ __forceinline__ u16 f2bf(float f) {
  unsigned u = __float_as_uint(f);
  return (u16)((u + 0x7FFFu + ((u >> 16) & 1u)) >> 16);
}
__device__ __forceinline__ float bf2f(u16 h) {
  return __uint_as_float(((unsigned)h) << 16);
}

// ---------------- bf16 MFMA GEMM, 2-phase double-buffered ----------------
template<int BNT>
__global__ __launch_bounds__(256) void mgemm_k(
    const u16* __restrict__ A, const u16* __restrict__ B, int K,
    float* __restrict__ C, float* __restrict__ C2, u16* __restrict__ C16, i64 sCm,
    const float* __restrict__ bias, int relu, int addres, int qkv,
    int M, int N, int mbsh, i64 bCz,
    int KS, float* __restrict__ part)
{
  constexpr int NW = BNT / 32;
  __shared__ u16 Asm[2][128 * 64];
  __shared__ u16 Bsm[2][BNT * 64];
  int tid = threadIdx.x;

  int bx = blockIdx.x, by = blockIdx.y;
  int gx = gridDim.x, gy = gridDim.y;
  int nwg = gx * gy;
  if (KS == 1 && nwg >= 16) {
    int lin = bx + gx * by;
    int xcd = lin & 7, k = lin >> 3;
    int q = nwg >> 3, r = nwg & 7;
    int f = (xcd < r) ? (xcd * (q + 1) + k) : (r * (q + 1) + (xcd - r) * q + k);
    bx = f / gy;
    by = f - bx * gy;
  }
  int m0 = bx * 128, n0 = by * BNT;

  int ks = blockIdx.z;
  int Kc = K / KS;
  int k0 = ks * Kc;
  int lane = tid & 63, w = tid >> 6;
  int wr = w >> 1, wc = w & 1;
  int r16 = lane & 15, g = lane >> 4;

  f32x4 acc[4][NW];
#pragma unroll
  for (int mi = 0; mi < 4; mi++)
#pragma unroll
    for (int nj = 0; nj < NW; nj++) acc[mi][nj] = (f32x4){0.f, 0.f, 0.f, 0.f};

  const u16* Ag = A + (i64)m0 * K + k0;
  const u16* Bg = B + (i64)n0 * K + k0;
  int nt = Kc >> 6;

  auto stage = [&](int buf, int kt) {
#pragma unroll
    for (int r = 0; r < 4; r++) {
      int s = r * 256 + tid;
      int row = s >> 3, c = s & 7;
      int cs = ((c ^ (row & 7)) << 3);
      __builtin_amdgcn_global_load_lds(
          (const __attribute__((address_space(1))) void*)(Ag + (i64)row * K + kt + cs),
          (__attribute__((address_space(3))) void*)(&Asm[buf][(r * 256 + (w << 6)) << 3]),
          16, 0, 0);
    }
#pragma unroll
    for (int r = 0; r < NW; r++) {
      int s = r * 256 + tid;
      int row = s >> 3, c = s & 7;
      int cs = ((c ^ (row & 7)) << 3);
      __builtin_amdgcn_global_load_lds(
          (const __attribute__((address_space(1))) void*)(Bg + (i64)row * K + kt + cs),
          (__attribute__((address_space(3))) void*)(&Bsm[buf][(r * 256 + (w << 6)) << 3]),
          16, 0, 0);
    }
  };

  stage(0, 0);
  __syncthreads();
  for (int t = 0; t < nt; t++) {
    int cur = t & 1;
    if (t + 1 < nt) stage(cur ^ 1, (t + 1) << 6);
#pragma unroll
    for (int h = 0; h < 2; h++) {
      short8 av[4], bv[NW];
#pragma unroll
      for (int mi = 0; mi < 4; mi++) {
        int row = wr * 64 + mi * 16 + r16;
        av[mi] = *(const short8*)&Asm[cur][row * 64 + ((((h << 2) + g) ^ (row & 7)) << 3)];
      }
#pragma unroll
      for (int nj = 0; nj < NW; nj++) {
        int row = wc * (NW * 16) + nj * 16 + r16;
        bv[nj] = *(const short8*)&Bsm[cur][row * 64 + ((((h << 2) + g) ^ (row & 7)) << 3)];
      }
#pragma unroll
      for (int mi = 0; mi < 4; mi++)
#pragma unroll
        for (int nj = 0; nj < NW; nj++)
          acc[mi][nj] = __builtin_amdgcn_mfma_f32_16x16x32_bf16(
              av[mi], bv[nj], acc[mi][nj], 0, 0, 0);
    }
    __syncthreads();
  }

  if (KS > 1) {
#pragma unroll
    for (int mi = 0; mi < 4; mi++)
#pragma unroll
      for (int nj = 0; nj < NW; nj++)
#pragma unroll
        for (int r = 0; r < 4; r++) {
          int grow = m0 + wr * 64 + mi * 16 + g * 4 + r;
          int gcol = n0 + wc * (NW * 16) + nj * 16 + r16;
          if (grow < M) part[((i64)ks * M + grow) * N + gcol] = acc[mi][nj][r];
        }
  } else if (qkv) {
    u16* off16 = (u16*)C;
    u16* att16 = (u16*)C2;
#pragma unroll
    for (int mi = 0; mi < 4; mi++)
#pragma unroll
      for (int nj = 0; nj < NW; nj++)
#pragma unroll
        for (int r = 0; r < 4; r++) {
          int grow = m0 + wr * 64 + mi * 16 + g * 4 + r;
          int gcol = n0 + wc * (NW * 16) + nj * 16 + r16;
          if (grow < M) {
            float v = acc[mi][nj][r] + bias[gcol];
            if (gcol < 320) off16[(i64)grow * 320 + gcol] = f2bf(v);
            else if (gcol < 480) att16[(i64)grow * 160 + (gcol - 320)] = f2bf(v);
            else if (gcol < 736) C16[(i64)grow * 256 + (gcol - 480)] = f2bf(v);
          }
        }
  } else {
    float bv[NW];
    int gc0 = n0 + wc * (NW * 16) + r16;
#pragma unroll
    for (int nj = 0; nj < NW; nj++)
      bv[nj] = bias ? bias[gc0 + nj * 16] : 0.f;
    int mask = (1 << mbsh) - 1;
#pragma unroll
    for (int mi = 0; mi < 4; mi++) {
#pragma unroll
      for (int r = 0; r < 4; r++) {
        int grow = m0 + wr * 64 + mi * 16 + g * 4 + r;
        if (grow >= M) continue;
        i64 rowb = (i64)(grow >> mbsh) * bCz + (i64)(grow & mask) * sCm;
#pragma unroll
        for (int nj = 0; nj < NW; nj++) {
          int gcol = gc0 + nj * 16;
          if (gcol >= N) continue;
          float v = acc[mi][nj][r] + bv[nj];
          if (relu) v = fmaxf(v, 0.f);
          i64 ci = rowb + gcol;
          if (C16) C16[ci] = f2bf(v);
          else {
            if (addres) v += C[ci];
            C[ci] = v;
          }
        }
      }
    }
  }
}

// ---------------- fused LN2+FFN v3 ----------------------------------------
// feats += W2^T(relu(W1 LN(feats) + b1)) + b2, block = 64 token rows,
// 512 threads (8 waves -> 2 waves/SIMD). 16 chunks of 64 FFN dims.
// LN computed in-kernel (8 lanes/row); A-panel bounced through LDS overlay
// (B1s[1], dead until first buf-1 prefetch) then held in registers.
__global__ __launch_bounds__(512, 1) void ffn_fused_k(
    float* __restrict__ feats, const u16* __restrict__ w1n,
    const u16* __restrict__ w2n, const float* __restrict__ b1,
    const float* __restrict__ b2, const float* __restrict__ lng,
    const float* __restrict__ lnb, int M)
{
  __shared__ u16 B1s[2][64 * 256];   // w1 chunk (32KB each)
  __shared__ u16 B2s[2][256 * 64];   // w2 chunk (32KB each)
  __shared__ u16 Hs[64 * 88];        // h chunk, padded stride 88
  __shared__ float b1s[1024];
  u16* As = &B1s[1][0];              // LN output overlay (freed before 1st prefetch)

  int tid = threadIdx.x;
  int lane = tid & 63, w = tid >> 6;
  int wr = w >> 1, wc = w & 1;       // wr in [0,4): 16-row group; wc in [0,2)
  int r16 = lane & 15, g = lane >> 4;
  int m0 = blockIdx.x * 64;

  auto stageW = [&](int buf, int ch) {
    // B1 chunk: 64 FFN rows x 256 k (4 rounds of 512thr x 16B)
#pragma unroll
    for (int r = 0; r < 4; r++) {
      int s = r * 512 + tid;
      int row = s >> 5, c = s & 31;
      int cs = ((c ^ (row & 7)) << 3);
      __builtin_amdgcn_global_load_lds(
          (const __attribute__((address_space(1))) void*)(w1n + (i64)(ch * 64 + row) * 256 + cs),
          (__attribute__((address_space(3))) void*)(&B1s[buf][(r * 512 + (w << 6)) << 3]),
          16, 0, 0);
    }
    // B2 chunk: 256 n-rows x 64 k (4 rounds)
#pragma unroll
    for (int r = 0; r < 4; r++) {
      int s = r * 512 + tid;
      int row = s >> 3, c = s & 7;
      int cs = ((c ^ (row & 7)) << 3);
      __builtin_amdgcn_global_load_lds(
          (const __attribute__((address_space(1))) void*)(w2n + (i64)row * 1024 + ch * 64 + cs),
          (__attribute__((address_space(3))) void*)(&B2s[buf][(r * 512 + (w << 6)) << 3]),
          16, 0, 0);
    }
  };

  stageW(0, 0);   // chunk 0 into buf0 (disjoint from As overlay)
  for (int i = tid; i < 1024; i += 512) b1s[i] = b1[i];

  // ---- LN2 on rows m0..m0+63: 8 lanes per row, 32 cols each ----
  {
    int rw = tid >> 3, c0 = (tid & 7) * 32;
    const float* fr = feats + (i64)(m0 + rw) * 256 + c0;
    float4 x[8];
    float s = 0.f, ss = 0.f;
#pragma unroll
    for (int j = 0; j < 8; j++) {
      x[j] = ((const float4*)fr)[j];
      s += x[j].x + x[j].y + x[j].z + x[j].w;
      ss += x[j].x * x[j].x + x[j].y * x[j].y + x[j].z * x[j].z + x[j].w * x[j].w;
    }
#pragma unroll
    for (int o = 1; o <= 4; o <<= 1) { s += __shfl_xor(s, o); ss += __shfl_xor(ss, o); }
    float mean = s * (1.f / 256.f);
    float rs = rsqrtf(ss * (1.f / 256.f) - mean * mean + 1e-5f);
    const float4* gp = (const float4*)(lng + c0);
    const float4* bp = (const float4*)(lnb + c0);
#pragma unroll
    for (int j = 0; j < 8; j += 2) {
      float4 g0 = gp[j], g1 = gp[j + 1];
      float4 b0 = bp[j], b1_ = bp[j + 1];
      us8 o;
      o[0] = f2bf((x[j].x - mean) * rs * g0.x + b0.x);
      o[1] = f2bf((x[j].y - mean) * rs * g0.y + b0.y);
      o[2] = f2bf((x[j].z - mean) * rs * g0.z + b0.z);
      o[3] = f2bf((x[j].w - mean) * rs * g0.w + b0.w);
      o[4] = f2bf((x[j + 1].x - mean) * rs * g1.x + b1_.x);
      o[5] = f2bf((x[j + 1].y - mean) * rs * g1.y + b1_.y);
      o[6] = f2bf((x[j + 1].z - mean) * rs * g1.z + b1_.z);
      o[7] = f2bf((x[j + 1].w - mean) * rs * g1.w + b1_.w);
      int gr = (tid & 7) * 4 + (j >> 1);
      *(us8*)&As[rw * 256 + ((gr ^ (rw & 7)) << 3)] = o;
    }
  }
  __syncthreads();   // As ready (also drains stageW(0))

  // ---- A-panel to registers: av_all[ks] = A[wr*16+r16][ks*32+g*8 ..] ----
  short8 av_all[8];
  {
    int row = wr * 16 + r16;
#pragma unroll
    for (int ks = 0; ks < 8; ks++)
      av_all[ks] = *(const short8*)&As[row * 256 + (((ks * 4 + g) ^ (row & 7)) << 3)];
  }
  __syncthreads();   // all As reads done before buf1 prefetch overwrites it

  f32x4 acc2[8];
#pragma unroll
  for (int nj = 0; nj < 8; nj++) acc2[nj] = (f32x4){0.f, 0.f, 0.f, 0.f};

  int cur = 0;
  for (int ch = 0; ch < 16; ch++) {
    if (ch + 1 < 16) stageW(cur ^ 1, ch + 1);   // prefetch; drains at mid barrier

    // GEMM1: h[64][64]; wave covers rows wr*16, cols wc*32 (2 frags)
    f32x4 acc1[2];
#pragma unroll
    for (int nj = 0; nj < 2; nj++) acc1[nj] = (f32x4){0.f, 0.f, 0.f, 0.f};
#pragma unroll
    for (int ks = 0; ks < 8; ks++) {
      short8 bv[2];
#pragma unroll
      for (int nj = 0; nj < 2; nj++) {
        int row = wc * 32 + nj * 16 + r16;
        bv[nj] = *(const short8*)&B1s[cur][row * 256 + (((ks * 4 + g) ^ (row & 7)) << 3)];
      }
#pragma unroll
      for (int nj = 0; nj < 2; nj++)
        acc1[nj] = __builtin_amdgcn_mfma_f32_16x16x32_bf16(
            av_all[ks], bv[nj], acc1[nj], 0, 0, 0);
    }
    // h = relu(acc1 + b1) -> Hs
#pragma unroll
    for (int nj = 0; nj < 2; nj++)
#pragma unroll
      for (int r = 0; r < 4; r++) {
        int hr = wr * 16 + g * 4 + r;
        int hc = wc * 32 + nj * 16 + r16;
        float v = acc1[nj][r] + b1s[ch * 64 + hc];
        Hs[hr * 88 + hc] = f2bf(fmaxf(v, 0.f));
      }
    __syncthreads();   // Hs visible; prefetch drained (overlapped with GEMM1)

    // GEMM2: rows wr*16 (1 frag), cols wc*128 (8 frags), K=64 (2 steps)
#pragma unroll
    for (int hh = 0; hh < 2; hh++) {
      short8 av2 = *(const short8*)&Hs[(wr * 16 + r16) * 88 + hh * 32 + g * 8];
      short8 bv2[8];
#pragma unroll
      for (int nj = 0; nj < 8; nj++) {
        int n = wc * 128 + nj * 16 + r16;
        bv2[nj] = *(const short8*)&B2s[cur][n * 64 + (((hh * 4 + g) ^ (n & 7)) << 3)];
      }
#pragma unroll
      for (int nj = 0; nj < 8; nj++)
        acc2[nj] = __builtin_amdgcn_mfma_f32_16x16x32_bf16(
            av2, bv2[nj], acc2[nj], 0, 0, 0);
    }
    __syncthreads();   // all reads of buf[cur]/Hs done before next overwrite
    cur ^= 1;
  }

  // epilogue: feats += acc2 + b2
#pragma unroll
  for (int r = 0; r < 4; r++) {
    int grow = m0 + wr * 16 + g * 4 + r;
    if (grow >= M) continue;
#pragma unroll
    for (int nj = 0; nj < 8; nj++) {
      int col = wc * 128 + nj * 16 + r16;
      i64 ci = (i64)grow * 256 + col;
      feats[ci] += acc2[nj][r] + b2[col];
    }
  }
}

// reduce split-K fp32 partials (stride N); row map via shift/mask
__global__ void reduce_k(const float* __restrict__ part, float* __restrict__ C,
    const float* __restrict__ bias, int mbsh, i64 bCz, i64 sCm, int M, int N, int KS)
{
  int idx = blockIdx.x * 256 + threadIdx.x;
  if (idx >= M * N) return;
  int m = idx / N, n = idx - m * N;
  float v = bias ? bias[n] : 0.f;
  for (int ks = 0; ks < KS; ks++) v += part[((i64)ks * M + m) * N + n];
  C[(i64)(m >> mbsh) * bCz + (i64)(m & ((1 << mbsh) - 1)) * sCm + n] = v;
}

// ---------------- weight conversions ----------------
__global__ void cvt_w_pro_k(const float* __restrict__ pw0, const float* __restrict__ pw1,
    const float* __restrict__ pw2, const float* __restrict__ buw0,
    const float* __restrict__ buw1, u16* __restrict__ dst)
{
  int idx = blockIdx.x * 256 + threadIdx.x;
  if (idx >= 6225920) return;
  float v;
  if (idx < 131072) v = pw0[idx];
  else if (idx < 393216) v = pw1[idx - 131072];
  else if (idx < 917504) v = pw2[idx - 393216];
  else if (idx < 5636096) v = buw0[idx - 917504];
  else v = buw1[idx - 5636096];
  dst[idx] = f2bf(v);
}

__global__ void cvt_w_layer_k(const float* __restrict__ woff, const float* __restrict__ watt,
    const float* __restrict__ wval, const float* __restrict__ wout,
    const float* __restrict__ w1, const float* __restrict__ w2, u16* __restrict__ dst)
{
  int L = blockIdx.y;
  int o = blockIdx.x * 256 + threadIdx.x;
  if (o >= 786432) return;
  u16* d = dst + (i64)L * 786432;
  float v;
  if (o < 196608) {
    int n = o >> 8, k = o & 255;
    if (n < 320) v = woff[(i64)L * 81920 + k * 320 + n];
    else if (n < 480) v = watt[(i64)L * 40960 + k * 160 + (n - 320)];
    else if (n < 736) v = wval[(i64)L * 65536 + k * 256 + (n - 480)];
    else v = 0.f;
  } else if (o < 262144) {
    int o2 = o - 196608; int n = o2 >> 8, k = o2 & 255;
    v = wout[(i64)L * 65536 + k * 256 + n];
  } else if (o < 524288) {
    int o2 = o - 262144; int n = o2 >> 8, k = o2 & 255;
    v = w1[(i64)L * 262144 + (i64)k * 1024 + n];
  } else {
    int o2 = o - 524288; int n = o2 >> 10, k = o2 & 1023;
    v = w2[(i64)L * 262144 + (i64)k * 256 + n];
  }
  d[o] = f2bf(v);
}

__global__ void cvt_bias_k(const float* __restrict__ boff, const float* __restrict__ batt,
    const float* __restrict__ bval, float* __restrict__ bq)
{
  int idx = blockIdx.x * 256 + threadIdx.x;
  if (idx >= NLAYERS * 768) return;
  int L = idx / 768, n = idx - L * 768;
  float v;
  if (n < 320) v = boff[(i64)L * 320 + n];
  else if (n < 480) v = batt[(i64)L * 160 + (n - 320)];
  else if (n < 736) v = bval[(i64)L * 256 + (n - 480)];
  else v = 0.f;
  bq[idx] = v;
}

__global__ void cvt_a_proj_k(const float* __restrict__ in, u16* __restrict__ out,
                             int P, int K)
{
  i64 o = (i64)blockIdx.x * 256 + threadIdx.x;
  if (o >= (i64)2 * P * K) return;
  int m = (int)(o / K), k = (int)(o % K);
  int b = m / P, p = m - b * P;
  out[o] = f2bf(in[((i64)b * K + k) * P + p]);
}

__global__ void im2col_bf16_k(const float* __restrict__ in, u16* __restrict__ out,
    int Cin, int Hin, int Win, int Ho, int Wo)
{
  int Kk = Cin * 9;
  i64 total = (i64)2 * Ho * Wo * Kk;
  i64 o = (i64)blockIdx.x * 256 + threadIdx.x;
  if (o >= total) return;
  int k = (int)(o % Kk);
  int m = (int)(o / Kk);
  int hw = Ho * Wo;
  int b = m / hw, pix = m - b * hw;
  int oy = pix / Wo, ox = pix - oy * Wo;
  int ci = k / 9, r = k - ci * 9;
  int ky = r / 3, kx = r - ky * 3;
  int iy = oy * 2 - 1 + ky, ix = ox * 2 - 1 + kx;
  float v = 0.f;
  if (iy >= 0 && iy < Hin && ix >= 0 && ix < Win)
    v = in[(((i64)b * Cin + ci) * Hin + iy) * Win + ix];
  out[o] = f2bf(v);
}

__global__ void gn_relu_k(const float* __restrict__ feats, float* __restrict__ y,
    const float* __restrict__ g, const float* __restrict__ bt)
{
  int grp = blockIdx.x, b = blockIdx.y;
  int tid = threadIdx.x;
  const float* fb = feats + ((i64)b * NTOK + 5376) * 256 + grp * 32;
  float s = 0.f, ss = 0.f;
  for (int i = tid; i < 2048; i += 256) {
    int cl = i >> 6, p = i & 63;
    float v = fb[(i64)p * 256 + cl];
    s += v; ss += v * v;
  }
  __shared__ float sb[4], ssb[4];
#pragma unroll
  for (int o = 32; o > 0; o >>= 1) { s += __shfl_down(s, o); ss += __shfl_down(ss, o); }
  int wv = tid >> 6;
  if ((tid & 63) == 0) { sb[wv] = s; ssb[wv] = ss; }
  __syncthreads();
  float ts = sb[0] + sb[1] + sb[2] + sb[3];
  float tss = ssb[0] + ssb[1] + ssb[2] + ssb[3];
  float mean = ts * (1.f / 2048.f);
  float rs = rsqrtf(tss * (1.f / 2048.f) - mean * mean + 1e-5f);
  for (int i = tid; i < 2048; i += 256) {
    int cl = i >> 6, p = i & 63;
    int c = grp * 32 + cl;
    float v = (fb[(i64)p * 256 + cl] - mean) * rs * g[c] + bt[c];
    y[((i64)b * 256 + c) * 64 + p] = fmaxf(v, 0.f);
  }
}

__global__ __launch_bounds__(256) void ln_k(const float* __restrict__ x,
    u16* __restrict__ y, const float* __restrict__ g, const float* __restrict__ bt,
    int rows)
{
  int row = blockIdx.x * 4 + (threadIdx.x >> 6);
  if (row >= rows) return;
  int lane = threadIdx.x & 63;
  float4 v = ((const float4*)(x + (i64)row * 256))[lane];
  float s = v.x + v.y + v.z + v.w;
  float ss = v.x * v.x + v.y * v.y + v.z * v.z + v.w * v.w;
#pragma unroll
  for (int o = 32; o > 0; o >>= 1) { s += __shfl_down(s, o); ss += __shfl_down(ss, o); }
  s = __shfl(s, 0);
  ss = __shfl(ss, 0);
  float mean = s * (1.f / 256.f);
  float rs = rsqrtf(ss * (1.f / 256.f) - mean * mean + 1e-5f);
  float4 gg = ((const float4*)g)[lane];
  float4 bb = ((const float4*)bt)[lane];
  ushort4 o4;
  o4.x = f2bf((v.x - mean) * rs * gg.x + bb.x);
  o4.y = f2bf((v.y - mean) * rs * gg.y + bb.y);
  o4.z = f2bf((v.z - mean) * rs * gg.z + bb.z);
  o4.w = f2bf((v.w - mean) * rs * gg.w + bb.w);
  ((ushort4*)(y + (i64)row * 256))[lane] = o4;
}

// deformable sampling v5 (unchanged)
__global__ __launch_bounds__(256) void dsample_k(
    const u16* __restrict__ val, const u16* __restrict__ off,
    const u16* __restrict__ att, u16* __restrict__ out)
{
  const int FH[5] = {64, 32, 16, 8, 4};
  const int ST[5] = {0, 4096, 5120, 5376, 5440};
  int bid = blockIdx.x;
  int chunk = (bid & 7) * 86 + (bid >> 3);
  if (chunk >= 682) return;
  int lane = threadIdx.x & 63;
  int half = lane >> 5;
  int l32 = lane & 31;
  int t = chunk * 8 + ((threadIdx.x >> 6) << 1) + half;
  int b = blockIdx.y;
  int h = l32 >> 2, d4 = l32 & 3;

  int lv;
  if (t < 4096)      lv = 0;
  else if (t < 5120) lv = 1;
  else if (t < 5376) lv = 2;
  else if (t < 5440) lv = 3;
  else               lv = 4;
  int loc = t - ST[lv];
  int sh = 6 - lv;
  int py = loc >> sh, px = loc - (py << sh);
  float inv = 1.f / (float)FH[lv];
  float prx = (px + 0.5f) * inv, pry = (py + 0.5f) * inv;
  i64 bt = (i64)b * NTOK + t;
  const u16* offp = off + bt * 320 + h * 40;
  const u16* attp = att + bt * 160 + h * 20;
  const u16* vbase = val + ((i64)b * NTOK) * 256 + h * 32 + d4 * 8;

  float own_a[5], own_fx[5], own_fy[5];
  int own_pk[5];
  float mx = -1e30f;
#pragma unroll
  for (int j = 0; j < 5; j++) {
    float lg = bf2f(attp[d4 + 4 * j]);
    own_a[j] = lg;
    mx = fmaxf(mx, lg);
  }
  mx = fmaxf(mx, __shfl_xor(mx, 1));
  mx = fmaxf(mx, __shfl_xor(mx, 2));
  float sum = 0.f;
#pragma unroll
  for (int j = 0; j < 5; j++) {
    float e = __expf(own_a[j] - mx);
    own_a[j] = e;
    sum += e;
  }
  sum += __shfl_xor(sum, 1);
  sum += __shfl_xor(sum, 2);
  float rinv = 1.f / sum;
#pragma unroll
  for (int j = 0; j < 5; j++) {
    int p = d4 + 4 * j;
    own_a[j] *= rinv;
    unsigned opk = *(const unsigned*)(offp + 2 * p);
    float ox = bf2f((u16)(opk & 0xFFFF));
    float oy = bf2f((u16)(opk >> 16));
    float sff = (float)(64 >> j);
    float xx = prx * sff + ox - 0.5f;
    float yy = pry * sff + oy - 0.5f;
    float xf = floorf(xx), yf = floorf(yy);
    own_fx[j] = xx - xf;
    own_fy[j] = yy - yf;
    own_pk[j] = (((int)yf) << 16) | (((int)xf) & 0xFFFF);
  }

  float acc[8] = {0.f, 0.f, 0.f, 0.f, 0.f, 0.f, 0.f, 0.f};
#pragma unroll
  for (int p = 0; p < 20; p++) {
    const int j = p >> 2;
    const int sf = FH[j], st = ST[j];
    int src = (half << 5) | (h << 2) | (p & 3);
    float wa = __shfl(own_a[j], src);
    float fx = __shfl(own_fx[j], src);
    float fy = __shfl(own_fy[j], src);
    int pk = __shfl(own_pk[j], src);
    int x0 = (pk << 16) >> 16;
    int y0 = pk >> 16;
    float gx0 = wa - wa * fx, gx1 = wa * fx;
    float w00 = gx0 - gx0 * fy, w01 = gx0 * fy;
    float w10 = gx1 - gx1 * fy, w11 = gx1 * fy;
    bool xin0 = (x0 >= 0) & (x0 < sf), xin1 = (x0 + 1 >= 0) & (x0 + 1 < sf);
    bool yin0 = (y0 >= 0) & (y0 < sf), yin1 = (y0 + 1 >= 0) & (y0 + 1 < sf);
    int ibase = st + y0 * sf + x0;
#define FMA8(W, IDX) { \
      us8 v = *(const us8*)(vbase + (i64)(IDX) * 256); \
      acc[0] = fmaf(W, bf2f(v[0]), acc[0]); acc[1] = fmaf(W, bf2f(v[1]), acc[1]); \
      acc[2] = fmaf(W, bf2f(v[2]), acc[2]); acc[3] = fmaf(W, bf2f(v[3]), acc[3]); \
      acc[4] = fmaf(W, bf2f(v[4]), acc[4]); acc[5] = fmaf(W, bf2f(v[5]), acc[5]); \
      acc[6] = fmaf(W, bf2f(v[6]), acc[6]); acc[7] = fmaf(W, bf2f(v[7]), acc[7]); }
    if (xin0 & yin0) FMA8(w00, ibase);
    if (xin1 & yin0) FMA8(w10, ibase + 1);
    if (xin0 & yin1) FMA8(w01, ibase + sf);
    if (xin1 & yin1) FMA8(w11, ibase + sf + 1);
#undef FMA8
  }
  us8 o;
#pragma unroll
  for (int i = 0; i < 8; i++) o[i] = f2bf(acc[i]);
  *(us8*)(out + ((bt * 8 + h) * 32 + d4 * 8)) = o;
}

// all 5 levels in one dispatch
__global__ __launch_bounds__(256) void untranspose_all_k(
    const float* __restrict__ feats, float* __restrict__ out)
{
  int u = blockIdx.x;
  int pt0, start, S; i64 ooff;
  if (u < 128)      { pt0 = u;       start = 0;    S = 4096; ooff = 0; }
  else if (u < 160) { pt0 = u - 128; start = 4096; S = 1024; ooff = 2097152; }
  else if (u < 168) { pt0 = u - 160; start = 5120; S = 256;  ooff = 2621440; }
  else if (u < 170) { pt0 = u - 168; start = 5376; S = 64;   ooff = 2752512; }
  else              { pt0 = 0;       start = 5440; S = 16;   ooff = 2785280; }
  __shared__ float tile[32][33];
  int pt = pt0 * 32, ct = blockIdx.y * 32, b = blockIdx.z;
  int tx = threadIdx.x & 31, ty = threadIdx.x >> 5;
  for (int i = ty; i < 32; i += 8) {
    int p = pt + i;
    tile[i][tx] = (p < S) ? feats[((i64)b * NTOK + start + p) * 256 + ct + tx] : 0.f;
  }
  __syncthreads();
  for (int i = ty; i < 32; i += 8) {
    int c = ct + i, p = pt + tx;
    if (p < S) out[ooff + ((i64)b * 256 + c) * S + p] = tile[tx][i];
  }
}

extern "C" void kernel_launch(void* const* d_in, const int* in_sizes, int n_in,
                              void* d_out, int out_size, void* d_ws, size_t ws_size,
                              hipStream_t stream)
{
  const float* in0  = (const float*)d_in[0];
  const float* in1  = (const float*)d_in[1];
  const float* in2  = (const float*)d_in[2];
  const float* pw0  = (const float*)d_in[3];
  const float* pb0  = (const float*)d_in[4];
  const float* pw1  = (const float*)d_in[5];
  const float* pb1  = (const float*)d_in[6];
  const float* pw2  = (const float*)d_in[7];
  const float* pb2  = (const float*)d_in[8];
  const float* buw0 = (const float*)d_in[9];
  const float* bub0 = (const float*)d_in[10];
  const float* gng  = (const float*)d_in[11];
  const float* gnb  = (const float*)d_in[12];
  const float* buw1 = (const float*)d_in[13];
  const float* bub1 = (const float*)d_in[14];
  const float* ln1g = (const float*)d_in[15];
  const float* ln1b = (const float*)d_in[16];
  const float* woff = (const float*)d_in[17];
  const float* boff = (const float*)d_in[18];
  const float* watt = (const float*)d_in[19];
  const float* batt = (const float*)d_in[20];
  const float* wval = (const float*)d_in[21];
  const float* bval = (const float*)d_in[22];
  const float* wout = (const float*)d_in[23];
  const float* bout = (const float*)d_in[24];
  const float* ln2g = (const float*)d_in[25];
  const float* ln2b = (const float*)d_in[26];
  const float* w1   = (const float*)d_in[27];
  const float* b1   = (const float*)d_in[28];
  const float* w2   = (const float*)d_in[29];
  const float* b2   = (const float*)d_in[30];
  float* out = (float*)d_out;

  const i64 TC = (i64)NTOK * 256;

  // ---- ws layout (f32 units) ----
  float* ws    = (float*)d_ws;
  float* feats = ws;                               // 2,793,472
  u16*   qb    = (u16*)(feats + 2793472);          // 11008x256 bf16
  u16*   valb  = qb + 2818048;
  u16*   sampb = valb + 2818048;
  float* U     = (float*)(sampb + 2818048);        // union region: 5,637,120 f32
  u16*   off16 = (u16*)U;                          // [10912][320] bf16
  u16*   att16 = off16 + 3491840;                  // [10912][160] bf16
  u16*   abuf  = (u16*)U;                          // prologue A
  float* part  = U + 2097152;                      // split-K partials
  u16*   wb    = (u16*)(U + 5637120);              // 10,944,512 bf16
  float* bqkv  = (float*)(wb + 10944512);          // 4,608 f32
  float* m4gn  = bqkv + 4608;                      // 32,768 f32

  auto mg128 = [&](dim3 grid, const u16* A, const u16* B, int K,
                   float* C, float* C2, u16* C16, i64 sCm, const float* bias,
                   int relu, int addres, int qkv, int M, int N, int mbsh, i64 bCz, int KS) {
    mgemm_k<128><<<grid, dim3(256), 0, stream>>>(A, B, K, C, C2, C16, sCm, bias,
        relu, addres, qkv, M, N, mbsh, bCz, KS, part);
  };
  auto mg64 = [&](dim3 grid, const u16* A, const u16* B, int K,
                  float* C, u16* C16, i64 sCm, const float* bias,
                  int relu, int addres, int M, int N, int mbsh, i64 bCz, int KS) {
    mgemm_k<64><<<grid, dim3(256), 0, stream>>>(A, B, K, C, nullptr, C16, sCm, bias,
        relu, addres, 0, M, N, mbsh, bCz, KS, part);
  };

  // ---- weight conversion ----
  cvt_w_pro_k<<<dim3(24320), dim3(256), 0, stream>>>(pw0, pw1, pw2, buw0, buw1, wb);
  cvt_w_layer_k<<<dim3(3072, NLAYERS), dim3(256), 0, stream>>>(
      woff, watt, wval, wout, w1, w2, wb + 6225920);
  cvt_bias_k<<<dim3(18), dim3(256), 0, stream>>>(boff, batt, bval, bqkv);

  // ---- projections ----
  cvt_a_proj_k<<<dim3(16384), dim3(256), 0, stream>>>(in0, abuf, 4096, 512);
  mg64(dim3(64, 4, 1), abuf, wb, 512, feats, nullptr, 256, pb0, 0, 0,
       8192, 256, 12, TC, 1);
  cvt_a_proj_k<<<dim3(8192), dim3(256), 0, stream>>>(in1, abuf, 1024, 1024);
  mg64(dim3(16, 4, 2), abuf, wb + 131072, 1024, nullptr, nullptr, 256, nullptr, 0, 0,
       2048, 256, 10, 0, 2);
  reduce_k<<<dim3(2048), dim3(256), 0, stream>>>(part, feats + (i64)4096 * 256, pb1,
      10, TC, 256, 2048, 256, 2);
  cvt_a_proj_k<<<dim3(4096), dim3(256), 0, stream>>>(in2, abuf, 256, 2048);
  mg64(dim3(4, 4, 4), abuf, wb + 393216, 2048, nullptr, nullptr, 256, nullptr, 0, 0,
       512, 256, 8, 0, 4);
  reduce_k<<<dim3(512), dim3(256), 0, stream>>>(part, feats + (i64)5120 * 256, pb2,
      8, TC, 256, 512, 256, 4);

  // ---- bottom-up conv0 ----
  im2col_bf16_k<<<dim3(9216), dim3(256), 0, stream>>>(in2, abuf, 2048, 16, 16, 8, 8);
  mg64(dim3(1, 4, 16), abuf, wb + 917504, 18432, nullptr, nullptr, 256, nullptr, 0, 0,
       128, 256, 6, 0, 16);
  reduce_k<<<dim3(128), dim3(256), 0, stream>>>(part, feats + (i64)5376 * 256, bub0,
      6, TC, 256, 128, 256, 16);

  // ---- GN+ReLU, bottom-up conv1 ----
  gn_relu_k<<<dim3(8, 2), dim3(256), 0, stream>>>(feats, m4gn, gng, gnb);
  im2col_bf16_k<<<dim3(288), dim3(256), 0, stream>>>(m4gn, abuf, 256, 8, 8, 4, 4);
  mg64(dim3(1, 4, 4), abuf, wb + 5636096, 2304, nullptr, nullptr, 256, nullptr, 0, 0,
       32, 256, 4, 0, 4);
  reduce_k<<<dim3(32), dim3(256), 0, stream>>>(part, feats + (i64)5440 * 256, bub1,
      4, TC, 256, 32, 256, 4);

  // ---- 6 transformer layers ----
  for (int i = 0; i < NLAYERS; i++) {
    const u16* wbL = wb + 6225920 + (i64)i * 786432;
    ln_k<<<dim3(2728), dim3(256), 0, stream>>>(feats, qb,
        ln1g + (i64)i * 256, ln1b + (i64)i * 256, BNROWS);
    mg128(dim3(86, 6, 1), qb, wbL, 256, (float*)off16, (float*)att16, valb, 0,
          bqkv + (i64)i * 768, 0, 0, 1, BNROWS, 768, 14, 0, 1);
    dsample_k<<<dim3(688, 2), dim3(256), 0, stream>>>(valb, off16, att16, sampb);
    mg64(dim3(86, 4, 1), sampb, wbL + 196608, 256, feats, nullptr, 256,
         bout + (i64)i * 256, 0, 1, BNROWS, 256, 14, 0, 1);
    // fused LN2 + FFN (h stays in LDS; LN in-kernel)
    ffn_fused_k<<<dim3(171), dim3(512), 0, stream>>>(feats, wbL + 262144,
        wbL + 524288, b1 + (i64)i * 1024, b2 + (i64)i * 256,
        ln2g + (i64)i * 256, ln2b + (i64)i * 256, BNROWS);
  }

  // ---- split into 5 level maps (one dispatch) ----
  untranspose_all_k<<<dim3(171, 8, 2), dim3(256), 0, stream>>>(feats, out);
  (void)in_sizes; (void)n_in; (void)out_size; (void)ws_size;
}